// Round 1
// baseline (2999.460 us; speedup 1.0000x reference)
//
#include <hip/hip_runtime.h>
#include <math.h>

#define BZ 2
#define SQ 2048
#define DIN 1024
#define HH 16
#define DQK 128
#define DV 128
#define CPH 384          // 2*DQK + DV
#define NT (HH*CPH)      // 6144
#define MROWS (BZ*SQ)    // 4096

__device__ __forceinline__ float cubef(float x) { return x * x * x; }

// ---------------- K1: qkv = x @ proj_in  (M=4096, K=1024, N=6144) ----------------
__global__ __launch_bounds__(256) void gemm_qkv(const float* __restrict__ A,
                                                const float* __restrict__ Bw,
                                                float* __restrict__ C) {
    __shared__ float AsT[16][68];   // [k][m], padded
    __shared__ float Bs[16][68];    // [k][n], padded
    const int t = threadIdx.x;
    const int tx = t & 15, ty = t >> 4;
    const int colBase = blockIdx.x * 64;
    const int rowBase = blockIdx.y * 64;
    float acc[4][4];
    #pragma unroll
    for (int i = 0; i < 4; i++)
        #pragma unroll
        for (int j = 0; j < 4; j++) acc[i][j] = 0.f;

    for (int k0 = 0; k0 < DIN; k0 += 16) {
        #pragma unroll
        for (int i = 0; i < 4; i++) {
            int e = t + 256 * i;
            int r = e >> 4, c = e & 15;
            AsT[c][r] = A[(size_t)(rowBase + r) * DIN + k0 + c];
            int rb = e >> 6, cb = e & 63;
            Bs[rb][cb] = Bw[(size_t)(k0 + rb) * NT + colBase + cb];
        }
        __syncthreads();
        #pragma unroll
        for (int kk = 0; kk < 16; kk++) {
            float4 a = *(const float4*)&AsT[kk][4 * ty];
            float4 b = *(const float4*)&Bs[kk][4 * tx];
            acc[0][0] += a.x * b.x; acc[0][1] += a.x * b.y; acc[0][2] += a.x * b.z; acc[0][3] += a.x * b.w;
            acc[1][0] += a.y * b.x; acc[1][1] += a.y * b.y; acc[1][2] += a.y * b.z; acc[1][3] += a.y * b.w;
            acc[2][0] += a.z * b.x; acc[2][1] += a.z * b.y; acc[2][2] += a.z * b.z; acc[2][3] += a.z * b.w;
            acc[3][0] += a.w * b.x; acc[3][1] += a.w * b.y; acc[3][2] += a.w * b.z; acc[3][3] += a.w * b.w;
        }
        __syncthreads();
    }
    #pragma unroll
    for (int i = 0; i < 4; i++) {
        float4 r;
        r.x = acc[i][0]; r.y = acc[i][1]; r.z = acc[i][2]; r.w = acc[i][3];
        *(float4*)&C[(size_t)(rowBase + 4 * ty + i) * NT + colBase + 4 * tx] = r;
    }
}

// ---------------- K2: in-place rotary on q,k + v_bias ----------------
__global__ __launch_bounds__(256) void rot_bias(float* __restrict__ qkv,
                                                const float* __restrict__ vbias) {
    int tid = blockIdx.x * 256 + threadIdx.x;
    int u = tid & 255;
    int h = (tid >> 8) & 15;
    int s = (tid >> 12) & 2047;
    int z = tid >> 23;
    size_t base = ((size_t)((z * SQ + s) * HH + h)) * CPH;
    if (u < 128) {
        int j = u & 63;
        int off = (u < 64) ? 0 : 128;
        // f = 10000^(-2j/128) = exp(-j * ln(10000)/64)
        float f = expf(-0.14391156831212788f * (float)j);
        float ang = (float)s * f;
        float sn, c;
        sincosf(ang, &sn, &c);
        float t1 = qkv[base + off + j];
        float t2 = qkv[base + off + j + 64];
        qkv[base + off + j]      = t1 * c - t2 * sn;
        qkv[base + off + j + 64] = t2 * c + t1 * sn;
    } else {
        int x = u - 128;
        qkv[base + 256 + x] += vbias[h * 128 + x];
    }
}

// ---------------- K3: masked softmax attention, one block = (z,h, 32 queries) ----------------
__global__ __launch_bounds__(256) void attn_kernel(const float* __restrict__ qkv,
                                                   const int* __restrict__ mask,
                                                   float* __restrict__ O3) {
    const int blk = blockIdx.x;
    const int qt = blk & 63;
    const int h  = (blk >> 6) & 15;
    const int z  = blk >> 10;
    const int t  = threadIdx.x;

    __shared__ float qs[32 * 132];
    __shared__ float ks[32 * 132];
    __shared__ float vs[32 * 132];
    __shared__ float wl[32 * 33];
    __shared__ float dpart[32][16];
    __shared__ int qm[32];
    __shared__ int km[32];

    const int q0 = qt * 32;
    const int lr = t >> 3;           // loader row 0..31
    const int lc = (t & 7) * 16;     // loader col base

    // load Q tile (rows q0..q0+31, dims 0..127)
    {
        const float* src = qkv + ((size_t)(((z * SQ) + q0 + lr) * HH + h)) * CPH + lc;
        float* dst = &qs[lr * 132 + lc];
        #pragma unroll
        for (int i = 0; i < 16; i += 4)
            *(float4*)(dst + i) = *(const float4*)(src + i);
    }
    if (t < 32) qm[t] = mask[z * SQ + q0 + t];

    const int qg = t >> 4;           // 0..15
    const int kg = t & 15;           // 0..15
    const int qa0 = 2 * qg, qa1 = qa0 + 1;
    const int ka0 = 2 * kg, ka1 = ka0 + 1;
    const int d0 = (t & 15) * 8;     // phase-B dim base

    float ob0[8], ob1[8];
    #pragma unroll
    for (int i = 0; i < 8; i++) { ob0[i] = 0.f; ob1[i] = 0.f; }
    float dsum0 = 0.f, dsum1 = 0.f;
    const float scale = 0.08838834764831845f;  // 1/sqrt(128)

    for (int kt = 0; kt < SQ; kt += 32) {
        __syncthreads();   // protect ks/vs/km reuse vs previous phase B
        {
            const float* srck = qkv + ((size_t)(((z * SQ) + kt + lr) * HH + h)) * CPH + 128 + lc;
            float* dstk = &ks[lr * 132 + lc];
            float* dstv = &vs[lr * 132 + lc];
            #pragma unroll
            for (int i = 0; i < 16; i += 4) {
                *(float4*)(dstk + i) = *(const float4*)(srck + i);
                *(float4*)(dstv + i) = *(const float4*)(srck + 128 + i);
            }
        }
        if (t < 32) km[t] = mask[z * SQ + kt + t];
        __syncthreads();

        // phase A: 2x2 scores per thread
        float s00 = 0.f, s01 = 0.f, s10 = 0.f, s11 = 0.f;
        {
            const float* q0p = &qs[qa0 * 132];
            const float* q1p = &qs[qa1 * 132];
            const float* k0p = &ks[ka0 * 132];
            const float* k1p = &ks[ka1 * 132];
            #pragma unroll
            for (int d = 0; d < 128; d += 4) {
                float4 a0 = *(const float4*)(q0p + d);
                float4 a1 = *(const float4*)(q1p + d);
                float4 b0 = *(const float4*)(k0p + d);
                float4 b1 = *(const float4*)(k1p + d);
                s00 += a0.x * b0.x + a0.y * b0.y + a0.z * b0.z + a0.w * b0.w;
                s01 += a0.x * b1.x + a0.y * b1.y + a0.z * b1.z + a0.w * b1.w;
                s10 += a1.x * b0.x + a1.y * b0.y + a1.z * b0.z + a1.w * b0.w;
                s11 += a1.x * b1.x + a1.y * b1.y + a1.z * b1.z + a1.w * b1.w;
            }
        }
        {
            int m0 = qm[qa0], m1 = qm[qa1], n0 = km[ka0], n1 = km[ka1];
            float w00 = (m0 | n0) ? 0.f : __expf(s00 * scale);
            float w01 = (m0 | n1) ? 0.f : __expf(s01 * scale);
            float w10 = (m1 | n0) ? 0.f : __expf(s10 * scale);
            float w11 = (m1 | n1) ? 0.f : __expf(s11 * scale);
            wl[qa0 * 33 + ka0] = w00;
            wl[qa0 * 33 + ka1] = w01;
            wl[qa1 * 33 + ka0] = w10;
            wl[qa1 * 33 + ka1] = w11;
            dsum0 += w00 + w01;
            dsum1 += w10 + w11;
        }
        __syncthreads();

        // phase B: thread (qg, d0): rows qa0/qa1, dims d0..d0+7
        #pragma unroll 8
        for (int k = 0; k < 32; k++) {
            float w0 = wl[qa0 * 33 + k];
            float w1 = wl[qa1 * 33 + k];
            const float* vp = &vs[k * 132 + d0];
            float4 v0 = *(const float4*)(vp);
            float4 v1 = *(const float4*)(vp + 4);
            ob0[0] += w0 * v0.x; ob0[1] += w0 * v0.y; ob0[2] += w0 * v0.z; ob0[3] += w0 * v0.w;
            ob0[4] += w0 * v1.x; ob0[5] += w0 * v1.y; ob0[6] += w0 * v1.z; ob0[7] += w0 * v1.w;
            ob1[0] += w1 * v0.x; ob1[1] += w1 * v0.y; ob1[2] += w1 * v0.z; ob1[3] += w1 * v0.w;
            ob1[4] += w1 * v1.x; ob1[5] += w1 * v1.y; ob1[6] += w1 * v1.z; ob1[7] += w1 * v1.w;
        }
    }

    dpart[qa0][kg] = dsum0;
    dpart[qa1][kg] = dsum1;
    __syncthreads();
    float den0 = 0.f, den1 = 0.f;
    #pragma unroll
    for (int i = 0; i < 16; i++) { den0 += dpart[qa0][i]; den1 += dpart[qa1][i]; }
    float inv0 = den0 > 0.f ? 1.f / den0 : 0.f;
    float inv1 = den1 > 0.f ? 1.f / den1 : 0.f;

    {
        float* dst0 = O3 + ((size_t)(((z * SQ) + q0 + qa0) * HH + h)) * DV + d0;
        float* dst1 = O3 + ((size_t)(((z * SQ) + q0 + qa1) * HH + h)) * DV + d0;
        float4 r;
        r.x = cubef(ob0[0] * inv0); r.y = cubef(ob0[1] * inv0);
        r.z = cubef(ob0[2] * inv0); r.w = cubef(ob0[3] * inv0);
        *(float4*)(dst0) = r;
        r.x = cubef(ob0[4] * inv0); r.y = cubef(ob0[5] * inv0);
        r.z = cubef(ob0[6] * inv0); r.w = cubef(ob0[7] * inv0);
        *(float4*)(dst0 + 4) = r;
        r.x = cubef(ob1[0] * inv1); r.y = cubef(ob1[1] * inv1);
        r.z = cubef(ob1[2] * inv1); r.w = cubef(ob1[3] * inv1);
        *(float4*)(dst1) = r;
        r.x = cubef(ob1[4] * inv1); r.y = cubef(ob1[5] * inv1);
        r.z = cubef(ob1[6] * inv1); r.w = cubef(ob1[7] * inv1);
        *(float4*)(dst1 + 4) = r;
    }
}

// ---------------- K4: out = cube(O3 @ proj_out + bias)  (M=4096, K=2048, N=128) ----------------
__global__ __launch_bounds__(256) void final_gemm(const float* __restrict__ O3,
                                                  const float* __restrict__ W,
                                                  const float* __restrict__ bias,
                                                  float* __restrict__ out) {
    __shared__ float Asub[16][36];     // [m][k], padded, 16B-aligned rows
    __shared__ float Bsub[32][128];    // [k][n]
    const int t = threadIdx.x;
    const int r0 = blockIdx.x * 16;
    const int y = t & 127;
    const int half = t >> 7;
    float acc[8];
    #pragma unroll
    for (int j = 0; j < 8; j++) acc[j] = 0.f;

    for (int kt = 0; kt < 2048; kt += 32) {
        #pragma unroll
        for (int i = 0; i < 2; i++) {
            int e = t + 256 * i;
            Asub[e >> 5][e & 31] = O3[(size_t)(r0 + (e >> 5)) * 2048 + kt + (e & 31)];
        }
        #pragma unroll
        for (int i = 0; i < 16; i++) {
            int e = t + 256 * i;
            Bsub[e >> 7][e & 127] = W[(size_t)(kt + (e >> 7)) * 128 + (e & 127)];
        }
        __syncthreads();
        #pragma unroll
        for (int k = 0; k < 32; k += 4) {
            float b0 = Bsub[k][y], b1 = Bsub[k + 1][y], b2 = Bsub[k + 2][y], b3 = Bsub[k + 3][y];
            #pragma unroll
            for (int j = 0; j < 8; j++) {
                float4 a = *(const float4*)&Asub[half * 8 + j][k];
                acc[j] += a.x * b0 + a.y * b1 + a.z * b2 + a.w * b3;
            }
        }
        __syncthreads();
    }
    float bb = bias[y];
    #pragma unroll
    for (int j = 0; j < 8; j++) {
        float u = acc[j] + bb;
        out[(size_t)(r0 + half * 8 + j) * 128 + y] = u * u * u;
    }
}

extern "C" void kernel_launch(void* const* d_in, const int* in_sizes, int n_in,
                              void* d_out, int out_size, void* d_ws, size_t ws_size,
                              hipStream_t stream) {
    const float* x        = (const float*)d_in[0];
    const int*   mask     = (const int*)d_in[1];     // bool -> int32 per harness convention
    const float* proj_in  = (const float*)d_in[2];
    const float* v_bias   = (const float*)d_in[3];
    const float* proj_out = (const float*)d_in[4];
    const float* po_bias  = (const float*)d_in[5];
    float* out = (float*)d_out;

    float* qkv = (float*)d_ws;                             // [4096, 6144]  (100.7 MB)
    float* O3  = qkv + (size_t)MROWS * NT;                 // [4096, 2048]  (33.6 MB)

    gemm_qkv<<<dim3(NT / 64, MROWS / 64), 256, 0, stream>>>(x, proj_in, qkv);
    rot_bias<<<(BZ * SQ * HH * 256) / 256, 256, 0, stream>>>(qkv, v_bias);
    attn_kernel<<<BZ * HH * (SQ / 32), 256, 0, stream>>>(qkv, mask, O3);
    final_gemm<<<MROWS / 16, 256, 0, stream>>>(O3, proj_out, po_bias, out);
}

// Round 3
// 1474.378 us; speedup vs baseline: 2.0344x; 2.0344x over previous
//
#include <hip/hip_runtime.h>
#include <math.h>

#define BZ 2
#define SQ 2048
#define DIN 1024
#define HH 16
#define DQK 128
#define DV 128
#define CPH 384          // 2*DQK + DV
#define NT (HH*CPH)      // 6144
#define MROWS (BZ*SQ)    // 4096

typedef unsigned short u16t;
typedef unsigned int u32t;
typedef __attribute__((ext_vector_type(8))) short bf16x8;
typedef __attribute__((ext_vector_type(4))) float f32x4;

__device__ __forceinline__ float cubef(float x) { return x * x * x; }

__device__ __forceinline__ u16t f2bf(float f) {          // fp32 -> bf16 RNE
    u32t b = __float_as_uint(f);
    b += 0x7FFFu + ((b >> 16) & 1u);
    return (u16t)(b >> 16);
}
__device__ __forceinline__ float bf2f(u16t u) { return __uint_as_float(((u32t)u) << 16); }
__device__ __forceinline__ u32t pk2(float a, float b) {
    return (u32t)f2bf(a) | ((u32t)f2bf(b) << 16);
}

// ---------------- K1: qkv = x @ proj_in  (M=4096, K=1024, N=6144) ----------------
__global__ __launch_bounds__(256) void gemm_qkv(const float* __restrict__ A,
                                                const float* __restrict__ Bw,
                                                float* __restrict__ C) {
    __shared__ float AsT[16][68];
    __shared__ float Bs[16][68];
    const int t = threadIdx.x;
    const int tx = t & 15, ty = t >> 4;
    const int colBase = blockIdx.x * 64;
    const int rowBase = blockIdx.y * 64;
    float acc[4][4];
    #pragma unroll
    for (int i = 0; i < 4; i++)
        #pragma unroll
        for (int j = 0; j < 4; j++) acc[i][j] = 0.f;

    for (int k0 = 0; k0 < DIN; k0 += 16) {
        #pragma unroll
        for (int i = 0; i < 4; i++) {
            int e = t + 256 * i;
            int r = e >> 4, c = e & 15;
            AsT[c][r] = A[(size_t)(rowBase + r) * DIN + k0 + c];
            int rb = e >> 6, cb = e & 63;
            Bs[rb][cb] = Bw[(size_t)(k0 + rb) * NT + colBase + cb];
        }
        __syncthreads();
        #pragma unroll
        for (int kk = 0; kk < 16; kk++) {
            float4 a = *(const float4*)&AsT[kk][4 * ty];
            float4 b = *(const float4*)&Bs[kk][4 * tx];
            acc[0][0] += a.x * b.x; acc[0][1] += a.x * b.y; acc[0][2] += a.x * b.z; acc[0][3] += a.x * b.w;
            acc[1][0] += a.y * b.x; acc[1][1] += a.y * b.y; acc[1][2] += a.y * b.z; acc[1][3] += a.y * b.w;
            acc[2][0] += a.z * b.x; acc[2][1] += a.z * b.y; acc[2][2] += a.z * b.z; acc[2][3] += a.z * b.w;
            acc[3][0] += a.w * b.x; acc[3][1] += a.w * b.y; acc[3][2] += a.w * b.z; acc[3][3] += a.w * b.w;
        }
        __syncthreads();
    }
    #pragma unroll
    for (int i = 0; i < 4; i++) {
        float4 r;
        r.x = acc[i][0]; r.y = acc[i][1]; r.z = acc[i][2]; r.w = acc[i][3];
        *(float4*)&C[(size_t)(rowBase + 4 * ty + i) * NT + colBase + 4 * tx] = r;
    }
}

// ---------------- K2: rotary on q,k; v -> (v+bias) split to bf16 hi/lo in place ----------------
__global__ __launch_bounds__(256) void rot_bias(float* __restrict__ qkv,
                                                const float* __restrict__ vbias) {
    const int bx = blockIdx.x;
    const int h = bx & 15;
    const int s = (bx >> 4) & 2047;
    const int z = bx >> 15;
    const int u = threadIdx.x;
    size_t base = ((size_t)((z * SQ + s) * HH + h)) * CPH;
    if (u < 128) {
        int j = u & 63;
        int off = (u < 64) ? 0 : 128;
        float f = expf(-0.14391156831212788f * (float)j);   // 10000^(-2j/128)
        float ang = (float)s * f;
        float sn, c;
        sincosf(ang, &sn, &c);
        float t1 = qkv[base + off + j];
        float t2 = qkv[base + off + j + 64];
        qkv[base + off + j]      = t1 * c - t2 * sn;
        qkv[base + off + j + 64] = t2 * c + t1 * sn;
    } else if (u < 192) {
        // one wave handles the 128 v dims; loads complete before stores (same wave)
        int j = u - 128;            // 0..63
        int d0 = 2 * j;
        float v0 = qkv[base + 256 + d0]     + vbias[h * 128 + d0];
        float v1 = qkv[base + 256 + d0 + 1] + vbias[h * 128 + d0 + 1];
        u16t h0 = f2bf(v0), h1 = f2bf(v1);
        u16t l0 = f2bf(v0 - bf2f(h0)), l1 = f2bf(v1 - bf2f(h1));
        u32t* vp = (u32t*)(qkv + base + 256);
        vp[j]      = (u32t)h0 | ((u32t)h1 << 16);   // hi(dim d) at u16 index d      (u16[0..127])
        vp[64 + j] = (u32t)l0 | ((u32t)l1 << 16);   // lo(dim d) at u16 index 128+d  (u16[128..255])
    }
}

// ---------------- K3: MFMA attention. block = (z,h, 32 queries), 4 waves ----------------
#define PADQ 136   // u16 stride q/k rows (bytes 272: 16B aligned, conflict-free frags)
#define PADV 40    // u16 stride vt rows (bytes 80: 16B aligned, conflict-free frags)
#define PADW 36    // f32 stride wl rows (bytes 144)
#define ATTSCALE 0.08838834764831845f

__global__ __launch_bounds__(256, 4) void attn_kernel(const float* __restrict__ qkv,
                                                      const int* __restrict__ mask,
                                                      float* __restrict__ O3) {
    const int blk = blockIdx.x;
    const int qt = blk & 63;
    const int h  = (blk >> 6) & 15;
    const int z  = blk >> 10;
    const int t  = threadIdx.x;
    const int lane = t & 63;
    const int wid  = t >> 6;
    const int quad = lane >> 4;
    const int l15  = lane & 15;
    const int m  = wid & 1;     // q-row 16-tile
    const int ng = wid >> 1;    // key 16-tile (QK) / d 64-half (PV)

    __shared__ __align__(16) u16t ks[32 * PADQ];       // K (and initially Q) bf16 [row][d]
    __shared__ __align__(16) u16t vth[128 * PADV];     // V^T hi bf16 [d][k]
    __shared__ __align__(16) u16t vtl[128 * PADV];     // V^T lo bf16 [d][k]
    __shared__ __align__(16) float wl[32 * PADW];      // P fp32 [q][k]
    __shared__ float dpart[2][32];
    __shared__ int qm[32], km[32];

    const int q0 = qt * 32;
    const int srow = t >> 3;          // 0..31
    const int sd0  = (t & 7) * 16;    // 0..112

    // ---- stage Q (bf16) into ks, read A-frags into registers ----
    {
        const float* src = qkv + ((size_t)(((z * SQ) + q0 + srow) * HH + h)) * CPH + sd0;
        float4 f0 = *(const float4*)(src);
        float4 f1 = *(const float4*)(src + 4);
        float4 f2 = *(const float4*)(src + 8);
        float4 f3 = *(const float4*)(src + 12);
        uint4 u0, u1;
        u0.x = pk2(f0.x, f0.y); u0.y = pk2(f0.z, f0.w); u0.z = pk2(f1.x, f1.y); u0.w = pk2(f1.z, f1.w);
        u1.x = pk2(f2.x, f2.y); u1.y = pk2(f2.z, f2.w); u1.z = pk2(f3.x, f3.y); u1.w = pk2(f3.z, f3.w);
        *(uint4*)&ks[srow * PADQ + sd0]     = u0;
        *(uint4*)&ks[srow * PADQ + sd0 + 8] = u1;
    }
    if (t < 32) qm[t] = mask[z * SQ + q0 + t];
    __syncthreads();
    bf16x8 qf[4];
    #pragma unroll
    for (int kk = 0; kk < 4; kk++)
        qf[kk] = *(const bf16x8*)&ks[(16 * m + l15) * PADQ + kk * 32 + quad * 8];

    f32x4 acc[4];
    #pragma unroll
    for (int i = 0; i < 4; i++) acc[i] = (f32x4){0.f, 0.f, 0.f, 0.f};
    float dsum[4] = {0.f, 0.f, 0.f, 0.f};

    const int dp = t & 63;            // d-pair index for V staging
    const int d2 = 2 * dp;
    const int kg = t >> 6;            // k-block 0..3
    const int k0v = kg * 8;

    for (int kt = 0; kt < SQ; kt += 32) {
        __syncthreads();   // prior-iter frag reads (and initial qf reads) done

        // ---- stage K tile as bf16 ----
        {
            const float* src = qkv + ((size_t)(((z * SQ) + kt + srow) * HH + h)) * CPH + 128 + sd0;
            float4 f0 = *(const float4*)(src);
            float4 f1 = *(const float4*)(src + 4);
            float4 f2 = *(const float4*)(src + 8);
            float4 f3 = *(const float4*)(src + 12);
            uint4 u0, u1;
            u0.x = pk2(f0.x, f0.y); u0.y = pk2(f0.z, f0.w); u0.z = pk2(f1.x, f1.y); u0.w = pk2(f1.z, f1.w);
            u1.x = pk2(f2.x, f2.y); u1.y = pk2(f2.z, f2.w); u1.z = pk2(f3.x, f3.y); u1.w = pk2(f3.z, f3.w);
            *(uint4*)&ks[srow * PADQ + sd0]     = u0;
            *(uint4*)&ks[srow * PADQ + sd0 + 8] = u1;
        }
        // ---- stage V^T hi/lo (register transpose of 8 keys x 2 dims) ----
        {
            const u16t* vp0 = (const u16t*)(qkv + ((size_t)(((z * SQ) + kt + k0v) * HH + h)) * CPH + 256);
            u32t hi[8], lo[8];
            #pragma unroll
            for (int j = 0; j < 8; j++) {
                const u16t* vp = vp0 + (size_t)j * (2 * HH * CPH);
                hi[j] = *(const u32t*)(vp + d2);        // hi(d2), hi(d2+1)
                lo[j] = *(const u32t*)(vp + 128 + d2);  // lo(d2), lo(d2+1)   [FIXED: was +256]
            }
            uint4 a, b;
            a.x = (hi[0] & 0xFFFFu) | (hi[1] << 16);
            a.y = (hi[2] & 0xFFFFu) | (hi[3] << 16);
            a.z = (hi[4] & 0xFFFFu) | (hi[5] << 16);
            a.w = (hi[6] & 0xFFFFu) | (hi[7] << 16);
            b.x = (hi[0] >> 16) | (hi[1] & 0xFFFF0000u);
            b.y = (hi[2] >> 16) | (hi[3] & 0xFFFF0000u);
            b.z = (hi[4] >> 16) | (hi[5] & 0xFFFF0000u);
            b.w = (hi[6] >> 16) | (hi[7] & 0xFFFF0000u);
            *(uint4*)&vth[d2 * PADV + k0v]       = a;
            *(uint4*)&vth[(d2 + 1) * PADV + k0v] = b;
            a.x = (lo[0] & 0xFFFFu) | (lo[1] << 16);
            a.y = (lo[2] & 0xFFFFu) | (lo[3] << 16);
            a.z = (lo[4] & 0xFFFFu) | (lo[5] << 16);
            a.w = (lo[6] & 0xFFFFu) | (lo[7] << 16);
            b.x = (lo[0] >> 16) | (lo[1] & 0xFFFF0000u);
            b.y = (lo[2] >> 16) | (lo[3] & 0xFFFF0000u);
            b.z = (lo[4] >> 16) | (lo[5] & 0xFFFF0000u);
            b.w = (lo[6] >> 16) | (lo[7] & 0xFFFF0000u);
            *(uint4*)&vtl[d2 * PADV + k0v]       = a;
            *(uint4*)&vtl[(d2 + 1) * PADV + k0v] = b;
        }
        if (t < 32) km[t] = mask[z * SQ + kt + t];
        __syncthreads();

        // ---- QK^T: wave computes S[16m.., 16ng..] ----
        f32x4 s4 = (f32x4){0.f, 0.f, 0.f, 0.f};
        #pragma unroll
        for (int kk = 0; kk < 4; kk++) {
            bf16x8 kf = *(const bf16x8*)&ks[(16 * ng + l15) * PADQ + kk * 32 + quad * 8];
            s4 = __builtin_amdgcn_mfma_f32_16x16x32_bf16(qf[kk], kf, s4, 0, 0, 0);
        }
        // ---- mask + exp (unnormalized), write P, accumulate denominator ----
        {
            int colm = km[16 * ng + l15];
            #pragma unroll
            for (int r = 0; r < 4; r++) {
                int row = 16 * m + 4 * quad + r;
                float w = (qm[row] | colm) ? 0.f : __expf(s4[r] * ATTSCALE);
                dsum[r] += w;
                wl[row * PADW + 16 * ng + l15] = w;
            }
        }
        __syncthreads();

        // ---- P·V: split P to bf16 hi/lo, 3 MFMAs per d-tile ----
        {
            const float* prow = &wl[(16 * m + l15) * PADW + quad * 8];
            float4 p0 = *(const float4*)(prow);
            float4 p1 = *(const float4*)(prow + 4);
            float pv[8] = {p0.x, p0.y, p0.z, p0.w, p1.x, p1.y, p1.z, p1.w};
            union { u16t u[8]; bf16x8 v; } ph, pl;
            #pragma unroll
            for (int e = 0; e < 8; e++) {
                u16t hh = f2bf(pv[e]);
                ph.u[e] = hh;
                pl.u[e] = f2bf(pv[e] - bf2f(hh));
            }
            #pragma unroll
            for (int i = 0; i < 4; i++) {
                int d = 64 * ng + 16 * i + l15;
                bf16x8 vh = *(const bf16x8*)&vth[d * PADV + quad * 8];
                bf16x8 vl = *(const bf16x8*)&vtl[d * PADV + quad * 8];
                acc[i] = __builtin_amdgcn_mfma_f32_16x16x32_bf16(ph.v, vh, acc[i], 0, 0, 0);
                acc[i] = __builtin_amdgcn_mfma_f32_16x16x32_bf16(ph.v, vl, acc[i], 0, 0, 0);
                acc[i] = __builtin_amdgcn_mfma_f32_16x16x32_bf16(pl.v, vh, acc[i], 0, 0, 0);
            }
        }
    }

    // ---- denominator: reduce over the 16 lanes of each quad, combine halves ----
    #pragma unroll
    for (int r = 0; r < 4; r++) {
        float v = dsum[r];
        v += __shfl_xor(v, 1);
        v += __shfl_xor(v, 2);
        v += __shfl_xor(v, 4);
        v += __shfl_xor(v, 8);
        dsum[r] = v;
    }
    if (l15 == 0) {
        #pragma unroll
        for (int r = 0; r < 4; r++) dpart[ng][16 * m + 4 * quad + r] = dsum[r];
    }
    __syncthreads();

    #pragma unroll
    for (int r = 0; r < 4; r++) {
        int row = 16 * m + 4 * quad + r;
        float den = dpart[0][row] + dpart[1][row];
        float inv = den > 0.f ? 1.f / den : 0.f;
        float* dst = O3 + ((size_t)(((z * SQ) + q0 + row) * HH + h)) * DV;
        #pragma unroll
        for (int i = 0; i < 4; i++) {
            float o = acc[i][r] * inv;
            dst[64 * ng + 16 * i + l15] = cubef(o);
        }
    }
}

// ---------------- K4: out = cube(O3 @ proj_out + bias)  (M=4096, K=2048, N=128) ----------------
__global__ __launch_bounds__(256) void final_gemm(const float* __restrict__ O3,
                                                  const float* __restrict__ W,
                                                  const float* __restrict__ bias,
                                                  float* __restrict__ out) {
    __shared__ float Asub[16][36];
    __shared__ float Bsub[32][128];
    const int t = threadIdx.x;
    const int r0 = blockIdx.x * 16;
    const int y = t & 127;
    const int half = t >> 7;
    float acc[8];
    #pragma unroll
    for (int j = 0; j < 8; j++) acc[j] = 0.f;

    for (int kt = 0; kt < 2048; kt += 32) {
        #pragma unroll
        for (int i = 0; i < 2; i++) {
            int e = t + 256 * i;
            Asub[e >> 5][e & 31] = O3[(size_t)(r0 + (e >> 5)) * 2048 + kt + (e & 31)];
        }
        #pragma unroll
        for (int i = 0; i < 16; i++) {
            int e = t + 256 * i;
            Bsub[e >> 7][e & 127] = W[(size_t)(kt + (e >> 7)) * 128 + (e & 127)];
        }
        __syncthreads();
        #pragma unroll
        for (int k = 0; k < 32; k += 4) {
            float b0 = Bsub[k][y], b1 = Bsub[k + 1][y], b2 = Bsub[k + 2][y], b3 = Bsub[k + 3][y];
            #pragma unroll
            for (int j = 0; j < 8; j++) {
                float4 a = *(const float4*)&Asub[half * 8 + j][k];
                acc[j] += a.x * b0 + a.y * b1 + a.z * b2 + a.w * b3;
            }
        }
        __syncthreads();
    }
    float bb = bias[y];
    #pragma unroll
    for (int j = 0; j < 8; j++) {
        float u = acc[j] + bb;
        out[(size_t)(r0 + half * 8 + j) * 128 + y] = u * u * u;
    }
}

extern "C" void kernel_launch(void* const* d_in, const int* in_sizes, int n_in,
                              void* d_out, int out_size, void* d_ws, size_t ws_size,
                              hipStream_t stream) {
    const float* x        = (const float*)d_in[0];
    const int*   mask     = (const int*)d_in[1];
    const float* proj_in  = (const float*)d_in[2];
    const float* v_bias   = (const float*)d_in[3];
    const float* proj_out = (const float*)d_in[4];
    const float* po_bias  = (const float*)d_in[5];
    float* out = (float*)d_out;

    float* qkv = (float*)d_ws;                 // [4096, 6144] fp32 (v slot rewritten as bf16 hi/lo)
    float* O3  = qkv + (size_t)MROWS * NT;     // [4096, 2048] fp32

    gemm_qkv<<<dim3(NT / 64, MROWS / 64), 256, 0, stream>>>(x, proj_in, qkv);
    rot_bias<<<BZ * SQ * HH, 256, 0, stream>>>(qkv, v_bias);
    attn_kernel<<<BZ * HH * (SQ / 32), 256, 0, stream>>>(qkv, mask, O3);
    final_gemm<<<MROWS / 16, 256, 0, stream>>>(O3, proj_out, po_bias, out);
}

// Round 4
// 1081.270 us; speedup vs baseline: 2.7740x; 1.3636x over previous
//
#include <hip/hip_runtime.h>
#include <math.h>

#define BZ 2
#define SQ 2048
#define DIN 1024
#define HH 16
#define DQK 128
#define DV 128
#define CPH 384          // 2*DQK + DV
#define NT (HH*CPH)      // 6144
#define MROWS (BZ*SQ)    // 4096

typedef unsigned short u16t;
typedef unsigned int u32t;
typedef __attribute__((ext_vector_type(8))) short bf16x8;
typedef __attribute__((ext_vector_type(4))) float f32x4;

__device__ __forceinline__ float cubef(float x) { return x * x * x; }

__device__ __forceinline__ u16t f2bf(float f) {          // fp32 -> bf16 RNE
    u32t b = __float_as_uint(f);
    b += 0x7FFFu + ((b >> 16) & 1u);
    return (u16t)(b >> 16);
}
__device__ __forceinline__ float bf2f(u16t u) { return __uint_as_float(((u32t)u) << 16); }
__device__ __forceinline__ u32t pk2(float a, float b) {
    return (u32t)f2bf(a) | ((u32t)f2bf(b) << 16);
}
// trunc-split pair: hi word = (trunc-bf16(f0), trunc-bf16(f1)); lo = trunc-bf16 of remainders
__device__ __forceinline__ void split2(float f0, float f1, u32t& hi, u32t& lo) {
    u32t u0 = __float_as_uint(f0), u1 = __float_as_uint(f1);
    u32t h0 = u0 & 0xFFFF0000u, h1 = u1 & 0xFFFF0000u;
    float r0 = f0 - __uint_as_float(h0);
    float r1 = f1 - __uint_as_float(h1);
    hi = (h0 >> 16) | h1;
    lo = (__float_as_uint(r0) >> 16) | (__float_as_uint(r1) & 0xFFFF0000u);
}

// ---------------- K0: proj_in [k][n] fp32 -> pTh/pTl [n][k] bf16 (trunc split) ----------------
__global__ __launch_bounds__(256) void split_transpose_w(const float* __restrict__ W,
                                                         u16t* __restrict__ Th,
                                                         u16t* __restrict__ Tl) {
    __shared__ float tile[64][68];
    const int n0 = blockIdx.x * 64;
    const int k0 = blockIdx.y * 64;
    const int t = threadIdx.x;
    {
        const int r = t >> 4, c = (t & 15) * 4;
        #pragma unroll
        for (int p = 0; p < 4; p++) {
            float4 v = *(const float4*)&W[(size_t)(k0 + r + p * 16) * NT + n0 + c];
            *(float4*)&tile[r + p * 16][c] = v;
        }
    }
    __syncthreads();
    const int nr = t >> 2;           // 0..63 output row (n)
    const int kc = (t & 3) * 16;     // k chunk base
    u32t hi[8], lo[8];
    #pragma unroll
    for (int j = 0; j < 8; j++) {
        float f0 = tile[kc + 2 * j][nr];
        float f1 = tile[kc + 2 * j + 1][nr];
        split2(f0, f1, hi[j], lo[j]);
    }
    size_t ob = (size_t)(n0 + nr) * DIN + k0 + kc;
    *(uint4*)&Th[ob]     = *(uint4*)&hi[0];
    *(uint4*)&Th[ob + 8] = *(uint4*)&hi[4];
    *(uint4*)&Tl[ob]     = *(uint4*)&lo[0];
    *(uint4*)&Tl[ob + 8] = *(uint4*)&lo[4];
}

// ---------------- K1: qkv = x @ proj_in via split-bf16 MFMA (M=4096,K=1024,N=6144) ----------------
__global__ __launch_bounds__(256) void gemm_qkv_mfma(const float* __restrict__ A,
                                                     const u16t* __restrict__ Bh,
                                                     const u16t* __restrict__ Bl,
                                                     float* __restrict__ C) {
    // LDS: [k-octet 0..3][col 0..127][8 bf16] per array — frag reads & stage writes conflict-free
    __shared__ __align__(16) u16t as_h[4 * 128 * 8];
    __shared__ __align__(16) u16t as_l[4 * 128 * 8];
    __shared__ __align__(16) u16t bs_h[4 * 128 * 8];
    __shared__ __align__(16) u16t bs_l[4 * 128 * 8];

    const int t = threadIdx.x;
    const int lane = t & 63, wid = t >> 6;
    const int quad = lane >> 4, l15 = lane & 15;
    const int wm = (wid & 1) * 64;
    const int wn = (wid >> 1) * 64;
    const int rowBase = blockIdx.y * 128;
    const int colBase = blockIdx.x * 128;
    const int sm = t & 127;          // staging col (m for A, n for B)
    const int skh = t >> 7;          // k-half (16 elems)

    f32x4 acc[4][4];
    #pragma unroll
    for (int i = 0; i < 4; i++)
        #pragma unroll
        for (int j = 0; j < 4; j++) acc[i][j] = (f32x4){0.f, 0.f, 0.f, 0.f};

    const float* aPtr  = A  + (size_t)(rowBase + sm) * DIN + skh * 16;
    const u16t*  bhPtr = Bh + (size_t)(colBase + sm) * DIN + skh * 16;
    const u16t*  blPtr = Bl + (size_t)(colBase + sm) * DIN + skh * 16;
    u16t* awh = &as_h[(skh * 2) * 1024 + sm * 8];
    u16t* awl = &as_l[(skh * 2) * 1024 + sm * 8];
    u16t* bwh = &bs_h[(skh * 2) * 1024 + sm * 8];
    u16t* bwl = &bs_l[(skh * 2) * 1024 + sm * 8];

    for (int k0 = 0; k0 < DIN; k0 += 32) {
        // global loads (off-LDS; overlap prior MFMA)
        float4 a0 = *(const float4*)(aPtr + k0);
        float4 a1 = *(const float4*)(aPtr + k0 + 4);
        float4 a2 = *(const float4*)(aPtr + k0 + 8);
        float4 a3 = *(const float4*)(aPtr + k0 + 12);
        uint4 bh0 = *(const uint4*)(bhPtr + k0);
        uint4 bh1 = *(const uint4*)(bhPtr + k0 + 8);
        uint4 bl0 = *(const uint4*)(blPtr + k0);
        uint4 bl1 = *(const uint4*)(blPtr + k0 + 8);
        uint4 ah0, ah1, al0, al1;
        split2(a0.x, a0.y, ah0.x, al0.x);
        split2(a0.z, a0.w, ah0.y, al0.y);
        split2(a1.x, a1.y, ah0.z, al0.z);
        split2(a1.z, a1.w, ah0.w, al0.w);
        split2(a2.x, a2.y, ah1.x, al1.x);
        split2(a2.z, a2.w, ah1.y, al1.y);
        split2(a3.x, a3.y, ah1.z, al1.z);
        split2(a3.z, a3.w, ah1.w, al1.w);

        __syncthreads();   // prior-iter frag reads complete
        *(uint4*)(awh)        = ah0;
        *(uint4*)(awh + 1024) = ah1;
        *(uint4*)(awl)        = al0;
        *(uint4*)(awl + 1024) = al1;
        *(uint4*)(bwh)        = bh0;
        *(uint4*)(bwh + 1024) = bh1;
        *(uint4*)(bwl)        = bl0;
        *(uint4*)(bwl + 1024) = bl1;
        __syncthreads();

        bf16x8 ah[4], al[4], bh[4], bl[4];
        #pragma unroll
        for (int mt = 0; mt < 4; mt++) {
            int off = quad * 1024 + (wm + mt * 16 + l15) * 8;
            ah[mt] = *(const bf16x8*)&as_h[off];
            al[mt] = *(const bf16x8*)&as_l[off];
        }
        #pragma unroll
        for (int nt = 0; nt < 4; nt++) {
            int off = quad * 1024 + (wn + nt * 16 + l15) * 8;
            bh[nt] = *(const bf16x8*)&bs_h[off];
            bl[nt] = *(const bf16x8*)&bs_l[off];
        }
        #pragma unroll
        for (int mt = 0; mt < 4; mt++)
            #pragma unroll
            for (int nt = 0; nt < 4; nt++) {
                acc[mt][nt] = __builtin_amdgcn_mfma_f32_16x16x32_bf16(ah[mt], bh[nt], acc[mt][nt], 0, 0, 0);
                acc[mt][nt] = __builtin_amdgcn_mfma_f32_16x16x32_bf16(ah[mt], bl[nt], acc[mt][nt], 0, 0, 0);
                acc[mt][nt] = __builtin_amdgcn_mfma_f32_16x16x32_bf16(al[mt], bh[nt], acc[mt][nt], 0, 0, 0);
            }
    }

    #pragma unroll
    for (int mt = 0; mt < 4; mt++)
        #pragma unroll
        for (int nt = 0; nt < 4; nt++) {
            int col = colBase + wn + nt * 16 + l15;
            #pragma unroll
            for (int r = 0; r < 4; r++) {
                int row = rowBase + wm + mt * 16 + quad * 4 + r;
                C[(size_t)row * NT + col] = acc[mt][nt][r];
            }
        }
}

// ---------------- K2: rotary on q,k; v -> (v+bias) split to bf16 hi/lo in place ----------------
__global__ __launch_bounds__(256) void rot_bias(float* __restrict__ qkv,
                                                const float* __restrict__ vbias) {
    const int bx = blockIdx.x;
    const int h = bx & 15;
    const int s = (bx >> 4) & 2047;
    const int z = bx >> 15;
    const int u = threadIdx.x;
    size_t base = ((size_t)((z * SQ + s) * HH + h)) * CPH;
    if (u < 128) {
        int j = u & 63;
        int off = (u < 64) ? 0 : 128;
        float f = expf(-0.14391156831212788f * (float)j);   // 10000^(-2j/128)
        float ang = (float)s * f;
        float sn, c;
        sincosf(ang, &sn, &c);
        float t1 = qkv[base + off + j];
        float t2 = qkv[base + off + j + 64];
        qkv[base + off + j]      = t1 * c - t2 * sn;
        qkv[base + off + j + 64] = t2 * c + t1 * sn;
    } else if (u < 192) {
        int j = u - 128;            // 0..63
        int d0 = 2 * j;
        float v0 = qkv[base + 256 + d0]     + vbias[h * 128 + d0];
        float v1 = qkv[base + 256 + d0 + 1] + vbias[h * 128 + d0 + 1];
        u16t h0 = f2bf(v0), h1 = f2bf(v1);
        u16t l0 = f2bf(v0 - bf2f(h0)), l1 = f2bf(v1 - bf2f(h1));
        u32t* vp = (u32t*)(qkv + base + 256);
        vp[j]      = (u32t)h0 | ((u32t)h1 << 16);   // hi(dim d) at u16 index d
        vp[64 + j] = (u32t)l0 | ((u32t)l1 << 16);   // lo(dim d) at u16 index 128+d
    }
}

// ---------------- K3: MFMA attention. block = (z,h, 32 queries), 4 waves ----------------
#define PADQ 136
#define PADV 40
#define PADW 36
#define ATTSCALE 0.08838834764831845f

__global__ __launch_bounds__(256, 4) void attn_kernel(const float* __restrict__ qkv,
                                                      const int* __restrict__ mask,
                                                      float* __restrict__ O3) {
    const int blk = blockIdx.x;
    const int qt = blk & 63;
    const int h  = (blk >> 6) & 15;
    const int z  = blk >> 10;
    const int t  = threadIdx.x;
    const int lane = t & 63;
    const int wid  = t >> 6;
    const int quad = lane >> 4;
    const int l15  = lane & 15;
    const int m  = wid & 1;
    const int ng = wid >> 1;

    __shared__ __align__(16) u16t ks[32 * PADQ];
    __shared__ __align__(16) u16t vth[128 * PADV];
    __shared__ __align__(16) u16t vtl[128 * PADV];
    __shared__ __align__(16) float wl[32 * PADW];
    __shared__ float dpart[2][32];
    __shared__ int qm[32], km[32];

    const int q0 = qt * 32;
    const int srow = t >> 3;
    const int sd0  = (t & 7) * 16;

    {
        const float* src = qkv + ((size_t)(((z * SQ) + q0 + srow) * HH + h)) * CPH + sd0;
        float4 f0 = *(const float4*)(src);
        float4 f1 = *(const float4*)(src + 4);
        float4 f2 = *(const float4*)(src + 8);
        float4 f3 = *(const float4*)(src + 12);
        uint4 u0, u1;
        u0.x = pk2(f0.x, f0.y); u0.y = pk2(f0.z, f0.w); u0.z = pk2(f1.x, f1.y); u0.w = pk2(f1.z, f1.w);
        u1.x = pk2(f2.x, f2.y); u1.y = pk2(f2.z, f2.w); u1.z = pk2(f3.x, f3.y); u1.w = pk2(f3.z, f3.w);
        *(uint4*)&ks[srow * PADQ + sd0]     = u0;
        *(uint4*)&ks[srow * PADQ + sd0 + 8] = u1;
    }
    if (t < 32) qm[t] = mask[z * SQ + q0 + t];
    __syncthreads();
    bf16x8 qf[4];
    #pragma unroll
    for (int kk = 0; kk < 4; kk++)
        qf[kk] = *(const bf16x8*)&ks[(16 * m + l15) * PADQ + kk * 32 + quad * 8];

    f32x4 acc[4];
    #pragma unroll
    for (int i = 0; i < 4; i++) acc[i] = (f32x4){0.f, 0.f, 0.f, 0.f};
    float dsum[4] = {0.f, 0.f, 0.f, 0.f};

    const int dp = t & 63;
    const int d2 = 2 * dp;
    const int kg = t >> 6;
    const int k0v = kg * 8;

    for (int kt = 0; kt < SQ; kt += 32) {
        __syncthreads();

        {
            const float* src = qkv + ((size_t)(((z * SQ) + kt + srow) * HH + h)) * CPH + 128 + sd0;
            float4 f0 = *(const float4*)(src);
            float4 f1 = *(const float4*)(src + 4);
            float4 f2 = *(const float4*)(src + 8);
            float4 f3 = *(const float4*)(src + 12);
            uint4 u0, u1;
            u0.x = pk2(f0.x, f0.y); u0.y = pk2(f0.z, f0.w); u0.z = pk2(f1.x, f1.y); u0.w = pk2(f1.z, f1.w);
            u1.x = pk2(f2.x, f2.y); u1.y = pk2(f2.z, f2.w); u1.z = pk2(f3.x, f3.y); u1.w = pk2(f3.z, f3.w);
            *(uint4*)&ks[srow * PADQ + sd0]     = u0;
            *(uint4*)&ks[srow * PADQ + sd0 + 8] = u1;
        }
        {
            const u16t* vp0 = (const u16t*)(qkv + ((size_t)(((z * SQ) + kt + k0v) * HH + h)) * CPH + 256);
            u32t hi[8], lo[8];
            #pragma unroll
            for (int j = 0; j < 8; j++) {
                const u16t* vp = vp0 + (size_t)j * (2 * HH * CPH);
                hi[j] = *(const u32t*)(vp + d2);
                lo[j] = *(const u32t*)(vp + 128 + d2);
            }
            uint4 a, b;
            a.x = (hi[0] & 0xFFFFu) | (hi[1] << 16);
            a.y = (hi[2] & 0xFFFFu) | (hi[3] << 16);
            a.z = (hi[4] & 0xFFFFu) | (hi[5] << 16);
            a.w = (hi[6] & 0xFFFFu) | (hi[7] << 16);
            b.x = (hi[0] >> 16) | (hi[1] & 0xFFFF0000u);
            b.y = (hi[2] >> 16) | (hi[3] & 0xFFFF0000u);
            b.z = (hi[4] >> 16) | (hi[5] & 0xFFFF0000u);
            b.w = (hi[6] >> 16) | (hi[7] & 0xFFFF0000u);
            *(uint4*)&vth[d2 * PADV + k0v]       = a;
            *(uint4*)&vth[(d2 + 1) * PADV + k0v] = b;
            a.x = (lo[0] & 0xFFFFu) | (lo[1] << 16);
            a.y = (lo[2] & 0xFFFFu) | (lo[3] << 16);
            a.z = (lo[4] & 0xFFFFu) | (lo[5] << 16);
            a.w = (lo[6] & 0xFFFFu) | (lo[7] << 16);
            b.x = (lo[0] >> 16) | (lo[1] & 0xFFFF0000u);
            b.y = (lo[2] >> 16) | (lo[3] & 0xFFFF0000u);
            b.z = (lo[4] >> 16) | (lo[5] & 0xFFFF0000u);
            b.w = (lo[6] >> 16) | (lo[7] & 0xFFFF0000u);
            *(uint4*)&vtl[d2 * PADV + k0v]       = a;
            *(uint4*)&vtl[(d2 + 1) * PADV + k0v] = b;
        }
        if (t < 32) km[t] = mask[z * SQ + kt + t];
        __syncthreads();

        f32x4 s4 = (f32x4){0.f, 0.f, 0.f, 0.f};
        #pragma unroll
        for (int kk = 0; kk < 4; kk++) {
            bf16x8 kf = *(const bf16x8*)&ks[(16 * ng + l15) * PADQ + kk * 32 + quad * 8];
            s4 = __builtin_amdgcn_mfma_f32_16x16x32_bf16(qf[kk], kf, s4, 0, 0, 0);
        }
        {
            int colm = km[16 * ng + l15];
            #pragma unroll
            for (int r = 0; r < 4; r++) {
                int row = 16 * m + 4 * quad + r;
                float w = (qm[row] | colm) ? 0.f : __expf(s4[r] * ATTSCALE);
                dsum[r] += w;
                wl[row * PADW + 16 * ng + l15] = w;
            }
        }
        __syncthreads();

        {
            const float* prow = &wl[(16 * m + l15) * PADW + quad * 8];
            float4 p0 = *(const float4*)(prow);
            float4 p1 = *(const float4*)(prow + 4);
            float pv[8] = {p0.x, p0.y, p0.z, p0.w, p1.x, p1.y, p1.z, p1.w};
            union { u16t u[8]; bf16x8 v; } ph, pl;
            #pragma unroll
            for (int e = 0; e < 8; e++) {
                u16t hh = f2bf(pv[e]);
                ph.u[e] = hh;
                pl.u[e] = f2bf(pv[e] - bf2f(hh));
            }
            #pragma unroll
            for (int i = 0; i < 4; i++) {
                int d = 64 * ng + 16 * i + l15;
                bf16x8 vh = *(const bf16x8*)&vth[d * PADV + quad * 8];
                bf16x8 vl = *(const bf16x8*)&vtl[d * PADV + quad * 8];
                acc[i] = __builtin_amdgcn_mfma_f32_16x16x32_bf16(ph.v, vh, acc[i], 0, 0, 0);
                acc[i] = __builtin_amdgcn_mfma_f32_16x16x32_bf16(ph.v, vl, acc[i], 0, 0, 0);
                acc[i] = __builtin_amdgcn_mfma_f32_16x16x32_bf16(pl.v, vh, acc[i], 0, 0, 0);
            }
        }
    }

    #pragma unroll
    for (int r = 0; r < 4; r++) {
        float v = dsum[r];
        v += __shfl_xor(v, 1);
        v += __shfl_xor(v, 2);
        v += __shfl_xor(v, 4);
        v += __shfl_xor(v, 8);
        dsum[r] = v;
    }
    if (l15 == 0) {
        #pragma unroll
        for (int r = 0; r < 4; r++) dpart[ng][16 * m + 4 * quad + r] = dsum[r];
    }
    __syncthreads();

    #pragma unroll
    for (int r = 0; r < 4; r++) {
        int row = 16 * m + 4 * quad + r;
        float den = dpart[0][row] + dpart[1][row];
        float inv = den > 0.f ? 1.f / den : 0.f;
        float* dst = O3 + ((size_t)(((z * SQ) + q0 + row) * HH + h)) * DV;
        #pragma unroll
        for (int i = 0; i < 4; i++) {
            float o = acc[i][r] * inv;
            dst[64 * ng + 16 * i + l15] = cubef(o);
        }
    }
}

// ---------------- K4: out = cube(O3 @ proj_out + bias)  (M=4096, K=2048, N=128) ----------------
__global__ __launch_bounds__(256) void final_gemm(const float* __restrict__ O3,
                                                  const float* __restrict__ W,
                                                  const float* __restrict__ bias,
                                                  float* __restrict__ out) {
    __shared__ float Asub[16][36];
    __shared__ float Bsub[32][128];
    const int t = threadIdx.x;
    const int r0 = blockIdx.x * 16;
    const int y = t & 127;
    const int half = t >> 7;
    float acc[8];
    #pragma unroll
    for (int j = 0; j < 8; j++) acc[j] = 0.f;

    for (int kt = 0; kt < 2048; kt += 32) {
        #pragma unroll
        for (int i = 0; i < 2; i++) {
            int e = t + 256 * i;
            Asub[e >> 5][e & 31] = O3[(size_t)(r0 + (e >> 5)) * 2048 + kt + (e & 31)];
        }
        #pragma unroll
        for (int i = 0; i < 16; i++) {
            int e = t + 256 * i;
            Bsub[e >> 7][e & 127] = W[(size_t)(kt + (e >> 7)) * 128 + (e & 127)];
        }
        __syncthreads();
        #pragma unroll
        for (int k = 0; k < 32; k += 4) {
            float b0 = Bsub[k][y], b1 = Bsub[k + 1][y], b2 = Bsub[k + 2][y], b3 = Bsub[k + 3][y];
            #pragma unroll
            for (int j = 0; j < 8; j++) {
                float4 a = *(const float4*)&Asub[half * 8 + j][k];
                acc[j] += a.x * b0 + a.y * b1 + a.z * b2 + a.w * b3;
            }
        }
        __syncthreads();
    }
    float bb = bias[y];
    #pragma unroll
    for (int j = 0; j < 8; j++) {
        float u = acc[j] + bb;
        out[(size_t)(r0 + half * 8 + j) * 128 + y] = u * u * u;
    }
}

extern "C" void kernel_launch(void* const* d_in, const int* in_sizes, int n_in,
                              void* d_out, int out_size, void* d_ws, size_t ws_size,
                              hipStream_t stream) {
    const float* x        = (const float*)d_in[0];
    const int*   mask     = (const int*)d_in[1];
    const float* proj_in  = (const float*)d_in[2];
    const float* v_bias   = (const float*)d_in[3];
    const float* proj_out = (const float*)d_in[4];
    const float* po_bias  = (const float*)d_in[5];
    float* out = (float*)d_out;

    float* qkv = (float*)d_ws;                 // [4096, 6144] fp32
    float* O3  = qkv + (size_t)MROWS * NT;     // [4096, 2048] fp32 (33.6 MB)
    // pT lives in the O3 slot: dead before attn writes O3 (stream-ordered)
    u16t* pTh = (u16t*)O3;                     // [6144,1024] bf16 (12.6 MB)
    u16t* pTl = pTh + (size_t)NT * DIN;        // [6144,1024] bf16 (12.6 MB)

    split_transpose_w<<<dim3(NT / 64, DIN / 64), 256, 0, stream>>>(proj_in, pTh, pTl);
    gemm_qkv_mfma<<<dim3(NT / 128, MROWS / 128), 256, 0, stream>>>(x, pTh, pTl, qkv);
    rot_bias<<<BZ * SQ * HH, 256, 0, stream>>>(qkv, v_bias);
    attn_kernel<<<BZ * HH * (SQ / 32), 256, 0, stream>>>(qkv, mask, O3);
    final_gemm<<<MROWS / 16, 256, 0, stream>>>(O3, proj_out, po_bias, out);
}

// Round 5
// 671.799 us; speedup vs baseline: 4.4648x; 1.6095x over previous
//
#include <hip/hip_runtime.h>
#include <math.h>

#define BZ 2
#define SQ 2048
#define DIN 1024
#define HH 16
#define DQK 128
#define DV 128
#define CPH 384          // 2*DQK + DV
#define NT (HH*CPH)      // 6144
#define MROWS (BZ*SQ)    // 4096
#define KOUT 2048        // K of final gemm
#define KSPLIT 8

typedef unsigned short u16t;
typedef unsigned int u32t;
typedef __attribute__((ext_vector_type(8))) short bf16x8;
typedef __attribute__((ext_vector_type(4))) float f32x4;

__device__ __forceinline__ float cubef(float x) { return x * x * x; }

__device__ __forceinline__ u16t f2bf(float f) {          // fp32 -> bf16 RNE
    u32t b = __float_as_uint(f);
    b += 0x7FFFu + ((b >> 16) & 1u);
    return (u16t)(b >> 16);
}
__device__ __forceinline__ float bf2f(u16t u) { return __uint_as_float(((u32t)u) << 16); }
__device__ __forceinline__ u32t pk2(float a, float b) {
    return (u32t)f2bf(a) | ((u32t)f2bf(b) << 16);
}
// trunc-split pair: hi word = (trunc-bf16(f0), trunc-bf16(f1)); lo = trunc-bf16 of remainders
__device__ __forceinline__ void split2(float f0, float f1, u32t& hi, u32t& lo) {
    u32t u0 = __float_as_uint(f0), u1 = __float_as_uint(f1);
    u32t h0 = u0 & 0xFFFF0000u, h1 = u1 & 0xFFFF0000u;
    float r0 = f0 - __uint_as_float(h0);
    float r1 = f1 - __uint_as_float(h1);
    hi = (h0 >> 16) | h1;
    lo = (__float_as_uint(r0) >> 16) | (__float_as_uint(r1) & 0xFFFF0000u);
}

// ---------------- K0a: proj_in [k][n](n=NT) fp32 -> pTh/pTl [n][k](k=DIN) bf16 ----------------
__global__ __launch_bounds__(256) void split_transpose_w(const float* __restrict__ W,
                                                         u16t* __restrict__ Th,
                                                         u16t* __restrict__ Tl) {
    __shared__ float tile[64][68];
    const int n0 = blockIdx.x * 64;
    const int k0 = blockIdx.y * 64;
    const int t = threadIdx.x;
    {
        const int r = t >> 4, c = (t & 15) * 4;
        #pragma unroll
        for (int p = 0; p < 4; p++) {
            float4 v = *(const float4*)&W[(size_t)(k0 + r + p * 16) * NT + n0 + c];
            *(float4*)&tile[r + p * 16][c] = v;
        }
    }
    __syncthreads();
    const int nr = t >> 2;
    const int kc = (t & 3) * 16;
    u32t hi[8], lo[8];
    #pragma unroll
    for (int j = 0; j < 8; j++) {
        float f0 = tile[kc + 2 * j][nr];
        float f1 = tile[kc + 2 * j + 1][nr];
        split2(f0, f1, hi[j], lo[j]);
    }
    size_t ob = (size_t)(n0 + nr) * DIN + k0 + kc;
    *(uint4*)&Th[ob]     = *(uint4*)&hi[0];
    *(uint4*)&Th[ob + 8] = *(uint4*)&hi[4];
    *(uint4*)&Tl[ob]     = *(uint4*)&lo[0];
    *(uint4*)&Tl[ob + 8] = *(uint4*)&lo[4];
}

// ---------------- K0b: proj_out [k][y](y=128,k=2048) fp32 -> WTh/WTl [y][k] bf16 ----------------
__global__ __launch_bounds__(256) void split_transpose_w2(const float* __restrict__ W,
                                                          u16t* __restrict__ Th,
                                                          u16t* __restrict__ Tl) {
    __shared__ float tile[64][68];
    const int n0 = blockIdx.x * 64;     // y
    const int k0 = blockIdx.y * 64;     // k
    const int t = threadIdx.x;
    {
        const int r = t >> 4, c = (t & 15) * 4;
        #pragma unroll
        for (int p = 0; p < 4; p++) {
            float4 v = *(const float4*)&W[(size_t)(k0 + r + p * 16) * 128 + n0 + c];
            *(float4*)&tile[r + p * 16][c] = v;
        }
    }
    __syncthreads();
    const int nr = t >> 2;
    const int kc = (t & 3) * 16;
    u32t hi[8], lo[8];
    #pragma unroll
    for (int j = 0; j < 8; j++) {
        float f0 = tile[kc + 2 * j][nr];
        float f1 = tile[kc + 2 * j + 1][nr];
        split2(f0, f1, hi[j], lo[j]);
    }
    size_t ob = (size_t)(n0 + nr) * KOUT + k0 + kc;
    *(uint4*)&Th[ob]     = *(uint4*)&hi[0];
    *(uint4*)&Th[ob + 8] = *(uint4*)&hi[4];
    *(uint4*)&Tl[ob]     = *(uint4*)&lo[0];
    *(uint4*)&Tl[ob + 8] = *(uint4*)&lo[4];
}

// ---------------- K1: qkv = x @ proj_in via split-bf16 MFMA (M=4096,K=1024,N=6144) ----------------
__global__ __launch_bounds__(256) void gemm_qkv_mfma(const float* __restrict__ A,
                                                     const u16t* __restrict__ Bh,
                                                     const u16t* __restrict__ Bl,
                                                     float* __restrict__ C) {
    __shared__ __align__(16) u16t as_h[4 * 128 * 8];
    __shared__ __align__(16) u16t as_l[4 * 128 * 8];
    __shared__ __align__(16) u16t bs_h[4 * 128 * 8];
    __shared__ __align__(16) u16t bs_l[4 * 128 * 8];

    const int t = threadIdx.x;
    const int lane = t & 63, wid = t >> 6;
    const int quad = lane >> 4, l15 = lane & 15;
    const int wm = (wid & 1) * 64;
    const int wn = (wid >> 1) * 64;
    const int rowBase = blockIdx.y * 128;
    const int colBase = blockIdx.x * 128;
    const int sm = t & 127;
    const int skh = t >> 7;

    f32x4 acc[4][4];
    #pragma unroll
    for (int i = 0; i < 4; i++)
        #pragma unroll
        for (int j = 0; j < 4; j++) acc[i][j] = (f32x4){0.f, 0.f, 0.f, 0.f};

    const float* aPtr  = A  + (size_t)(rowBase + sm) * DIN + skh * 16;
    const u16t*  bhPtr = Bh + (size_t)(colBase + sm) * DIN + skh * 16;
    const u16t*  blPtr = Bl + (size_t)(colBase + sm) * DIN + skh * 16;
    u16t* awh = &as_h[(skh * 2) * 1024 + sm * 8];
    u16t* awl = &as_l[(skh * 2) * 1024 + sm * 8];
    u16t* bwh = &bs_h[(skh * 2) * 1024 + sm * 8];
    u16t* bwl = &bs_l[(skh * 2) * 1024 + sm * 8];

    for (int k0 = 0; k0 < DIN; k0 += 32) {
        float4 a0 = *(const float4*)(aPtr + k0);
        float4 a1 = *(const float4*)(aPtr + k0 + 4);
        float4 a2 = *(const float4*)(aPtr + k0 + 8);
        float4 a3 = *(const float4*)(aPtr + k0 + 12);
        uint4 bh0 = *(const uint4*)(bhPtr + k0);
        uint4 bh1 = *(const uint4*)(bhPtr + k0 + 8);
        uint4 bl0 = *(const uint4*)(blPtr + k0);
        uint4 bl1 = *(const uint4*)(blPtr + k0 + 8);
        uint4 ah0, ah1, al0, al1;
        split2(a0.x, a0.y, ah0.x, al0.x);
        split2(a0.z, a0.w, ah0.y, al0.y);
        split2(a1.x, a1.y, ah0.z, al0.z);
        split2(a1.z, a1.w, ah0.w, al0.w);
        split2(a2.x, a2.y, ah1.x, al1.x);
        split2(a2.z, a2.w, ah1.y, al1.y);
        split2(a3.x, a3.y, ah1.z, al1.z);
        split2(a3.z, a3.w, ah1.w, al1.w);

        __syncthreads();
        *(uint4*)(awh)        = ah0;
        *(uint4*)(awh + 1024) = ah1;
        *(uint4*)(awl)        = al0;
        *(uint4*)(awl + 1024) = al1;
        *(uint4*)(bwh)        = bh0;
        *(uint4*)(bwh + 1024) = bh1;
        *(uint4*)(bwl)        = bl0;
        *(uint4*)(bwl + 1024) = bl1;
        __syncthreads();

        bf16x8 ah[4], al[4], bh[4], bl[4];
        #pragma unroll
        for (int mt = 0; mt < 4; mt++) {
            int off = quad * 1024 + (wm + mt * 16 + l15) * 8;
            ah[mt] = *(const bf16x8*)&as_h[off];
            al[mt] = *(const bf16x8*)&as_l[off];
        }
        #pragma unroll
        for (int nt = 0; nt < 4; nt++) {
            int off = quad * 1024 + (wn + nt * 16 + l15) * 8;
            bh[nt] = *(const bf16x8*)&bs_h[off];
            bl[nt] = *(const bf16x8*)&bs_l[off];
        }
        #pragma unroll
        for (int mt = 0; mt < 4; mt++)
            #pragma unroll
            for (int nt = 0; nt < 4; nt++) {
                acc[mt][nt] = __builtin_amdgcn_mfma_f32_16x16x32_bf16(ah[mt], bh[nt], acc[mt][nt], 0, 0, 0);
                acc[mt][nt] = __builtin_amdgcn_mfma_f32_16x16x32_bf16(ah[mt], bl[nt], acc[mt][nt], 0, 0, 0);
                acc[mt][nt] = __builtin_amdgcn_mfma_f32_16x16x32_bf16(al[mt], bh[nt], acc[mt][nt], 0, 0, 0);
            }
    }

    #pragma unroll
    for (int mt = 0; mt < 4; mt++)
        #pragma unroll
        for (int nt = 0; nt < 4; nt++) {
            int col = colBase + wn + nt * 16 + l15;
            #pragma unroll
            for (int r = 0; r < 4; r++) {
                int row = rowBase + wm + mt * 16 + quad * 4 + r;
                C[(size_t)row * NT + col] = acc[mt][nt][r];
            }
        }
}

// ---------------- K2: rotary on q,k; v -> (v+bias) split to bf16 hi/lo in place ----------------
__global__ __launch_bounds__(256) void rot_bias(float* __restrict__ qkv,
                                                const float* __restrict__ vbias) {
    const int bx = blockIdx.x;
    const int h = bx & 15;
    const int s = (bx >> 4) & 2047;
    const int z = bx >> 15;
    const int u = threadIdx.x;
    size_t base = ((size_t)((z * SQ + s) * HH + h)) * CPH;
    if (u < 128) {
        int j = u & 63;
        int off = (u < 64) ? 0 : 128;
        float f = expf(-0.14391156831212788f * (float)j);   // 10000^(-2j/128)
        float ang = (float)s * f;
        float sn, c;
        sincosf(ang, &sn, &c);
        float t1 = qkv[base + off + j];
        float t2 = qkv[base + off + j + 64];
        qkv[base + off + j]      = t1 * c - t2 * sn;
        qkv[base + off + j + 64] = t2 * c + t1 * sn;
    } else if (u < 192) {
        int j = u - 128;            // 0..63
        int d0 = 2 * j;
        float v0 = qkv[base + 256 + d0]     + vbias[h * 128 + d0];
        float v1 = qkv[base + 256 + d0 + 1] + vbias[h * 128 + d0 + 1];
        u16t h0 = f2bf(v0), h1 = f2bf(v1);
        u16t l0 = f2bf(v0 - bf2f(h0)), l1 = f2bf(v1 - bf2f(h1));
        u32t* vp = (u32t*)(qkv + base + 256);
        vp[j]      = (u32t)h0 | ((u32t)h1 << 16);   // hi(dim d) at u16 index d
        vp[64 + j] = (u32t)l0 | ((u32t)l1 << 16);   // lo(dim d) at u16 index 128+d
    }
}

// ---------------- K3: MFMA attention. block = (z,h, 32 queries), 4 waves ----------------
#define PADQ 136
#define PADV 40
#define PADW 36
#define ATTSCALE 0.08838834764831845f

__global__ __launch_bounds__(256, 4) void attn_kernel(const float* __restrict__ qkv,
                                                      const int* __restrict__ mask,
                                                      float* __restrict__ O3) {
    const int blk = blockIdx.x;
    const int qt = blk & 63;
    const int h  = (blk >> 6) & 15;
    const int z  = blk >> 10;
    const int t  = threadIdx.x;
    const int lane = t & 63;
    const int wid  = t >> 6;
    const int quad = lane >> 4;
    const int l15  = lane & 15;
    const int m  = wid & 1;
    const int ng = wid >> 1;

    __shared__ __align__(16) u16t ks[32 * PADQ];
    __shared__ __align__(16) u16t vth[128 * PADV];
    __shared__ __align__(16) u16t vtl[128 * PADV];
    __shared__ __align__(16) float wl[32 * PADW];
    __shared__ float dpart[2][32];
    __shared__ int qm[32], km[32];

    const int q0 = qt * 32;
    const int srow = t >> 3;
    const int sd0  = (t & 7) * 16;

    {
        const float* src = qkv + ((size_t)(((z * SQ) + q0 + srow) * HH + h)) * CPH + sd0;
        float4 f0 = *(const float4*)(src);
        float4 f1 = *(const float4*)(src + 4);
        float4 f2 = *(const float4*)(src + 8);
        float4 f3 = *(const float4*)(src + 12);
        uint4 u0, u1;
        u0.x = pk2(f0.x, f0.y); u0.y = pk2(f0.z, f0.w); u0.z = pk2(f1.x, f1.y); u0.w = pk2(f1.z, f1.w);
        u1.x = pk2(f2.x, f2.y); u1.y = pk2(f2.z, f2.w); u1.z = pk2(f3.x, f3.y); u1.w = pk2(f3.z, f3.w);
        *(uint4*)&ks[srow * PADQ + sd0]     = u0;
        *(uint4*)&ks[srow * PADQ + sd0 + 8] = u1;
    }
    if (t < 32) qm[t] = mask[z * SQ + q0 + t];
    __syncthreads();
    bf16x8 qf[4];
    #pragma unroll
    for (int kk = 0; kk < 4; kk++)
        qf[kk] = *(const bf16x8*)&ks[(16 * m + l15) * PADQ + kk * 32 + quad * 8];

    f32x4 acc[4];
    #pragma unroll
    for (int i = 0; i < 4; i++) acc[i] = (f32x4){0.f, 0.f, 0.f, 0.f};
    float dsum[4] = {0.f, 0.f, 0.f, 0.f};

    const int dp = t & 63;
    const int d2 = 2 * dp;
    const int kg = t >> 6;
    const int k0v = kg * 8;

    for (int kt = 0; kt < SQ; kt += 32) {
        __syncthreads();

        {
            const float* src = qkv + ((size_t)(((z * SQ) + kt + srow) * HH + h)) * CPH + 128 + sd0;
            float4 f0 = *(const float4*)(src);
            float4 f1 = *(const float4*)(src + 4);
            float4 f2 = *(const float4*)(src + 8);
            float4 f3 = *(const float4*)(src + 12);
            uint4 u0, u1;
            u0.x = pk2(f0.x, f0.y); u0.y = pk2(f0.z, f0.w); u0.z = pk2(f1.x, f1.y); u0.w = pk2(f1.z, f1.w);
            u1.x = pk2(f2.x, f2.y); u1.y = pk2(f2.z, f2.w); u1.z = pk2(f3.x, f3.y); u1.w = pk2(f3.z, f3.w);
            *(uint4*)&ks[srow * PADQ + sd0]     = u0;
            *(uint4*)&ks[srow * PADQ + sd0 + 8] = u1;
        }
        {
            const u16t* vp0 = (const u16t*)(qkv + ((size_t)(((z * SQ) + kt + k0v) * HH + h)) * CPH + 256);
            u32t hi[8], lo[8];
            #pragma unroll
            for (int j = 0; j < 8; j++) {
                const u16t* vp = vp0 + (size_t)j * (2 * HH * CPH);
                hi[j] = *(const u32t*)(vp + d2);
                lo[j] = *(const u32t*)(vp + 128 + d2);
            }
            uint4 a, b;
            a.x = (hi[0] & 0xFFFFu) | (hi[1] << 16);
            a.y = (hi[2] & 0xFFFFu) | (hi[3] << 16);
            a.z = (hi[4] & 0xFFFFu) | (hi[5] << 16);
            a.w = (hi[6] & 0xFFFFu) | (hi[7] << 16);
            b.x = (hi[0] >> 16) | (hi[1] & 0xFFFF0000u);
            b.y = (hi[2] >> 16) | (hi[3] & 0xFFFF0000u);
            b.z = (hi[4] >> 16) | (hi[5] & 0xFFFF0000u);
            b.w = (hi[6] >> 16) | (hi[7] & 0xFFFF0000u);
            *(uint4*)&vth[d2 * PADV + k0v]       = a;
            *(uint4*)&vth[(d2 + 1) * PADV + k0v] = b;
            a.x = (lo[0] & 0xFFFFu) | (lo[1] << 16);
            a.y = (lo[2] & 0xFFFFu) | (lo[3] << 16);
            a.z = (lo[4] & 0xFFFFu) | (lo[5] << 16);
            a.w = (lo[6] & 0xFFFFu) | (lo[7] << 16);
            b.x = (lo[0] >> 16) | (lo[1] & 0xFFFF0000u);
            b.y = (lo[2] >> 16) | (lo[3] & 0xFFFF0000u);
            b.z = (lo[4] >> 16) | (lo[5] & 0xFFFF0000u);
            b.w = (lo[6] >> 16) | (lo[7] & 0xFFFF0000u);
            *(uint4*)&vtl[d2 * PADV + k0v]       = a;
            *(uint4*)&vtl[(d2 + 1) * PADV + k0v] = b;
        }
        if (t < 32) km[t] = mask[z * SQ + kt + t];
        __syncthreads();

        f32x4 s4 = (f32x4){0.f, 0.f, 0.f, 0.f};
        #pragma unroll
        for (int kk = 0; kk < 4; kk++) {
            bf16x8 kf = *(const bf16x8*)&ks[(16 * ng + l15) * PADQ + kk * 32 + quad * 8];
            s4 = __builtin_amdgcn_mfma_f32_16x16x32_bf16(qf[kk], kf, s4, 0, 0, 0);
        }
        {
            int colm = km[16 * ng + l15];
            #pragma unroll
            for (int r = 0; r < 4; r++) {
                int row = 16 * m + 4 * quad + r;
                float w = (qm[row] | colm) ? 0.f : __expf(s4[r] * ATTSCALE);
                dsum[r] += w;
                wl[row * PADW + 16 * ng + l15] = w;
            }
        }
        __syncthreads();

        {
            const float* prow = &wl[(16 * m + l15) * PADW + quad * 8];
            float4 p0 = *(const float4*)(prow);
            float4 p1 = *(const float4*)(prow + 4);
            float pv[8] = {p0.x, p0.y, p0.z, p0.w, p1.x, p1.y, p1.z, p1.w};
            union { u16t u[8]; bf16x8 v; } ph, pl;
            #pragma unroll
            for (int e = 0; e < 8; e++) {
                u16t hh = f2bf(pv[e]);
                ph.u[e] = hh;
                pl.u[e] = f2bf(pv[e] - bf2f(hh));
            }
            #pragma unroll
            for (int i = 0; i < 4; i++) {
                int d = 64 * ng + 16 * i + l15;
                bf16x8 vh = *(const bf16x8*)&vth[d * PADV + quad * 8];
                bf16x8 vl = *(const bf16x8*)&vtl[d * PADV + quad * 8];
                acc[i] = __builtin_amdgcn_mfma_f32_16x16x32_bf16(ph.v, vh, acc[i], 0, 0, 0);
                acc[i] = __builtin_amdgcn_mfma_f32_16x16x32_bf16(ph.v, vl, acc[i], 0, 0, 0);
                acc[i] = __builtin_amdgcn_mfma_f32_16x16x32_bf16(pl.v, vh, acc[i], 0, 0, 0);
            }
        }
    }

    #pragma unroll
    for (int r = 0; r < 4; r++) {
        float v = dsum[r];
        v += __shfl_xor(v, 1);
        v += __shfl_xor(v, 2);
        v += __shfl_xor(v, 4);
        v += __shfl_xor(v, 8);
        dsum[r] = v;
    }
    if (l15 == 0) {
        #pragma unroll
        for (int r = 0; r < 4; r++) dpart[ng][16 * m + 4 * quad + r] = dsum[r];
    }
    __syncthreads();

    #pragma unroll
    for (int r = 0; r < 4; r++) {
        int row = 16 * m + 4 * quad + r;
        float den = dpart[0][row] + dpart[1][row];
        float inv = den > 0.f ? 1.f / den : 0.f;
        float* dst = O3 + ((size_t)(((z * SQ) + q0 + row) * HH + h)) * DV;
        #pragma unroll
        for (int i = 0; i < 4; i++) {
            float o = acc[i][r] * inv;
            dst[64 * ng + 16 * i + l15] = cubef(o);
        }
    }
}

// ---------------- K4: partial[s] = O3[:, s-chunk] @ W[s-chunk, :]  (split-bf16 MFMA) ----------------
__global__ __launch_bounds__(256) void final_gemm_mfma(const float* __restrict__ A,
                                                       const u16t* __restrict__ Bh,
                                                       const u16t* __restrict__ Bl,
                                                       float* __restrict__ part) {
    __shared__ __align__(16) u16t as_h[4 * 128 * 8];
    __shared__ __align__(16) u16t as_l[4 * 128 * 8];
    __shared__ __align__(16) u16t bs_h[4 * 128 * 8];
    __shared__ __align__(16) u16t bs_l[4 * 128 * 8];

    const int t = threadIdx.x;
    const int lane = t & 63, wid = t >> 6;
    const int quad = lane >> 4, l15 = lane & 15;
    const int wm = (wid & 1) * 64;
    const int wn = (wid >> 1) * 64;
    const int rowBase = blockIdx.x * 128;
    const int kBase   = blockIdx.y * (KOUT / KSPLIT);   // 256
    const int sm = t & 127;
    const int skh = t >> 7;

    f32x4 acc[4][4];
    #pragma unroll
    for (int i = 0; i < 4; i++)
        #pragma unroll
        for (int j = 0; j < 4; j++) acc[i][j] = (f32x4){0.f, 0.f, 0.f, 0.f};

    const float* aPtr  = A  + (size_t)(rowBase + sm) * KOUT + kBase + skh * 16;
    const u16t*  bhPtr = Bh + (size_t)sm * KOUT + kBase + skh * 16;
    const u16t*  blPtr = Bl + (size_t)sm * KOUT + kBase + skh * 16;
    u16t* awh = &as_h[(skh * 2) * 1024 + sm * 8];
    u16t* awl = &as_l[(skh * 2) * 1024 + sm * 8];
    u16t* bwh = &bs_h[(skh * 2) * 1024 + sm * 8];
    u16t* bwl = &bs_l[(skh * 2) * 1024 + sm * 8];

    for (int k0 = 0; k0 < KOUT / KSPLIT; k0 += 32) {
        float4 a0 = *(const float4*)(aPtr + k0);
        float4 a1 = *(const float4*)(aPtr + k0 + 4);
        float4 a2 = *(const float4*)(aPtr + k0 + 8);
        float4 a3 = *(const float4*)(aPtr + k0 + 12);
        uint4 bh0 = *(const uint4*)(bhPtr + k0);
        uint4 bh1 = *(const uint4*)(bhPtr + k0 + 8);
        uint4 bl0 = *(const uint4*)(blPtr + k0);
        uint4 bl1 = *(const uint4*)(blPtr + k0 + 8);
        uint4 ah0, ah1, al0, al1;
        split2(a0.x, a0.y, ah0.x, al0.x);
        split2(a0.z, a0.w, ah0.y, al0.y);
        split2(a1.x, a1.y, ah0.z, al0.z);
        split2(a1.z, a1.w, ah0.w, al0.w);
        split2(a2.x, a2.y, ah1.x, al1.x);
        split2(a2.z, a2.w, ah1.y, al1.y);
        split2(a3.x, a3.y, ah1.z, al1.z);
        split2(a3.z, a3.w, ah1.w, al1.w);

        __syncthreads();
        *(uint4*)(awh)        = ah0;
        *(uint4*)(awh + 1024) = ah1;
        *(uint4*)(awl)        = al0;
        *(uint4*)(awl + 1024) = al1;
        *(uint4*)(bwh)        = bh0;
        *(uint4*)(bwh + 1024) = bh1;
        *(uint4*)(bwl)        = bl0;
        *(uint4*)(bwl + 1024) = bl1;
        __syncthreads();

        bf16x8 ah[4], al[4], bh[4], bl[4];
        #pragma unroll
        for (int mt = 0; mt < 4; mt++) {
            int off = quad * 1024 + (wm + mt * 16 + l15) * 8;
            ah[mt] = *(const bf16x8*)&as_h[off];
            al[mt] = *(const bf16x8*)&as_l[off];
        }
        #pragma unroll
        for (int nt = 0; nt < 4; nt++) {
            int off = quad * 1024 + (wn + nt * 16 + l15) * 8;
            bh[nt] = *(const bf16x8*)&bs_h[off];
            bl[nt] = *(const bf16x8*)&bs_l[off];
        }
        #pragma unroll
        for (int mt = 0; mt < 4; mt++)
            #pragma unroll
            for (int nt = 0; nt < 4; nt++) {
                acc[mt][nt] = __builtin_amdgcn_mfma_f32_16x16x32_bf16(ah[mt], bh[nt], acc[mt][nt], 0, 0, 0);
                acc[mt][nt] = __builtin_amdgcn_mfma_f32_16x16x32_bf16(ah[mt], bl[nt], acc[mt][nt], 0, 0, 0);
                acc[mt][nt] = __builtin_amdgcn_mfma_f32_16x16x32_bf16(al[mt], bh[nt], acc[mt][nt], 0, 0, 0);
            }
    }

    float* pbase = part + (size_t)blockIdx.y * ((size_t)MROWS * 128);
    #pragma unroll
    for (int mt = 0; mt < 4; mt++)
        #pragma unroll
        for (int nt = 0; nt < 4; nt++) {
            int col = wn + nt * 16 + l15;
            #pragma unroll
            for (int r = 0; r < 4; r++) {
                int row = rowBase + wm + mt * 16 + quad * 4 + r;
                pbase[(size_t)row * 128 + col] = acc[mt][nt][r];
            }
        }
}

// ---------------- K5: out = cube(sum_s partial[s] + bias) ----------------
__global__ __launch_bounds__(256) void reduce_bias_cube(const float* __restrict__ part,
                                                        const float* __restrict__ bias,
                                                        float* __restrict__ out) {
    const int idx = (blockIdx.x * 256 + threadIdx.x) * 4;
    float4 s = {0.f, 0.f, 0.f, 0.f};
    #pragma unroll
    for (int p = 0; p < KSPLIT; p++) {
        float4 v = *(const float4*)&part[(size_t)p * ((size_t)MROWS * 128) + idx];
        s.x += v.x; s.y += v.y; s.z += v.z; s.w += v.w;
    }
    float4 b = *(const float4*)&bias[idx & 127];
    float4 r;
    r.x = cubef(s.x + b.x);
    r.y = cubef(s.y + b.y);
    r.z = cubef(s.z + b.z);
    r.w = cubef(s.w + b.w);
    *(float4*)&out[idx] = r;
}

extern "C" void kernel_launch(void* const* d_in, const int* in_sizes, int n_in,
                              void* d_out, int out_size, void* d_ws, size_t ws_size,
                              hipStream_t stream) {
    const float* x        = (const float*)d_in[0];
    const int*   mask     = (const int*)d_in[1];
    const float* proj_in  = (const float*)d_in[2];
    const float* v_bias   = (const float*)d_in[3];
    const float* proj_out = (const float*)d_in[4];
    const float* po_bias  = (const float*)d_in[5];
    float* out = (float*)d_out;

    float* qkv = (float*)d_ws;                 // [4096, 6144] fp32 (100.7 MB)
    float* O3  = qkv + (size_t)MROWS * NT;     // [4096, 2048] fp32 (33.6 MB)
    // pT aliases the O3 slot: dead before attn writes O3 (stream-ordered)
    u16t* pTh = (u16t*)O3;                     // [6144,1024] bf16
    u16t* pTl = pTh + (size_t)NT * DIN;        // [6144,1024] bf16
    // WT + partials alias the qkv slot: qkv dead after attn (stream-ordered)
    u16t* WTh = (u16t*)qkv;                          // [128,2048] bf16 (0.5 MB)
    u16t* WTl = WTh + (size_t)128 * KOUT;            // [128,2048] bf16 (0.5 MB)
    float* partials = (float*)(WTl + (size_t)128 * KOUT);  // [8,4096,128] f32 (16.8 MB)

    split_transpose_w<<<dim3(NT / 64, DIN / 64), 256, 0, stream>>>(proj_in, pTh, pTl);
    gemm_qkv_mfma<<<dim3(NT / 128, MROWS / 128), 256, 0, stream>>>(x, pTh, pTl, qkv);
    rot_bias<<<BZ * SQ * HH, 256, 0, stream>>>(qkv, v_bias);
    attn_kernel<<<BZ * HH * (SQ / 32), 256, 0, stream>>>(qkv, mask, O3);
    split_transpose_w2<<<dim3(2, KOUT / 64), 256, 0, stream>>>(proj_out, WTh, WTl);
    final_gemm_mfma<<<dim3(MROWS / 128, KSPLIT), 256, 0, stream>>>(O3, WTh, WTl, partials);
    reduce_bias_cube<<<(MROWS * 128) / (256 * 4), 256, 0, stream>>>(partials, po_bias, out);
}

// Round 6
// 529.292 us; speedup vs baseline: 5.6669x; 1.2692x over previous
//
#include <hip/hip_runtime.h>
#include <math.h>

#define BZ 2
#define SQ 2048
#define DIN 1024
#define HH 16
#define NT 6144
#define MROWS 4096
#define KOUT 2048
#define KSPLIT 8

typedef unsigned short u16t;
typedef unsigned int u32t;
typedef __attribute__((ext_vector_type(8))) short bf16x8;
typedef __attribute__((ext_vector_type(4))) float f32x4;

__device__ __forceinline__ float cubef(float x) { return x * x * x; }

__device__ __forceinline__ u16t f2bf(float f) {          // fp32 -> bf16 RNE
    u32t b = __float_as_uint(f);
    b += 0x7FFFu + ((b >> 16) & 1u);
    return (u16t)(b >> 16);
}
__device__ __forceinline__ float bf2f(u16t u) { return __uint_as_float(((u32t)u) << 16); }
__device__ __forceinline__ u32t pk2(float a, float b) {
    return (u32t)f2bf(a) | ((u32t)f2bf(b) << 16);
}
__device__ __forceinline__ void split2(float f0, float f1, u32t& hi, u32t& lo) {
    u32t u0 = __float_as_uint(f0), u1 = __float_as_uint(f1);
    u32t h0 = u0 & 0xFFFF0000u, h1 = u1 & 0xFFFF0000u;
    float r0 = f0 - __uint_as_float(h0);
    float r1 = f1 - __uint_as_float(h1);
    hi = (h0 >> 16) | h1;
    lo = (__float_as_uint(r0) >> 16) | (__float_as_uint(r1) & 0xFFFF0000u);
}

// ---------------- K0a: proj_in [k][n] fp32 -> pTh/pTl [n][k] bf16 ----------------
__global__ __launch_bounds__(256) void split_transpose_w(const float* __restrict__ W,
                                                         u16t* __restrict__ Th,
                                                         u16t* __restrict__ Tl) {
    __shared__ float tile[64][68];
    const int n0 = blockIdx.x * 64;
    const int k0 = blockIdx.y * 64;
    const int t = threadIdx.x;
    {
        const int r = t >> 4, c = (t & 15) * 4;
        #pragma unroll
        for (int p = 0; p < 4; p++) {
            float4 v = *(const float4*)&W[(size_t)(k0 + r + p * 16) * NT + n0 + c];
            *(float4*)&tile[r + p * 16][c] = v;
        }
    }
    __syncthreads();
    const int nr = t >> 2;
    const int kc = (t & 3) * 16;
    u32t hi[8], lo[8];
    #pragma unroll
    for (int j = 0; j < 8; j++)
        split2(tile[kc + 2 * j][nr], tile[kc + 2 * j + 1][nr], hi[j], lo[j]);
    size_t ob = (size_t)(n0 + nr) * DIN + k0 + kc;
    *(uint4*)&Th[ob]     = *(uint4*)&hi[0];
    *(uint4*)&Th[ob + 8] = *(uint4*)&hi[4];
    *(uint4*)&Tl[ob]     = *(uint4*)&lo[0];
    *(uint4*)&Tl[ob + 8] = *(uint4*)&lo[4];
}

// ---------------- K0b: proj_out [k][y] fp32 -> WTh/WTl [y][k] bf16 ----------------
__global__ __launch_bounds__(256) void split_transpose_w2(const float* __restrict__ W,
                                                          u16t* __restrict__ Th,
                                                          u16t* __restrict__ Tl) {
    __shared__ float tile[64][68];
    const int n0 = blockIdx.x * 64;
    const int k0 = blockIdx.y * 64;
    const int t = threadIdx.x;
    {
        const int r = t >> 4, c = (t & 15) * 4;
        #pragma unroll
        for (int p = 0; p < 4; p++) {
            float4 v = *(const float4*)&W[(size_t)(k0 + r + p * 16) * 128 + n0 + c];
            *(float4*)&tile[r + p * 16][c] = v;
        }
    }
    __syncthreads();
    const int nr = t >> 2;
    const int kc = (t & 3) * 16;
    u32t hi[8], lo[8];
    #pragma unroll
    for (int j = 0; j < 8; j++)
        split2(tile[kc + 2 * j][nr], tile[kc + 2 * j + 1][nr], hi[j], lo[j]);
    size_t ob = (size_t)(n0 + nr) * KOUT + k0 + kc;
    *(uint4*)&Th[ob]     = *(uint4*)&hi[0];
    *(uint4*)&Th[ob + 8] = *(uint4*)&hi[4];
    *(uint4*)&Tl[ob]     = *(uint4*)&lo[0];
    *(uint4*)&Tl[ob + 8] = *(uint4*)&lo[4];
}

// ---------------- K1: qkv GEMM, epilogue writes head-major bf16 Q/K + split V ----------------
__global__ __launch_bounds__(256) void gemm_qkv_mfma2(const float* __restrict__ A,
                                                      const u16t* __restrict__ Bh,
                                                      const u16t* __restrict__ Bl,
                                                      const float* __restrict__ vb,
                                                      u16t* __restrict__ QB,
                                                      u16t* __restrict__ KB,
                                                      u16t* __restrict__ VFh,
                                                      u16t* __restrict__ VFl) {
    __shared__ __align__(16) u16t as_h[4 * 128 * 8];
    __shared__ __align__(16) u16t as_l[4 * 128 * 8];
    __shared__ __align__(16) u16t bs_h[4 * 128 * 8];
    __shared__ __align__(16) u16t bs_l[4 * 128 * 8];

    const int t = threadIdx.x;
    const int lane = t & 63, wid = t >> 6;
    const int quad = lane >> 4, l15 = lane & 15;
    const int wm = (wid & 1) * 64;
    const int wn = (wid >> 1) * 64;
    const int rowBase = blockIdx.y * 128;
    const int colBase = blockIdx.x * 128;
    const int sm = t & 127;
    const int skh = t >> 7;

    f32x4 acc[4][4];
    #pragma unroll
    for (int i = 0; i < 4; i++)
        #pragma unroll
        for (int j = 0; j < 4; j++) acc[i][j] = (f32x4){0.f, 0.f, 0.f, 0.f};

    const float* aPtr  = A  + (size_t)(rowBase + sm) * DIN + skh * 16;
    const u16t*  bhPtr = Bh + (size_t)(colBase + sm) * DIN + skh * 16;
    const u16t*  blPtr = Bl + (size_t)(colBase + sm) * DIN + skh * 16;
    u16t* awh = &as_h[(skh * 2) * 1024 + sm * 8];
    u16t* awl = &as_l[(skh * 2) * 1024 + sm * 8];
    u16t* bwh = &bs_h[(skh * 2) * 1024 + sm * 8];
    u16t* bwl = &bs_l[(skh * 2) * 1024 + sm * 8];

    for (int k0 = 0; k0 < DIN; k0 += 32) {
        float4 a0 = *(const float4*)(aPtr + k0);
        float4 a1 = *(const float4*)(aPtr + k0 + 4);
        float4 a2 = *(const float4*)(aPtr + k0 + 8);
        float4 a3 = *(const float4*)(aPtr + k0 + 12);
        uint4 bh0 = *(const uint4*)(bhPtr + k0);
        uint4 bh1 = *(const uint4*)(bhPtr + k0 + 8);
        uint4 bl0 = *(const uint4*)(blPtr + k0);
        uint4 bl1 = *(const uint4*)(blPtr + k0 + 8);
        uint4 ah0, ah1, al0, al1;
        split2(a0.x, a0.y, ah0.x, al0.x);
        split2(a0.z, a0.w, ah0.y, al0.y);
        split2(a1.x, a1.y, ah0.z, al0.z);
        split2(a1.z, a1.w, ah0.w, al0.w);
        split2(a2.x, a2.y, ah1.x, al1.x);
        split2(a2.z, a2.w, ah1.y, al1.y);
        split2(a3.x, a3.y, ah1.z, al1.z);
        split2(a3.z, a3.w, ah1.w, al1.w);

        __syncthreads();
        *(uint4*)(awh)        = ah0;
        *(uint4*)(awh + 1024) = ah1;
        *(uint4*)(awl)        = al0;
        *(uint4*)(awl + 1024) = al1;
        *(uint4*)(bwh)        = bh0;
        *(uint4*)(bwh + 1024) = bh1;
        *(uint4*)(bwl)        = bl0;
        *(uint4*)(bwl + 1024) = bl1;
        __syncthreads();

        bf16x8 ah[4], al[4], bh[4], bl[4];
        #pragma unroll
        for (int mt = 0; mt < 4; mt++) {
            int off = quad * 1024 + (wm + mt * 16 + l15) * 8;
            ah[mt] = *(const bf16x8*)&as_h[off];
            al[mt] = *(const bf16x8*)&as_l[off];
        }
        #pragma unroll
        for (int nt = 0; nt < 4; nt++) {
            int off = quad * 1024 + (wn + nt * 16 + l15) * 8;
            bh[nt] = *(const bf16x8*)&bs_h[off];
            bl[nt] = *(const bf16x8*)&bs_l[off];
        }
        #pragma unroll
        for (int mt = 0; mt < 4; mt++)
            #pragma unroll
            for (int nt = 0; nt < 4; nt++) {
                acc[mt][nt] = __builtin_amdgcn_mfma_f32_16x16x32_bf16(ah[mt], bh[nt], acc[mt][nt], 0, 0, 0);
                acc[mt][nt] = __builtin_amdgcn_mfma_f32_16x16x32_bf16(ah[mt], bl[nt], acc[mt][nt], 0, 0, 0);
                acc[mt][nt] = __builtin_amdgcn_mfma_f32_16x16x32_bf16(al[mt], bh[nt], acc[mt][nt], 0, 0, 0);
            }
    }

    // epilogue: col tile -> (head, q/k/v); 384 = 3*128 so tileX%3 selects q/k/v
    const int hed = colBase >> 7;           // tile index
    const int h = hed / 3, t3 = hed % 3;
    const int z = rowBase >> 11;
    const int s0 = (rowBase & 2047) + wm + quad * 4;
    const size_t obase = (size_t)(z * 16 + h) * 2048;

    if (t3 == 2) {
        #pragma unroll
        for (int nt = 0; nt < 4; nt++) {
            int c = wn + nt * 16 + l15;
            float bb = vb[h * 128 + c];
            #pragma unroll
            for (int mt = 0; mt < 4; mt++)
                #pragma unroll
                for (int r = 0; r < 4; r++) {
                    int s = s0 + mt * 16 + r;
                    float v = acc[mt][nt][r] + bb;
                    u32t u = __float_as_uint(v);
                    u32t hb = u & 0xFFFF0000u;
                    size_t idx = (obase + s) * 128 + c;
                    VFh[idx] = (u16t)(hb >> 16);
                    VFl[idx] = f2bf(v - __uint_as_float(hb));
                }
        }
    } else {
        u16t* dst = t3 ? KB : QB;
        #pragma unroll
        for (int nt = 0; nt < 4; nt++) {
            int c = wn + nt * 16 + l15;
            #pragma unroll
            for (int mt = 0; mt < 4; mt++)
                #pragma unroll
                for (int r = 0; r < 4; r++) {
                    int s = s0 + mt * 16 + r;
                    dst[(obase + s) * 128 + c] = f2bf(acc[mt][nt][r]);
                }
        }
    }
}

// ---------------- K2: rotary in-place on QB/KB; V tile-transpose in-place ----------------
__global__ __launch_bounds__(256) void prep_rot_trans(u16t* __restrict__ QB,
                                                      u16t* __restrict__ KB,
                                                      u16t* __restrict__ VTh,
                                                      u16t* __restrict__ VTl) {
    const int bx = blockIdx.x;
    const int st = bx & 63, h = (bx >> 6) & 15, z = bx >> 10;
    const int t = threadIdx.x;
    const size_t base = ((size_t)(z * 16 + h) * 2048 + st * 32) * 128;   // u16 index

    // ---- rotary: lanes w<4 -> Q chunks {c, c+4}; w>=4 -> K ----
    {
        const int r = t >> 3, w = t & 7;
        const int c = w & 3;
        const int s = st * 32 + r;
        u16t* buf = (w < 4) ? QB : KB;
        u16t* p1 = buf + base + (size_t)r * 128 + c * 16;
        u16t* p2 = p1 + 64;
        uint4 a0 = *(uint4*)p1, a1 = *(uint4*)(p1 + 8);
        uint4 b0 = *(uint4*)p2, b1 = *(uint4*)(p2 + 8);
        u32t A[8] = {a0.x, a0.y, a0.z, a0.w, a1.x, a1.y, a1.z, a1.w};
        u32t B[8] = {b0.x, b0.y, b0.z, b0.w, b1.x, b1.y, b1.z, b1.w};
        u32t OA[8], OB[8];
        #pragma unroll
        for (int p = 0; p < 8; p++) {
            float x1a = bf2f((u16t)(A[p] & 0xFFFFu)), x1b = bf2f((u16t)(A[p] >> 16));
            float x2a = bf2f((u16t)(B[p] & 0xFFFFu)), x2b = bf2f((u16t)(B[p] >> 16));
            int j0 = c * 16 + 2 * p;
            float f0 = expf(-0.14391156831212788f * (float)j0);
            float f1 = expf(-0.14391156831212788f * (float)(j0 + 1));
            float sn0, cs0, sn1, cs1;
            sincosf((float)s * f0, &sn0, &cs0);
            sincosf((float)s * f1, &sn1, &cs1);
            OA[p] = pk2(x1a * cs0 - x2a * sn0, x1b * cs1 - x2b * sn1);
            OB[p] = pk2(x2a * cs0 + x1a * sn0, x2b * cs1 + x1b * sn1);
        }
        *(uint4*)p1       = make_uint4(OA[0], OA[1], OA[2], OA[3]);
        *(uint4*)(p1 + 8) = make_uint4(OA[4], OA[5], OA[6], OA[7]);
        *(uint4*)p2       = make_uint4(OB[0], OB[1], OB[2], OB[3]);
        *(uint4*)(p2 + 8) = make_uint4(OB[4], OB[5], OB[6], OB[7]);
    }

    // ---- V transpose in place: [32 s][128 d] -> [128 d][32 s], same byte range ----
    __shared__ u16t vt[128 * 40];
    #pragma unroll
    for (int pass = 0; pass < 2; pass++) {
        u16t* V = pass ? VTl : VTh;
        {
            uint4 a = *(uint4*)(V + base + t * 16);
            uint4 b = *(uint4*)(V + base + t * 16 + 8);
            int row = t >> 3, d0 = (t & 7) * 16;
            u32t W[8] = {a.x, a.y, a.z, a.w, b.x, b.y, b.z, b.w};
            #pragma unroll
            for (int p = 0; p < 8; p++) {
                vt[(d0 + 2 * p) * 40 + row]     = (u16t)(W[p] & 0xFFFFu);
                vt[(d0 + 2 * p + 1) * 40 + row] = (u16t)(W[p] >> 16);
            }
        }
        __syncthreads();
        {
            int d = t >> 1, k0 = (t & 1) * 16;
            uint4 a = *(uint4*)&vt[d * 40 + k0];
            uint4 b = *(uint4*)&vt[d * 40 + k0 + 8];
            *(uint4*)(V + base + t * 16)     = a;
            *(uint4*)(V + base + t * 16 + 8) = b;
        }
        __syncthreads();
    }
}

// ---------------- K3: MFMA attention v2. block = (z,h, 64 queries), 4 waves ----------------
#define ATTSCALE 0.08838834764831845f

__global__ __launch_bounds__(256, 4) void attn_kernel2(const u16t* __restrict__ QB,
                                                       const u16t* __restrict__ KB,
                                                       const u16t* __restrict__ VTh,
                                                       const u16t* __restrict__ VTl,
                                                       const int* __restrict__ mask,
                                                       float* __restrict__ O3) {
    const int blk = blockIdx.x;
    const int qt = blk & 31;
    const int h  = (blk >> 5) & 15;
    const int z  = blk >> 9;
    const int t  = threadIdx.x;
    const int lane = t & 63, wid = t >> 6;
    const int quad = lane >> 4, l15 = lane & 15;
    const int w1 = wid & 1;       // q-pair selector: q-16-tiles {w1, w1+2}
    const int kh = wid >> 1;      // k-16-col tile (QK) / d-64 half (PV)

    __shared__ __align__(16) u16t ks[32 * 136];
    __shared__ __align__(16) u16t vth[128 * 40];
    __shared__ __align__(16) u16t vtl[128 * 40];
    __shared__ __align__(16) float wl[64 * 36];
    __shared__ float dpart[2][64];
    __shared__ int qm[64], km[32];

    const int q0 = qt * 64;
    const size_t zh = (size_t)(z * 16 + h);
    const u16t* qb = QB + zh * 262144;
    const u16t* kb = KB + zh * 262144;
    const u16t* vhg = VTh + zh * 262144;
    const u16t* vlg = VTl + zh * 262144;

    bf16x8 qf[2][4];
    #pragma unroll
    for (int i = 0; i < 2; i++)
        #pragma unroll
        for (int kk = 0; kk < 4; kk++)
            qf[i][kk] = *(const bf16x8*)(qb + (size_t)(q0 + 16 * (w1 + 2 * i) + l15) * 128 + kk * 32 + quad * 8);
    if (t < 64) qm[t] = mask[z * SQ + q0 + t];

    f32x4 acc[2][4];
    #pragma unroll
    for (int i = 0; i < 2; i++)
        #pragma unroll
        for (int d = 0; d < 4; d++) acc[i][d] = (f32x4){0.f, 0.f, 0.f, 0.f};
    float dsum[2][4] = {{0.f, 0.f, 0.f, 0.f}, {0.f, 0.f, 0.f, 0.f}};

    for (int kt = 0; kt < SQ; kt += 32) {
        __syncthreads();
        // stage K (contiguous 8KB) and V^T hi/lo (contiguous 8KB each)
        {
            const u16t* src = kb + (size_t)kt * 128 + t * 16;
            uint4 a = *(const uint4*)(src);
            uint4 b = *(const uint4*)(src + 8);
            int row = t >> 3, co = (t & 7) * 16;
            *(uint4*)&ks[row * 136 + co]     = a;
            *(uint4*)&ks[row * 136 + co + 8] = b;
        }
        {
            const u16t* srch = vhg + (size_t)(kt >> 5) * 4096 + t * 16;
            const u16t* srcl = vlg + (size_t)(kt >> 5) * 4096 + t * 16;
            uint4 a = *(const uint4*)(srch);
            uint4 b = *(const uint4*)(srch + 8);
            uint4 c = *(const uint4*)(srcl);
            uint4 d = *(const uint4*)(srcl + 8);
            int dd = t >> 1, k0 = (t & 1) * 16;
            *(uint4*)&vth[dd * 40 + k0]     = a;
            *(uint4*)&vth[dd * 40 + k0 + 8] = b;
            *(uint4*)&vtl[dd * 40 + k0]     = c;
            *(uint4*)&vtl[dd * 40 + k0 + 8] = d;
        }
        if (t < 32) km[t] = mask[z * SQ + kt + t];
        __syncthreads();

        // QK^T + mask + exp
        #pragma unroll
        for (int i = 0; i < 2; i++) {
            const int qsel = w1 + 2 * i;
            f32x4 s4 = (f32x4){0.f, 0.f, 0.f, 0.f};
            #pragma unroll
            for (int kk = 0; kk < 4; kk++) {
                bf16x8 kf = *(const bf16x8*)&ks[(16 * kh + l15) * 136 + kk * 32 + quad * 8];
                s4 = __builtin_amdgcn_mfma_f32_16x16x32_bf16(qf[i][kk], kf, s4, 0, 0, 0);
            }
            int colm = km[16 * kh + l15];
            #pragma unroll
            for (int r = 0; r < 4; r++) {
                int row = 16 * qsel + 4 * quad + r;
                float wv = (qm[row] | colm) ? 0.f : __expf(s4[r] * ATTSCALE);
                dsum[i][r] += wv;
                wl[row * 36 + 16 * kh + l15] = wv;
            }
        }
        __syncthreads();

        // P·V (split P, reuse V frags across q-pair)
        union { u16t u[8]; bf16x8 v; } ph[2], pl[2];
        #pragma unroll
        for (int i = 0; i < 2; i++) {
            const float* pr = &wl[(16 * (w1 + 2 * i) + l15) * 36 + quad * 8];
            float4 p0 = *(const float4*)(pr);
            float4 p1 = *(const float4*)(pr + 4);
            float pv[8] = {p0.x, p0.y, p0.z, p0.w, p1.x, p1.y, p1.z, p1.w};
            #pragma unroll
            for (int e = 0; e < 8; e++) {
                u16t hi = f2bf(pv[e]);
                ph[i].u[e] = hi;
                pl[i].u[e] = f2bf(pv[e] - bf2f(hi));
            }
        }
        #pragma unroll
        for (int dt = 0; dt < 4; dt++) {
            int d = 64 * kh + 16 * dt + l15;
            bf16x8 vh = *(const bf16x8*)&vth[d * 40 + quad * 8];
            bf16x8 vl = *(const bf16x8*)&vtl[d * 40 + quad * 8];
            #pragma unroll
            for (int i = 0; i < 2; i++) {
                acc[i][dt] = __builtin_amdgcn_mfma_f32_16x16x32_bf16(ph[i].v, vh, acc[i][dt], 0, 0, 0);
                acc[i][dt] = __builtin_amdgcn_mfma_f32_16x16x32_bf16(ph[i].v, vl, acc[i][dt], 0, 0, 0);
                acc[i][dt] = __builtin_amdgcn_mfma_f32_16x16x32_bf16(pl[i].v, vh, acc[i][dt], 0, 0, 0);
            }
        }
    }

    // denominators: reduce over 16 lanes, combine k-halves via LDS
    #pragma unroll
    for (int i = 0; i < 2; i++)
        #pragma unroll
        for (int r = 0; r < 4; r++) {
            float v = dsum[i][r];
            v += __shfl_xor(v, 1);
            v += __shfl_xor(v, 2);
            v += __shfl_xor(v, 4);
            v += __shfl_xor(v, 8);
            dsum[i][r] = v;
        }
    if (l15 == 0) {
        #pragma unroll
        for (int i = 0; i < 2; i++)
            #pragma unroll
            for (int r = 0; r < 4; r++)
                dpart[kh][16 * (w1 + 2 * i) + 4 * quad + r] = dsum[i][r];
    }
    __syncthreads();

    #pragma unroll
    for (int i = 0; i < 2; i++)
        #pragma unroll
        for (int r = 0; r < 4; r++) {
            int row = 16 * (w1 + 2 * i) + 4 * quad + r;
            float den = dpart[0][row] + dpart[1][row];
            float inv = den > 0.f ? 1.f / den : 0.f;
            float* dst = O3 + ((size_t)(z * SQ + q0 + row) * HH + h) * 128;
            #pragma unroll
            for (int dt = 0; dt < 4; dt++)
                dst[64 * kh + 16 * dt + l15] = cubef(acc[i][dt][r] * inv);
        }
}

// ---------------- K4: partial[s] = O3[:, chunk] @ W[chunk, :]  (split-bf16 MFMA) ----------------
__global__ __launch_bounds__(256) void final_gemm_mfma(const float* __restrict__ A,
                                                       const u16t* __restrict__ Bh,
                                                       const u16t* __restrict__ Bl,
                                                       float* __restrict__ part) {
    __shared__ __align__(16) u16t as_h[4 * 128 * 8];
    __shared__ __align__(16) u16t as_l[4 * 128 * 8];
    __shared__ __align__(16) u16t bs_h[4 * 128 * 8];
    __shared__ __align__(16) u16t bs_l[4 * 128 * 8];

    const int t = threadIdx.x;
    const int lane = t & 63, wid = t >> 6;
    const int quad = lane >> 4, l15 = lane & 15;
    const int wm = (wid & 1) * 64;
    const int wn = (wid >> 1) * 64;
    const int rowBase = blockIdx.x * 128;
    const int kBase   = blockIdx.y * (KOUT / KSPLIT);
    const int sm = t & 127;
    const int skh = t >> 7;

    f32x4 acc[4][4];
    #pragma unroll
    for (int i = 0; i < 4; i++)
        #pragma unroll
        for (int j = 0; j < 4; j++) acc[i][j] = (f32x4){0.f, 0.f, 0.f, 0.f};

    const float* aPtr  = A  + (size_t)(rowBase + sm) * KOUT + kBase + skh * 16;
    const u16t*  bhPtr = Bh + (size_t)sm * KOUT + kBase + skh * 16;
    const u16t*  blPtr = Bl + (size_t)sm * KOUT + kBase + skh * 16;
    u16t* awh = &as_h[(skh * 2) * 1024 + sm * 8];
    u16t* awl = &as_l[(skh * 2) * 1024 + sm * 8];
    u16t* bwh = &bs_h[(skh * 2) * 1024 + sm * 8];
    u16t* bwl = &bs_l[(skh * 2) * 1024 + sm * 8];

    for (int k0 = 0; k0 < KOUT / KSPLIT; k0 += 32) {
        float4 a0 = *(const float4*)(aPtr + k0);
        float4 a1 = *(const float4*)(aPtr + k0 + 4);
        float4 a2 = *(const float4*)(aPtr + k0 + 8);
        float4 a3 = *(const float4*)(aPtr + k0 + 12);
        uint4 bh0 = *(const uint4*)(bhPtr + k0);
        uint4 bh1 = *(const uint4*)(bhPtr + k0 + 8);
        uint4 bl0 = *(const uint4*)(blPtr + k0);
        uint4 bl1 = *(const uint4*)(blPtr + k0 + 8);
        uint4 ah0, ah1, al0, al1;
        split2(a0.x, a0.y, ah0.x, al0.x);
        split2(a0.z, a0.w, ah0.y, al0.y);
        split2(a1.x, a1.y, ah0.z, al0.z);
        split2(a1.z, a1.w, ah0.w, al0.w);
        split2(a2.x, a2.y, ah1.x, al1.x);
        split2(a2.z, a2.w, ah1.y, al1.y);
        split2(a3.x, a3.y, ah1.z, al1.z);
        split2(a3.z, a3.w, ah1.w, al1.w);

        __syncthreads();
        *(uint4*)(awh)        = ah0;
        *(uint4*)(awh + 1024) = ah1;
        *(uint4*)(awl)        = al0;
        *(uint4*)(awl + 1024) = al1;
        *(uint4*)(bwh)        = bh0;
        *(uint4*)(bwh + 1024) = bh1;
        *(uint4*)(bwl)        = bl0;
        *(uint4*)(bwl + 1024) = bl1;
        __syncthreads();

        bf16x8 ah[4], al[4], bh[4], bl[4];
        #pragma unroll
        for (int mt = 0; mt < 4; mt++) {
            int off = quad * 1024 + (wm + mt * 16 + l15) * 8;
            ah[mt] = *(const bf16x8*)&as_h[off];
            al[mt] = *(const bf16x8*)&as_l[off];
        }
        #pragma unroll
        for (int nt = 0; nt < 4; nt++) {
            int off = quad * 1024 + (wn + nt * 16 + l15) * 8;
            bh[nt] = *(const bf16x8*)&bs_h[off];
            bl[nt] = *(const bf16x8*)&bs_l[off];
        }
        #pragma unroll
        for (int mt = 0; mt < 4; mt++)
            #pragma unroll
            for (int nt = 0; nt < 4; nt++) {
                acc[mt][nt] = __builtin_amdgcn_mfma_f32_16x16x32_bf16(ah[mt], bh[nt], acc[mt][nt], 0, 0, 0);
                acc[mt][nt] = __builtin_amdgcn_mfma_f32_16x16x32_bf16(ah[mt], bl[nt], acc[mt][nt], 0, 0, 0);
                acc[mt][nt] = __builtin_amdgcn_mfma_f32_16x16x32_bf16(al[mt], bh[nt], acc[mt][nt], 0, 0, 0);
            }
    }

    float* pbase = part + (size_t)blockIdx.y * ((size_t)MROWS * 128);
    #pragma unroll
    for (int mt = 0; mt < 4; mt++)
        #pragma unroll
        for (int nt = 0; nt < 4; nt++) {
            int col = wn + nt * 16 + l15;
            #pragma unroll
            for (int r = 0; r < 4; r++) {
                int row = rowBase + wm + mt * 16 + quad * 4 + r;
                pbase[(size_t)row * 128 + col] = acc[mt][nt][r];
            }
        }
}

// ---------------- K5: out = cube(sum partials + bias) ----------------
__global__ __launch_bounds__(256) void reduce_bias_cube(const float* __restrict__ part,
                                                        const float* __restrict__ bias,
                                                        float* __restrict__ out) {
    const int idx = (blockIdx.x * 256 + threadIdx.x) * 4;
    float4 s = {0.f, 0.f, 0.f, 0.f};
    #pragma unroll
    for (int p = 0; p < KSPLIT; p++) {
        float4 v = *(const float4*)&part[(size_t)p * ((size_t)MROWS * 128) + idx];
        s.x += v.x; s.y += v.y; s.z += v.z; s.w += v.w;
    }
    float4 b = *(const float4*)&bias[idx & 127];
    float4 r;
    r.x = cubef(s.x + b.x);
    r.y = cubef(s.y + b.y);
    r.z = cubef(s.z + b.z);
    r.w = cubef(s.w + b.w);
    *(float4*)&out[idx] = r;
}

extern "C" void kernel_launch(void* const* d_in, const int* in_sizes, int n_in,
                              void* d_out, int out_size, void* d_ws, size_t ws_size,
                              hipStream_t stream) {
    const float* x        = (const float*)d_in[0];
    const int*   mask     = (const int*)d_in[1];
    const float* proj_in  = (const float*)d_in[2];
    const float* v_bias   = (const float*)d_in[3];
    const float* proj_out = (const float*)d_in[4];
    const float* po_bias  = (const float*)d_in[5];
    float* out = (float*)d_out;

    // ws layout (96 MB total):
    u16t* QB  = (u16t*)d_ws;                   // [z,h,s,d] bf16, 16 MB
    u16t* KB  = QB + (size_t)8388608;          // 16 MB
    u16t* VTh = KB + (size_t)8388608;          // 16 MB ([s][d] from gemm, [d][s]-tiled after prep)
    u16t* VTl = VTh + (size_t)8388608;         // 16 MB
    float* O3 = (float*)(VTl + (size_t)8388608);  // [4096,2048] f32, 32 MB
    // pT aliases O3 (dead before attn writes O3)
    u16t* pTh = (u16t*)O3;                     // [6144,1024] bf16, 12 MB
    u16t* pTl = pTh + (size_t)NT * DIN;        // 12 MB
    // WT + partials alias QB/KB (dead after attn)
    u16t* WTh = QB;                            // [128,2048] bf16
    u16t* WTl = WTh + (size_t)128 * KOUT;
    float* partials = (float*)(WTl + (size_t)128 * KOUT);  // [8,4096,128] f32, 16 MB

    split_transpose_w<<<dim3(NT / 64, DIN / 64), 256, 0, stream>>>(proj_in, pTh, pTl);
    gemm_qkv_mfma2<<<dim3(NT / 128, MROWS / 128), 256, 0, stream>>>(x, pTh, pTl, v_bias,
                                                                    QB, KB, VTh, VTl);
    prep_rot_trans<<<BZ * HH * (SQ / 32), 256, 0, stream>>>(QB, KB, VTh, VTl);
    attn_kernel2<<<BZ * HH * (SQ / 64), 256, 0, stream>>>(QB, KB, VTh, VTl, mask, O3);
    split_transpose_w2<<<dim3(2, KOUT / 64), 256, 0, stream>>>(proj_out, WTh, WTl);
    final_gemm_mfma<<<dim3(MROWS / 128, KSPLIT), 256, 0, stream>>>(O3, WTh, WTl, partials);
    reduce_bias_cube<<<(MROWS * 128) / (256 * 4), 256, 0, stream>>>(partials, po_bias, out);
}

// Round 7
// 480.122 us; speedup vs baseline: 6.2473x; 1.1024x over previous
//
#include <hip/hip_runtime.h>
#include <math.h>

#define BZ 2
#define SQ 2048
#define DIN 1024
#define HH 16
#define NT 6144
#define MROWS 4096
#define KOUT 2048
#define KSPLIT 8

typedef unsigned short u16t;
typedef unsigned int u32t;
typedef __attribute__((ext_vector_type(8))) short bf16x8;
typedef __attribute__((ext_vector_type(4))) float f32x4;

__device__ __forceinline__ float cubef(float x) { return x * x * x; }

__device__ __forceinline__ u16t f2bf(float f) {          // fp32 -> bf16 RNE
    u32t b = __float_as_uint(f);
    b += 0x7FFFu + ((b >> 16) & 1u);
    return (u16t)(b >> 16);
}
__device__ __forceinline__ float bf2f(u16t u) { return __uint_as_float(((u32t)u) << 16); }
__device__ __forceinline__ u32t pk2(float a, float b) {
    return (u32t)f2bf(a) | ((u32t)f2bf(b) << 16);
}
__device__ __forceinline__ void split2(float f0, float f1, u32t& hi, u32t& lo) {
    u32t u0 = __float_as_uint(f0), u1 = __float_as_uint(f1);
    u32t h0 = u0 & 0xFFFF0000u, h1 = u1 & 0xFFFF0000u;
    float r0 = f0 - __uint_as_float(h0);
    float r1 = f1 - __uint_as_float(h1);
    hi = (h0 >> 16) | h1;
    lo = (__float_as_uint(r0) >> 16) | (__float_as_uint(r1) & 0xFFFF0000u);
}

// ---------------- K0x: x fp32 -> xh/xl bf16 (trunc split), same layout ----------------
__global__ __launch_bounds__(256) void split_x(const float* __restrict__ x,
                                               u16t* __restrict__ xh,
                                               u16t* __restrict__ xl) {
    const size_t idx = ((size_t)blockIdx.x * 256 + threadIdx.x) * 8;
    float4 f0 = *(const float4*)&x[idx];
    float4 f1 = *(const float4*)&x[idx + 4];
    u32t h[4], l[4];
    split2(f0.x, f0.y, h[0], l[0]);
    split2(f0.z, f0.w, h[1], l[1]);
    split2(f1.x, f1.y, h[2], l[2]);
    split2(f1.z, f1.w, h[3], l[3]);
    *(uint4*)&xh[idx] = *(uint4*)&h[0];
    *(uint4*)&xl[idx] = *(uint4*)&l[0];
}

// ---------------- K0a: proj_in [k][n] fp32 -> pTh/pTl [n][k] bf16 ----------------
__global__ __launch_bounds__(256) void split_transpose_w(const float* __restrict__ W,
                                                         u16t* __restrict__ Th,
                                                         u16t* __restrict__ Tl) {
    __shared__ float tile[64][68];
    const int n0 = blockIdx.x * 64;
    const int k0 = blockIdx.y * 64;
    const int t = threadIdx.x;
    {
        const int r = t >> 4, c = (t & 15) * 4;
        #pragma unroll
        for (int p = 0; p < 4; p++) {
            float4 v = *(const float4*)&W[(size_t)(k0 + r + p * 16) * NT + n0 + c];
            *(float4*)&tile[r + p * 16][c] = v;
        }
    }
    __syncthreads();
    const int nr = t >> 2;
    const int kc = (t & 3) * 16;
    u32t hi[8], lo[8];
    #pragma unroll
    for (int j = 0; j < 8; j++)
        split2(tile[kc + 2 * j][nr], tile[kc + 2 * j + 1][nr], hi[j], lo[j]);
    size_t ob = (size_t)(n0 + nr) * DIN + k0 + kc;
    *(uint4*)&Th[ob]     = *(uint4*)&hi[0];
    *(uint4*)&Th[ob + 8] = *(uint4*)&hi[4];
    *(uint4*)&Tl[ob]     = *(uint4*)&lo[0];
    *(uint4*)&Tl[ob + 8] = *(uint4*)&lo[4];
}

// ---------------- K0b: proj_out [k][y] fp32 -> WTh/WTl [y][k] bf16 ----------------
__global__ __launch_bounds__(256) void split_transpose_w2(const float* __restrict__ W,
                                                          u16t* __restrict__ Th,
                                                          u16t* __restrict__ Tl) {
    __shared__ float tile[64][68];
    const int n0 = blockIdx.x * 64;
    const int k0 = blockIdx.y * 64;
    const int t = threadIdx.x;
    {
        const int r = t >> 4, c = (t & 15) * 4;
        #pragma unroll
        for (int p = 0; p < 4; p++) {
            float4 v = *(const float4*)&W[(size_t)(k0 + r + p * 16) * 128 + n0 + c];
            *(float4*)&tile[r + p * 16][c] = v;
        }
    }
    __syncthreads();
    const int nr = t >> 2;
    const int kc = (t & 3) * 16;
    u32t hi[8], lo[8];
    #pragma unroll
    for (int j = 0; j < 8; j++)
        split2(tile[kc + 2 * j][nr], tile[kc + 2 * j + 1][nr], hi[j], lo[j]);
    size_t ob = (size_t)(n0 + nr) * KOUT + k0 + kc;
    *(uint4*)&Th[ob]     = *(uint4*)&hi[0];
    *(uint4*)&Th[ob + 8] = *(uint4*)&hi[4];
    *(uint4*)&Tl[ob]     = *(uint4*)&lo[0];
    *(uint4*)&Tl[ob + 8] = *(uint4*)&lo[4];
}

// ---------------- K1a: q,k tiles — 1-term bf16 MFMA (consumers round to bf16 anyway) ----------------
__global__ __launch_bounds__(256) void gemm_qk(const u16t* __restrict__ Ah,
                                               const u16t* __restrict__ Bh,
                                               u16t* __restrict__ QB,
                                               u16t* __restrict__ KB) {
    __shared__ __align__(16) u16t as_h[4 * 128 * 8];
    __shared__ __align__(16) u16t bs_h[4 * 128 * 8];

    const int t = threadIdx.x;
    const int lane = t & 63, wid = t >> 6;
    const int quad = lane >> 4, l15 = lane & 15;
    const int wm = (wid & 1) * 64;
    const int wn = (wid >> 1) * 64;
    const int tile = blockIdx.x;               // 0..31: head*2 + (q|k)
    const int h = tile >> 1, t3 = tile & 1;
    const int colBase = (h * 3 + t3) * 128;
    const int rowBase = blockIdx.y * 128;
    const int sm = t & 127;
    const int skh = t >> 7;

    f32x4 acc[4][4];
    #pragma unroll
    for (int i = 0; i < 4; i++)
        #pragma unroll
        for (int j = 0; j < 4; j++) acc[i][j] = (f32x4){0.f, 0.f, 0.f, 0.f};

    const u16t* aPtr = Ah + (size_t)(rowBase + sm) * DIN + skh * 16;
    const u16t* bPtr = Bh + (size_t)(colBase + sm) * DIN + skh * 16;
    u16t* aw = &as_h[(skh * 2) * 1024 + sm * 8];
    u16t* bw = &bs_h[(skh * 2) * 1024 + sm * 8];

    for (int k0 = 0; k0 < DIN; k0 += 32) {
        uint4 a0 = *(const uint4*)(aPtr + k0);
        uint4 a1 = *(const uint4*)(aPtr + k0 + 8);
        uint4 b0 = *(const uint4*)(bPtr + k0);
        uint4 b1 = *(const uint4*)(bPtr + k0 + 8);
        __syncthreads();
        *(uint4*)(aw)        = a0;
        *(uint4*)(aw + 1024) = a1;
        *(uint4*)(bw)        = b0;
        *(uint4*)(bw + 1024) = b1;
        __syncthreads();

        bf16x8 ah[4], bh[4];
        #pragma unroll
        for (int mt = 0; mt < 4; mt++)
            ah[mt] = *(const bf16x8*)&as_h[quad * 1024 + (wm + mt * 16 + l15) * 8];
        #pragma unroll
        for (int nt = 0; nt < 4; nt++)
            bh[nt] = *(const bf16x8*)&bs_h[quad * 1024 + (wn + nt * 16 + l15) * 8];
        #pragma unroll
        for (int mt = 0; mt < 4; mt++)
            #pragma unroll
            for (int nt = 0; nt < 4; nt++)
                acc[mt][nt] = __builtin_amdgcn_mfma_f32_16x16x32_bf16(ah[mt], bh[nt], acc[mt][nt], 0, 0, 0);
    }

    const int z = rowBase >> 11;
    const int s0 = (rowBase & 2047) + wm + quad * 4;
    const size_t obase = (size_t)(z * 16 + h) * 2048;
    u16t* dst = t3 ? KB : QB;
    #pragma unroll
    for (int nt = 0; nt < 4; nt++) {
        int c = wn + nt * 16 + l15;
        #pragma unroll
        for (int mt = 0; mt < 4; mt++)
            #pragma unroll
            for (int r = 0; r < 4; r++)
                dst[(obase + s0 + mt * 16 + r) * 128 + c] = f2bf(acc[mt][nt][r]);
    }
}

// ---------------- K1b: v tiles — 3-term split MFMA, epilogue +bias, split to hi/lo ----------------
__global__ __launch_bounds__(256) void gemm_v(const u16t* __restrict__ Ah,
                                              const u16t* __restrict__ Al,
                                              const u16t* __restrict__ Bh,
                                              const u16t* __restrict__ Bl,
                                              const float* __restrict__ vb,
                                              u16t* __restrict__ VFh,
                                              u16t* __restrict__ VFl) {
    __shared__ __align__(16) u16t as_h[4 * 128 * 8];
    __shared__ __align__(16) u16t as_l[4 * 128 * 8];
    __shared__ __align__(16) u16t bs_h[4 * 128 * 8];
    __shared__ __align__(16) u16t bs_l[4 * 128 * 8];

    const int t = threadIdx.x;
    const int lane = t & 63, wid = t >> 6;
    const int quad = lane >> 4, l15 = lane & 15;
    const int wm = (wid & 1) * 64;
    const int wn = (wid >> 1) * 64;
    const int h = blockIdx.x;                  // head
    const int colBase = (h * 3 + 2) * 128;
    const int rowBase = blockIdx.y * 128;
    const int sm = t & 127;
    const int skh = t >> 7;

    f32x4 acc[4][4];
    #pragma unroll
    for (int i = 0; i < 4; i++)
        #pragma unroll
        for (int j = 0; j < 4; j++) acc[i][j] = (f32x4){0.f, 0.f, 0.f, 0.f};

    const u16t* ahPtr = Ah + (size_t)(rowBase + sm) * DIN + skh * 16;
    const u16t* alPtr = Al + (size_t)(rowBase + sm) * DIN + skh * 16;
    const u16t* bhPtr = Bh + (size_t)(colBase + sm) * DIN + skh * 16;
    const u16t* blPtr = Bl + (size_t)(colBase + sm) * DIN + skh * 16;
    u16t* awh = &as_h[(skh * 2) * 1024 + sm * 8];
    u16t* awl = &as_l[(skh * 2) * 1024 + sm * 8];
    u16t* bwh = &bs_h[(skh * 2) * 1024 + sm * 8];
    u16t* bwl = &bs_l[(skh * 2) * 1024 + sm * 8];

    for (int k0 = 0; k0 < DIN; k0 += 32) {
        uint4 ah0 = *(const uint4*)(ahPtr + k0);
        uint4 ah1 = *(const uint4*)(ahPtr + k0 + 8);
        uint4 al0 = *(const uint4*)(alPtr + k0);
        uint4 al1 = *(const uint4*)(alPtr + k0 + 8);
        uint4 bh0 = *(const uint4*)(bhPtr + k0);
        uint4 bh1 = *(const uint4*)(bhPtr + k0 + 8);
        uint4 bl0 = *(const uint4*)(blPtr + k0);
        uint4 bl1 = *(const uint4*)(blPtr + k0 + 8);
        __syncthreads();
        *(uint4*)(awh)        = ah0;
        *(uint4*)(awh + 1024) = ah1;
        *(uint4*)(awl)        = al0;
        *(uint4*)(awl + 1024) = al1;
        *(uint4*)(bwh)        = bh0;
        *(uint4*)(bwh + 1024) = bh1;
        *(uint4*)(bwl)        = bl0;
        *(uint4*)(bwl + 1024) = bl1;
        __syncthreads();

        bf16x8 ah[4], al[4], bh[4], bl[4];
        #pragma unroll
        for (int mt = 0; mt < 4; mt++) {
            int off = quad * 1024 + (wm + mt * 16 + l15) * 8;
            ah[mt] = *(const bf16x8*)&as_h[off];
            al[mt] = *(const bf16x8*)&as_l[off];
        }
        #pragma unroll
        for (int nt = 0; nt < 4; nt++) {
            int off = quad * 1024 + (wn + nt * 16 + l15) * 8;
            bh[nt] = *(const bf16x8*)&bs_h[off];
            bl[nt] = *(const bf16x8*)&bs_l[off];
        }
        #pragma unroll
        for (int mt = 0; mt < 4; mt++)
            #pragma unroll
            for (int nt = 0; nt < 4; nt++) {
                acc[mt][nt] = __builtin_amdgcn_mfma_f32_16x16x32_bf16(ah[mt], bh[nt], acc[mt][nt], 0, 0, 0);
                acc[mt][nt] = __builtin_amdgcn_mfma_f32_16x16x32_bf16(ah[mt], bl[nt], acc[mt][nt], 0, 0, 0);
                acc[mt][nt] = __builtin_amdgcn_mfma_f32_16x16x32_bf16(al[mt], bh[nt], acc[mt][nt], 0, 0, 0);
            }
    }

    const int z = rowBase >> 11;
    const int s0 = (rowBase & 2047) + wm + quad * 4;
    const size_t obase = (size_t)(z * 16 + h) * 2048;
    #pragma unroll
    for (int nt = 0; nt < 4; nt++) {
        int c = wn + nt * 16 + l15;
        float bb = vb[h * 128 + c];
        #pragma unroll
        for (int mt = 0; mt < 4; mt++)
            #pragma unroll
            for (int r = 0; r < 4; r++) {
                float v = acc[mt][nt][r] + bb;
                u32t u = __float_as_uint(v);
                u32t hb = u & 0xFFFF0000u;
                size_t idx = (obase + s0 + mt * 16 + r) * 128 + c;
                VFh[idx] = (u16t)(hb >> 16);
                VFl[idx] = f2bf(v - __uint_as_float(hb));
            }
    }
}

// ---------------- K2: rotary in-place on QB/KB; V tile-transpose in-place ----------------
__global__ __launch_bounds__(256) void prep_rot_trans(u16t* __restrict__ QB,
                                                      u16t* __restrict__ KB,
                                                      u16t* __restrict__ VTh,
                                                      u16t* __restrict__ VTl) {
    const int bx = blockIdx.x;
    const int st = bx & 63, h = (bx >> 6) & 15, z = bx >> 10;
    const int t = threadIdx.x;
    const size_t base = ((size_t)(z * 16 + h) * 2048 + st * 32) * 128;

    {
        const int r = t >> 3, w = t & 7;
        const int c = w & 3;
        const int s = st * 32 + r;
        u16t* buf = (w < 4) ? QB : KB;
        u16t* p1 = buf + base + (size_t)r * 128 + c * 16;
        u16t* p2 = p1 + 64;
        uint4 a0 = *(uint4*)p1, a1 = *(uint4*)(p1 + 8);
        uint4 b0 = *(uint4*)p2, b1 = *(uint4*)(p2 + 8);
        u32t A[8] = {a0.x, a0.y, a0.z, a0.w, a1.x, a1.y, a1.z, a1.w};
        u32t B[8] = {b0.x, b0.y, b0.z, b0.w, b1.x, b1.y, b1.z, b1.w};
        u32t OA[8], OB[8];
        #pragma unroll
        for (int p = 0; p < 8; p++) {
            float x1a = bf2f((u16t)(A[p] & 0xFFFFu)), x1b = bf2f((u16t)(A[p] >> 16));
            float x2a = bf2f((u16t)(B[p] & 0xFFFFu)), x2b = bf2f((u16t)(B[p] >> 16));
            int j0 = c * 16 + 2 * p;
            float f0 = expf(-0.14391156831212788f * (float)j0);
            float f1 = expf(-0.14391156831212788f * (float)(j0 + 1));
            float sn0, cs0, sn1, cs1;
            sincosf((float)s * f0, &sn0, &cs0);
            sincosf((float)s * f1, &sn1, &cs1);
            OA[p] = pk2(x1a * cs0 - x2a * sn0, x1b * cs1 - x2b * sn1);
            OB[p] = pk2(x2a * cs0 + x1a * sn0, x2b * cs1 + x1b * sn1);
        }
        *(uint4*)p1       = make_uint4(OA[0], OA[1], OA[2], OA[3]);
        *(uint4*)(p1 + 8) = make_uint4(OA[4], OA[5], OA[6], OA[7]);
        *(uint4*)p2       = make_uint4(OB[0], OB[1], OB[2], OB[3]);
        *(uint4*)(p2 + 8) = make_uint4(OB[4], OB[5], OB[6], OB[7]);
    }

    __shared__ u16t vt[128 * 40];
    #pragma unroll
    for (int pass = 0; pass < 2; pass++) {
        u16t* V = pass ? VTl : VTh;
        {
            uint4 a = *(uint4*)(V + base + t * 16);
            uint4 b = *(uint4*)(V + base + t * 16 + 8);
            int row = t >> 3, d0 = (t & 7) * 16;
            u32t W[8] = {a.x, a.y, a.z, a.w, b.x, b.y, b.z, b.w};
            #pragma unroll
            for (int p = 0; p < 8; p++) {
                vt[(d0 + 2 * p) * 40 + row]     = (u16t)(W[p] & 0xFFFFu);
                vt[(d0 + 2 * p + 1) * 40 + row] = (u16t)(W[p] >> 16);
            }
        }
        __syncthreads();
        {
            int d = t >> 1, k0 = (t & 1) * 16;
            uint4 a = *(uint4*)&vt[d * 40 + k0];
            uint4 b = *(uint4*)&vt[d * 40 + k0 + 8];
            *(uint4*)(V + base + t * 16)     = a;
            *(uint4*)(V + base + t * 16 + 8) = b;
        }
        __syncthreads();
    }
}

// ---------------- K3: MFMA attention v2. block = (z,h, 64 queries), 4 waves ----------------
#define ATTSCALE 0.08838834764831845f

__global__ __launch_bounds__(256, 4) void attn_kernel2(const u16t* __restrict__ QB,
                                                       const u16t* __restrict__ KB,
                                                       const u16t* __restrict__ VTh,
                                                       const u16t* __restrict__ VTl,
                                                       const int* __restrict__ mask,
                                                       float* __restrict__ O3) {
    const int blk = blockIdx.x;
    const int qt = blk & 31;
    const int h  = (blk >> 5) & 15;
    const int z  = blk >> 9;
    const int t  = threadIdx.x;
    const int lane = t & 63, wid = t >> 6;
    const int quad = lane >> 4, l15 = lane & 15;
    const int w1 = wid & 1;
    const int kh = wid >> 1;

    __shared__ __align__(16) u16t ks[32 * 136];
    __shared__ __align__(16) u16t vth[128 * 40];
    __shared__ __align__(16) u16t vtl[128 * 40];
    __shared__ __align__(16) float wl[64 * 36];
    __shared__ float dpart[2][64];
    __shared__ int qm[64], km[32];

    const int q0 = qt * 64;
    const size_t zh = (size_t)(z * 16 + h);
    const u16t* qb = QB + zh * 262144;
    const u16t* kb = KB + zh * 262144;
    const u16t* vhg = VTh + zh * 262144;
    const u16t* vlg = VTl + zh * 262144;

    bf16x8 qf[2][4];
    #pragma unroll
    for (int i = 0; i < 2; i++)
        #pragma unroll
        for (int kk = 0; kk < 4; kk++)
            qf[i][kk] = *(const bf16x8*)(qb + (size_t)(q0 + 16 * (w1 + 2 * i) + l15) * 128 + kk * 32 + quad * 8);
    if (t < 64) qm[t] = mask[z * SQ + q0 + t];

    f32x4 acc[2][4];
    #pragma unroll
    for (int i = 0; i < 2; i++)
        #pragma unroll
        for (int d = 0; d < 4; d++) acc[i][d] = (f32x4){0.f, 0.f, 0.f, 0.f};
    float dsum[2][4] = {{0.f, 0.f, 0.f, 0.f}, {0.f, 0.f, 0.f, 0.f}};

    for (int kt = 0; kt < SQ; kt += 32) {
        __syncthreads();
        {
            const u16t* src = kb + (size_t)kt * 128 + t * 16;
            uint4 a = *(const uint4*)(src);
            uint4 b = *(const uint4*)(src + 8);
            int row = t >> 3, co = (t & 7) * 16;
            *(uint4*)&ks[row * 136 + co]     = a;
            *(uint4*)&ks[row * 136 + co + 8] = b;
        }
        {
            const u16t* srch = vhg + (size_t)(kt >> 5) * 4096 + t * 16;
            const u16t* srcl = vlg + (size_t)(kt >> 5) * 4096 + t * 16;
            uint4 a = *(const uint4*)(srch);
            uint4 b = *(const uint4*)(srch + 8);
            uint4 c = *(const uint4*)(srcl);
            uint4 d = *(const uint4*)(srcl + 8);
            int dd = t >> 1, k0 = (t & 1) * 16;
            *(uint4*)&vth[dd * 40 + k0]     = a;
            *(uint4*)&vth[dd * 40 + k0 + 8] = b;
            *(uint4*)&vtl[dd * 40 + k0]     = c;
            *(uint4*)&vtl[dd * 40 + k0 + 8] = d;
        }
        if (t < 32) km[t] = mask[z * SQ + kt + t];
        __syncthreads();

        #pragma unroll
        for (int i = 0; i < 2; i++) {
            const int qsel = w1 + 2 * i;
            f32x4 s4 = (f32x4){0.f, 0.f, 0.f, 0.f};
            #pragma unroll
            for (int kk = 0; kk < 4; kk++) {
                bf16x8 kf = *(const bf16x8*)&ks[(16 * kh + l15) * 136 + kk * 32 + quad * 8];
                s4 = __builtin_amdgcn_mfma_f32_16x16x32_bf16(qf[i][kk], kf, s4, 0, 0, 0);
            }
            int colm = km[16 * kh + l15];
            #pragma unroll
            for (int r = 0; r < 4; r++) {
                int row = 16 * qsel + 4 * quad + r;
                float wv = (qm[row] | colm) ? 0.f : __expf(s4[r] * ATTSCALE);
                dsum[i][r] += wv;
                wl[row * 36 + 16 * kh + l15] = wv;
            }
        }
        __syncthreads();

        union { u16t u[8]; bf16x8 v; } ph[2], pl[2];
        #pragma unroll
        for (int i = 0; i < 2; i++) {
            const float* pr = &wl[(16 * (w1 + 2 * i) + l15) * 36 + quad * 8];
            float4 p0 = *(const float4*)(pr);
            float4 p1 = *(const float4*)(pr + 4);
            float pv[8] = {p0.x, p0.y, p0.z, p0.w, p1.x, p1.y, p1.z, p1.w};
            #pragma unroll
            for (int e = 0; e < 8; e++) {
                u16t hi = f2bf(pv[e]);
                ph[i].u[e] = hi;
                pl[i].u[e] = f2bf(pv[e] - bf2f(hi));
            }
        }
        #pragma unroll
        for (int dt = 0; dt < 4; dt++) {
            int d = 64 * kh + 16 * dt + l15;
            bf16x8 vh = *(const bf16x8*)&vth[d * 40 + quad * 8];
            bf16x8 vl = *(const bf16x8*)&vtl[d * 40 + quad * 8];
            #pragma unroll
            for (int i = 0; i < 2; i++) {
                acc[i][dt] = __builtin_amdgcn_mfma_f32_16x16x32_bf16(ph[i].v, vh, acc[i][dt], 0, 0, 0);
                acc[i][dt] = __builtin_amdgcn_mfma_f32_16x16x32_bf16(ph[i].v, vl, acc[i][dt], 0, 0, 0);
                acc[i][dt] = __builtin_amdgcn_mfma_f32_16x16x32_bf16(pl[i].v, vh, acc[i][dt], 0, 0, 0);
            }
        }
    }

    #pragma unroll
    for (int i = 0; i < 2; i++)
        #pragma unroll
        for (int r = 0; r < 4; r++) {
            float v = dsum[i][r];
            v += __shfl_xor(v, 1);
            v += __shfl_xor(v, 2);
            v += __shfl_xor(v, 4);
            v += __shfl_xor(v, 8);
            dsum[i][r] = v;
        }
    if (l15 == 0) {
        #pragma unroll
        for (int i = 0; i < 2; i++)
            #pragma unroll
            for (int r = 0; r < 4; r++)
                dpart[kh][16 * (w1 + 2 * i) + 4 * quad + r] = dsum[i][r];
    }
    __syncthreads();

    #pragma unroll
    for (int i = 0; i < 2; i++)
        #pragma unroll
        for (int r = 0; r < 4; r++) {
            int row = 16 * (w1 + 2 * i) + 4 * quad + r;
            float den = dpart[0][row] + dpart[1][row];
            float inv = den > 0.f ? 1.f / den : 0.f;
            float* dst = O3 + ((size_t)(z * SQ + q0 + row) * HH + h) * 128;
            #pragma unroll
            for (int dt = 0; dt < 4; dt++)
                dst[64 * kh + 16 * dt + l15] = cubef(acc[i][dt][r] * inv);
        }
}

// ---------------- K4: partial[s] = O3[:, chunk] @ W[chunk, :]  (split-bf16 MFMA) ----------------
__global__ __launch_bounds__(256) void final_gemm_mfma(const float* __restrict__ A,
                                                       const u16t* __restrict__ Bh,
                                                       const u16t* __restrict__ Bl,
                                                       float* __restrict__ part) {
    __shared__ __align__(16) u16t as_h[4 * 128 * 8];
    __shared__ __align__(16) u16t as_l[4 * 128 * 8];
    __shared__ __align__(16) u16t bs_h[4 * 128 * 8];
    __shared__ __align__(16) u16t bs_l[4 * 128 * 8];

    const int t = threadIdx.x;
    const int lane = t & 63, wid = t >> 6;
    const int quad = lane >> 4, l15 = lane & 15;
    const int wm = (wid & 1) * 64;
    const int wn = (wid >> 1) * 64;
    const int rowBase = blockIdx.x * 128;
    const int kBase   = blockIdx.y * (KOUT / KSPLIT);
    const int sm = t & 127;
    const int skh = t >> 7;

    f32x4 acc[4][4];
    #pragma unroll
    for (int i = 0; i < 4; i++)
        #pragma unroll
        for (int j = 0; j < 4; j++) acc[i][j] = (f32x4){0.f, 0.f, 0.f, 0.f};

    const float* aPtr  = A  + (size_t)(rowBase + sm) * KOUT + kBase + skh * 16;
    const u16t*  bhPtr = Bh + (size_t)sm * KOUT + kBase + skh * 16;
    const u16t*  blPtr = Bl + (size_t)sm * KOUT + kBase + skh * 16;
    u16t* awh = &as_h[(skh * 2) * 1024 + sm * 8];
    u16t* awl = &as_l[(skh * 2) * 1024 + sm * 8];
    u16t* bwh = &bs_h[(skh * 2) * 1024 + sm * 8];
    u16t* bwl = &bs_l[(skh * 2) * 1024 + sm * 8];

    for (int k0 = 0; k0 < KOUT / KSPLIT; k0 += 32) {
        float4 a0 = *(const float4*)(aPtr + k0);
        float4 a1 = *(const float4*)(aPtr + k0 + 4);
        float4 a2 = *(const float4*)(aPtr + k0 + 8);
        float4 a3 = *(const float4*)(aPtr + k0 + 12);
        uint4 bh0 = *(const uint4*)(bhPtr + k0);
        uint4 bh1 = *(const uint4*)(bhPtr + k0 + 8);
        uint4 bl0 = *(const uint4*)(blPtr + k0);
        uint4 bl1 = *(const uint4*)(blPtr + k0 + 8);
        uint4 ah0, ah1, al0, al1;
        split2(a0.x, a0.y, ah0.x, al0.x);
        split2(a0.z, a0.w, ah0.y, al0.y);
        split2(a1.x, a1.y, ah0.z, al0.z);
        split2(a1.z, a1.w, ah0.w, al0.w);
        split2(a2.x, a2.y, ah1.x, al1.x);
        split2(a2.z, a2.w, ah1.y, al1.y);
        split2(a3.x, a3.y, ah1.z, al1.z);
        split2(a3.z, a3.w, ah1.w, al1.w);

        __syncthreads();
        *(uint4*)(awh)        = ah0;
        *(uint4*)(awh + 1024) = ah1;
        *(uint4*)(awl)        = al0;
        *(uint4*)(awl + 1024) = al1;
        *(uint4*)(bwh)        = bh0;
        *(uint4*)(bwh + 1024) = bh1;
        *(uint4*)(bwl)        = bl0;
        *(uint4*)(bwl + 1024) = bl1;
        __syncthreads();

        bf16x8 ah[4], al[4], bh[4], bl[4];
        #pragma unroll
        for (int mt = 0; mt < 4; mt++) {
            int off = quad * 1024 + (wm + mt * 16 + l15) * 8;
            ah[mt] = *(const bf16x8*)&as_h[off];
            al[mt] = *(const bf16x8*)&as_l[off];
        }
        #pragma unroll
        for (int nt = 0; nt < 4; nt++) {
            int off = quad * 1024 + (wn + nt * 16 + l15) * 8;
            bh[nt] = *(const bf16x8*)&bs_h[off];
            bl[nt] = *(const bf16x8*)&bs_l[off];
        }
        #pragma unroll
        for (int mt = 0; mt < 4; mt++)
            #pragma unroll
            for (int nt = 0; nt < 4; nt++) {
                acc[mt][nt] = __builtin_amdgcn_mfma_f32_16x16x32_bf16(ah[mt], bh[nt], acc[mt][nt], 0, 0, 0);
                acc[mt][nt] = __builtin_amdgcn_mfma_f32_16x16x32_bf16(ah[mt], bl[nt], acc[mt][nt], 0, 0, 0);
                acc[mt][nt] = __builtin_amdgcn_mfma_f32_16x16x32_bf16(al[mt], bh[nt], acc[mt][nt], 0, 0, 0);
            }
    }

    float* pbase = part + (size_t)blockIdx.y * ((size_t)MROWS * 128);
    #pragma unroll
    for (int mt = 0; mt < 4; mt++)
        #pragma unroll
        for (int nt = 0; nt < 4; nt++) {
            int col = wn + nt * 16 + l15;
            #pragma unroll
            for (int r = 0; r < 4; r++) {
                int row = rowBase + wm + mt * 16 + quad * 4 + r;
                pbase[(size_t)row * 128 + col] = acc[mt][nt][r];
            }
        }
}

// ---------------- K5: out = cube(sum partials + bias) ----------------
__global__ __launch_bounds__(256) void reduce_bias_cube(const float* __restrict__ part,
                                                        const float* __restrict__ bias,
                                                        float* __restrict__ out) {
    const int idx = (blockIdx.x * 256 + threadIdx.x) * 4;
    float4 s = {0.f, 0.f, 0.f, 0.f};
    #pragma unroll
    for (int p = 0; p < KSPLIT; p++) {
        float4 v = *(const float4*)&part[(size_t)p * ((size_t)MROWS * 128) + idx];
        s.x += v.x; s.y += v.y; s.z += v.z; s.w += v.w;
    }
    float4 b = *(const float4*)&bias[idx & 127];
    float4 r;
    r.x = cubef(s.x + b.x);
    r.y = cubef(s.y + b.y);
    r.z = cubef(s.z + b.z);
    r.w = cubef(s.w + b.w);
    *(float4*)&out[idx] = r;
}

extern "C" void kernel_launch(void* const* d_in, const int* in_sizes, int n_in,
                              void* d_out, int out_size, void* d_ws, size_t ws_size,
                              hipStream_t stream) {
    const float* x        = (const float*)d_in[0];
    const int*   mask     = (const int*)d_in[1];
    const float* proj_in  = (const float*)d_in[2];
    const float* v_bias   = (const float*)d_in[3];
    const float* proj_out = (const float*)d_in[4];
    const float* po_bias  = (const float*)d_in[5];
    float* out = (float*)d_out;

    // ws layout (112 MB):
    u16t* QB  = (u16t*)d_ws;                      // 16 MB
    u16t* KB  = QB + (size_t)8388608;             // 16 MB
    u16t* VTh = KB + (size_t)8388608;             // 16 MB
    u16t* VTl = VTh + (size_t)8388608;            // 16 MB
    float* O3 = (float*)(VTl + (size_t)8388608);  // 32 MB
    u16t* xh  = (u16t*)(O3 + (size_t)MROWS * KOUT);  // 8 MB
    u16t* xl  = xh + (size_t)MROWS * DIN;            // 8 MB
    // pT aliases O3 (dead before attn writes O3)
    u16t* pTh = (u16t*)O3;
    u16t* pTl = pTh + (size_t)NT * DIN;
    // WT + partials alias QB/KB (dead after attn)
    u16t* WTh = QB;
    u16t* WTl = WTh + (size_t)128 * KOUT;
    float* partials = (float*)(WTl + (size_t)128 * KOUT);

    split_x<<<(MROWS * DIN) / (256 * 8), 256, 0, stream>>>(x, xh, xl);
    split_transpose_w<<<dim3(NT / 64, DIN / 64), 256, 0, stream>>>(proj_in, pTh, pTl);
    gemm_qk<<<dim3(32, MROWS / 128), 256, 0, stream>>>(xh, pTh, QB, KB);
    gemm_v<<<dim3(16, MROWS / 128), 256, 0, stream>>>(xh, xl, pTh, pTl, v_bias, VTh, VTl);
    prep_rot_trans<<<BZ * HH * (SQ / 32), 256, 0, stream>>>(QB, KB, VTh, VTl);
    attn_kernel2<<<BZ * HH * (SQ / 64), 256, 0, stream>>>(QB, KB, VTh, VTl, mask, O3);
    split_transpose_w2<<<dim3(2, KOUT / 64), 256, 0, stream>>>(proj_out, WTh, WTl);
    final_gemm_mfma<<<dim3(MROWS / 128, KSPLIT), 256, 0, stream>>>(O3, WTh, WTl, partials);
    reduce_bias_cube<<<(MROWS * 128) / (256 * 4), 256, 0, stream>>>(partials, po_bias, out);
}

// Round 8
// 347.428 us; speedup vs baseline: 8.6333x; 1.3819x over previous
//
#include <hip/hip_runtime.h>
#include <math.h>

#define BZ 2
#define SQ 2048
#define DIN 1024
#define HH 16
#define NT 6144
#define MROWS 4096
#define KOUT 2048
#define KSPLIT 8

typedef unsigned short u16t;
typedef unsigned int u32t;
typedef __attribute__((ext_vector_type(8))) short bf16x8;
typedef __attribute__((ext_vector_type(4))) float f32x4;

__device__ __forceinline__ float cubef(float x) { return x * x * x; }

__device__ __forceinline__ u16t f2bf(float f) {          // fp32 -> bf16 RNE (unbiased)
    u32t b = __float_as_uint(f);
    b += 0x7FFFu + ((b >> 16) & 1u);
    return (u16t)(b >> 16);
}
__device__ __forceinline__ float bf2f(u16t u) { return __uint_as_float(((u32t)u) << 16); }
__device__ __forceinline__ u32t pk2(float a, float b) {
    return (u32t)f2bf(a) | ((u32t)f2bf(b) << 16);
}

// ---------------- K0x: x fp32 -> xb bf16 RNE ----------------
__global__ __launch_bounds__(256) void bf16_x(const float* __restrict__ x,
                                              u16t* __restrict__ xb) {
    const size_t idx = ((size_t)blockIdx.x * 256 + threadIdx.x) * 8;
    float4 f0 = *(const float4*)&x[idx];
    float4 f1 = *(const float4*)&x[idx + 4];
    u32t h[4];
    h[0] = pk2(f0.x, f0.y); h[1] = pk2(f0.z, f0.w);
    h[2] = pk2(f1.x, f1.y); h[3] = pk2(f1.z, f1.w);
    *(uint4*)&xb[idx] = *(uint4*)&h[0];
}

// ---------------- K0a: proj_in [k][n] fp32 -> pTh [n][k] bf16 RNE ----------------
__global__ __launch_bounds__(256) void transpose_w(const float* __restrict__ W,
                                                   u16t* __restrict__ Th) {
    __shared__ float tile[64][68];
    const int n0 = blockIdx.x * 64;
    const int k0 = blockIdx.y * 64;
    const int t = threadIdx.x;
    {
        const int r = t >> 4, c = (t & 15) * 4;
        #pragma unroll
        for (int p = 0; p < 4; p++) {
            float4 v = *(const float4*)&W[(size_t)(k0 + r + p * 16) * NT + n0 + c];
            *(float4*)&tile[r + p * 16][c] = v;
        }
    }
    __syncthreads();
    const int nr = t >> 2;
    const int kc = (t & 3) * 16;
    u32t hi[8];
    #pragma unroll
    for (int j = 0; j < 8; j++)
        hi[j] = pk2(tile[kc + 2 * j][nr], tile[kc + 2 * j + 1][nr]);
    size_t ob = (size_t)(n0 + nr) * DIN + k0 + kc;
    *(uint4*)&Th[ob]     = *(uint4*)&hi[0];
    *(uint4*)&Th[ob + 8] = *(uint4*)&hi[4];
}

// ---------------- K0b: proj_out [k][y] fp32 -> WTh [y][k] bf16 RNE ----------------
__global__ __launch_bounds__(256) void transpose_w2(const float* __restrict__ W,
                                                    u16t* __restrict__ Th) {
    __shared__ float tile[64][68];
    const int n0 = blockIdx.x * 64;
    const int k0 = blockIdx.y * 64;
    const int t = threadIdx.x;
    {
        const int r = t >> 4, c = (t & 15) * 4;
        #pragma unroll
        for (int p = 0; p < 4; p++) {
            float4 v = *(const float4*)&W[(size_t)(k0 + r + p * 16) * 128 + n0 + c];
            *(float4*)&tile[r + p * 16][c] = v;
        }
    }
    __syncthreads();
    const int nr = t >> 2;
    const int kc = (t & 3) * 16;
    u32t hi[8];
    #pragma unroll
    for (int j = 0; j < 8; j++)
        hi[j] = pk2(tile[kc + 2 * j][nr], tile[kc + 2 * j + 1][nr]);
    size_t ob = (size_t)(n0 + nr) * KOUT + k0 + kc;
    *(uint4*)&Th[ob]     = *(uint4*)&hi[0];
    *(uint4*)&Th[ob + 8] = *(uint4*)&hi[4];
}

// ---------------- K1: qkv GEMM, 1-term bf16, head-major epilogue ----------------
__global__ __launch_bounds__(256) void gemm_qkv3(const u16t* __restrict__ Ah,
                                                 const u16t* __restrict__ Bh,
                                                 const float* __restrict__ vb,
                                                 u16t* __restrict__ QB,
                                                 u16t* __restrict__ KB,
                                                 u16t* __restrict__ VF) {
    __shared__ __align__(16) u16t as_h[4 * 128 * 8];
    __shared__ __align__(16) u16t bs_h[4 * 128 * 8];

    const int t = threadIdx.x;
    const int lane = t & 63, wid = t >> 6;
    const int quad = lane >> 4, l15 = lane & 15;
    const int wm = (wid & 1) * 64;
    const int wn = (wid >> 1) * 64;
    const int tile = blockIdx.x;               // 0..47 = h*3 + {q,k,v}
    const int h = tile / 3, t3 = tile - h * 3;
    const int colBase = tile * 128;
    const int rowBase = blockIdx.y * 128;
    const int sm = t & 127;
    const int skh = t >> 7;

    f32x4 acc[4][4];
    #pragma unroll
    for (int i = 0; i < 4; i++)
        #pragma unroll
        for (int j = 0; j < 4; j++) acc[i][j] = (f32x4){0.f, 0.f, 0.f, 0.f};

    const u16t* aPtr = Ah + (size_t)(rowBase + sm) * DIN + skh * 16;
    const u16t* bPtr = Bh + (size_t)(colBase + sm) * DIN + skh * 16;
    u16t* aw = &as_h[(skh * 2) * 1024 + sm * 8];
    u16t* bw = &bs_h[(skh * 2) * 1024 + sm * 8];

    for (int k0 = 0; k0 < DIN; k0 += 32) {
        uint4 a0 = *(const uint4*)(aPtr + k0);
        uint4 a1 = *(const uint4*)(aPtr + k0 + 8);
        uint4 b0 = *(const uint4*)(bPtr + k0);
        uint4 b1 = *(const uint4*)(bPtr + k0 + 8);
        __syncthreads();
        *(uint4*)(aw)        = a0;
        *(uint4*)(aw + 1024) = a1;
        *(uint4*)(bw)        = b0;
        *(uint4*)(bw + 1024) = b1;
        __syncthreads();

        bf16x8 ah[4], bh[4];
        #pragma unroll
        for (int mt = 0; mt < 4; mt++)
            ah[mt] = *(const bf16x8*)&as_h[quad * 1024 + (wm + mt * 16 + l15) * 8];
        #pragma unroll
        for (int nt = 0; nt < 4; nt++)
            bh[nt] = *(const bf16x8*)&bs_h[quad * 1024 + (wn + nt * 16 + l15) * 8];
        #pragma unroll
        for (int mt = 0; mt < 4; mt++)
            #pragma unroll
            for (int nt = 0; nt < 4; nt++)
                acc[mt][nt] = __builtin_amdgcn_mfma_f32_16x16x32_bf16(ah[mt], bh[nt], acc[mt][nt], 0, 0, 0);
    }

    const int z = rowBase >> 11;
    const int s0 = (rowBase & 2047) + wm + quad * 4;
    const size_t obase = (size_t)(z * 16 + h) * 2048;
    if (t3 == 2) {
        #pragma unroll
        for (int nt = 0; nt < 4; nt++) {
            int c = wn + nt * 16 + l15;
            float bb = vb[h * 128 + c];
            #pragma unroll
            for (int mt = 0; mt < 4; mt++)
                #pragma unroll
                for (int r = 0; r < 4; r++)
                    VF[(obase + s0 + mt * 16 + r) * 128 + c] = f2bf(acc[mt][nt][r] + bb);
        }
    } else {
        u16t* dst = t3 ? KB : QB;
        #pragma unroll
        for (int nt = 0; nt < 4; nt++) {
            int c = wn + nt * 16 + l15;
            #pragma unroll
            for (int mt = 0; mt < 4; mt++)
                #pragma unroll
                for (int r = 0; r < 4; r++)
                    dst[(obase + s0 + mt * 16 + r) * 128 + c] = f2bf(acc[mt][nt][r]);
        }
    }
}

// ---------------- K2: rotary in-place on QB/KB; V tile-transpose in-place ----------------
__global__ __launch_bounds__(256) void prep_rot_trans(u16t* __restrict__ QB,
                                                      u16t* __restrict__ KB,
                                                      u16t* __restrict__ VTh) {
    const int bx = blockIdx.x;
    const int st = bx & 63, h = (bx >> 6) & 15, z = bx >> 10;
    const int t = threadIdx.x;
    const size_t base = ((size_t)(z * 16 + h) * 2048 + st * 32) * 128;

    {
        const int r = t >> 3, w = t & 7;
        const int c = w & 3;
        const int s = st * 32 + r;
        u16t* buf = (w < 4) ? QB : KB;
        u16t* p1 = buf + base + (size_t)r * 128 + c * 16;
        u16t* p2 = p1 + 64;
        uint4 a0 = *(uint4*)p1, a1 = *(uint4*)(p1 + 8);
        uint4 b0 = *(uint4*)p2, b1 = *(uint4*)(p2 + 8);
        u32t A[8] = {a0.x, a0.y, a0.z, a0.w, a1.x, a1.y, a1.z, a1.w};
        u32t B[8] = {b0.x, b0.y, b0.z, b0.w, b1.x, b1.y, b1.z, b1.w};
        u32t OA[8], OB[8];
        #pragma unroll
        for (int p = 0; p < 8; p++) {
            float x1a = bf2f((u16t)(A[p] & 0xFFFFu)), x1b = bf2f((u16t)(A[p] >> 16));
            float x2a = bf2f((u16t)(B[p] & 0xFFFFu)), x2b = bf2f((u16t)(B[p] >> 16));
            int j0 = c * 16 + 2 * p;
            float f0 = expf(-0.14391156831212788f * (float)j0);
            float f1 = expf(-0.14391156831212788f * (float)(j0 + 1));
            float sn0, cs0, sn1, cs1;
            sincosf((float)s * f0, &sn0, &cs0);
            sincosf((float)s * f1, &sn1, &cs1);
            OA[p] = pk2(x1a * cs0 - x2a * sn0, x1b * cs1 - x2b * sn1);
            OB[p] = pk2(x2a * cs0 + x1a * sn0, x2b * cs1 + x1b * sn1);
        }
        *(uint4*)p1       = make_uint4(OA[0], OA[1], OA[2], OA[3]);
        *(uint4*)(p1 + 8) = make_uint4(OA[4], OA[5], OA[6], OA[7]);
        *(uint4*)p2       = make_uint4(OB[0], OB[1], OB[2], OB[3]);
        *(uint4*)(p2 + 8) = make_uint4(OB[4], OB[5], OB[6], OB[7]);
    }

    __shared__ u16t vt[128 * 40];
    {
        uint4 a = *(uint4*)(VTh + base + t * 16);
        uint4 b = *(uint4*)(VTh + base + t * 16 + 8);
        int row = t >> 3, d0 = (t & 7) * 16;
        u32t W[8] = {a.x, a.y, a.z, a.w, b.x, b.y, b.z, b.w};
        #pragma unroll
        for (int p = 0; p < 8; p++) {
            vt[(d0 + 2 * p) * 40 + row]     = (u16t)(W[p] & 0xFFFFu);
            vt[(d0 + 2 * p + 1) * 40 + row] = (u16t)(W[p] >> 16);
        }
    }
    __syncthreads();
    {
        int d = t >> 1, k0 = (t & 1) * 16;
        uint4 a = *(uint4*)&vt[d * 40 + k0];
        uint4 b = *(uint4*)&vt[d * 40 + k0 + 8];
        *(uint4*)(VTh + base + t * 16)     = a;
        *(uint4*)(VTh + base + t * 16 + 8) = b;
    }
}

// ---------------- K3: MFMA attention v3 — 1-term PV, bf16 P in LDS, bf16 O out ----------------
#define ATTSCALE 0.08838834764831845f

__global__ __launch_bounds__(256, 4) void attn_kernel3(const u16t* __restrict__ QB,
                                                       const u16t* __restrict__ KB,
                                                       const u16t* __restrict__ VTh,
                                                       const int* __restrict__ mask,
                                                       u16t* __restrict__ O3b) {
    const int blk = blockIdx.x;
    const int qt = blk & 31;
    const int h  = (blk >> 5) & 15;
    const int z  = blk >> 9;
    const int t  = threadIdx.x;
    const int lane = t & 63, wid = t >> 6;
    const int quad = lane >> 4, l15 = lane & 15;
    const int w1 = wid & 1;       // q-pair selector: q-16-tiles {w1, w1+2}
    const int kh = wid >> 1;      // k-16-col tile (QK) / d-64 half (PV)

    __shared__ __align__(16) u16t ks[32 * 136];     // K bf16 [row][d], pad 17 chunks (odd)
    __shared__ __align__(16) u16t vth[128 * 40];    // V^T bf16 [d][k], pad 5 chunks (odd)
    __shared__ __align__(16) u16t wlb[64 * 40];     // P bf16 [q][k], pad 5 chunks (odd)
    __shared__ float dpart[2][64];
    __shared__ int qm[64], km[32];

    const int q0 = qt * 64;
    const size_t zh = (size_t)(z * 16 + h);
    const u16t* qb  = QB  + zh * 262144;
    const u16t* kb  = KB  + zh * 262144;
    const u16t* vhg = VTh + zh * 262144;

    bf16x8 qf[2][4];
    #pragma unroll
    for (int i = 0; i < 2; i++)
        #pragma unroll
        for (int kk = 0; kk < 4; kk++)
            qf[i][kk] = *(const bf16x8*)(qb + (size_t)(q0 + 16 * (w1 + 2 * i) + l15) * 128 + kk * 32 + quad * 8);
    if (t < 64) qm[t] = mask[z * SQ + q0 + t];

    f32x4 acc[2][4];
    #pragma unroll
    for (int i = 0; i < 2; i++)
        #pragma unroll
        for (int d = 0; d < 4; d++) acc[i][d] = (f32x4){0.f, 0.f, 0.f, 0.f};
    float dsum[2][4] = {{0.f, 0.f, 0.f, 0.f}, {0.f, 0.f, 0.f, 0.f}};

    for (int kt = 0; kt < SQ; kt += 32) {
        __syncthreads();
        {   // stage K tile (8 KB, contiguous)
            const u16t* src = kb + (size_t)kt * 128 + t * 16;
            uint4 a = *(const uint4*)(src);
            uint4 b = *(const uint4*)(src + 8);
            int row = t >> 3, co = (t & 7) * 16;
            *(uint4*)&ks[row * 136 + co]     = a;
            *(uint4*)&ks[row * 136 + co + 8] = b;
        }
        {   // stage V^T tile (8 KB, contiguous)
            const u16t* srch = vhg + (size_t)(kt >> 5) * 4096 + t * 16;
            uint4 a = *(const uint4*)(srch);
            uint4 b = *(const uint4*)(srch + 8);
            int dd = t >> 1, k0 = (t & 1) * 16;
            *(uint4*)&vth[dd * 40 + k0]     = a;
            *(uint4*)&vth[dd * 40 + k0 + 8] = b;
        }
        if (t < 32) km[t] = mask[z * SQ + kt + t];
        __syncthreads();

        // QK^T (kf hoisted across q-pair)
        f32x4 s4[2] = {(f32x4){0.f, 0.f, 0.f, 0.f}, (f32x4){0.f, 0.f, 0.f, 0.f}};
        #pragma unroll
        for (int kk = 0; kk < 4; kk++) {
            bf16x8 kf = *(const bf16x8*)&ks[(16 * kh + l15) * 136 + kk * 32 + quad * 8];
            s4[0] = __builtin_amdgcn_mfma_f32_16x16x32_bf16(qf[0][kk], kf, s4[0], 0, 0, 0);
            s4[1] = __builtin_amdgcn_mfma_f32_16x16x32_bf16(qf[1][kk], kf, s4[1], 0, 0, 0);
        }
        {   // mask + exp -> bf16 P straight into LDS; fp32 denominator
            int colm = km[16 * kh + l15];
            #pragma unroll
            for (int i = 0; i < 2; i++)
                #pragma unroll
                for (int r = 0; r < 4; r++) {
                    int row = 16 * (w1 + 2 * i) + 4 * quad + r;
                    float wv = (qm[row] | colm) ? 0.f : __expf(s4[i][r] * ATTSCALE);
                    dsum[i][r] += wv;
                    wlb[row * 40 + 16 * kh + l15] = f2bf(wv);
                }
        }
        __syncthreads();

        // P·V: single-term bf16 (A-frag read directly from LDS)
        bf16x8 pa[2];
        #pragma unroll
        for (int i = 0; i < 2; i++)
            pa[i] = *(const bf16x8*)&wlb[(16 * (w1 + 2 * i) + l15) * 40 + quad * 8];
        #pragma unroll
        for (int dt = 0; dt < 4; dt++) {
            int d = 64 * kh + 16 * dt + l15;
            bf16x8 vh = *(const bf16x8*)&vth[d * 40 + quad * 8];
            acc[0][dt] = __builtin_amdgcn_mfma_f32_16x16x32_bf16(pa[0], vh, acc[0][dt], 0, 0, 0);
            acc[1][dt] = __builtin_amdgcn_mfma_f32_16x16x32_bf16(pa[1], vh, acc[1][dt], 0, 0, 0);
        }
    }

    #pragma unroll
    for (int i = 0; i < 2; i++)
        #pragma unroll
        for (int r = 0; r < 4; r++) {
            float v = dsum[i][r];
            v += __shfl_xor(v, 1);
            v += __shfl_xor(v, 2);
            v += __shfl_xor(v, 4);
            v += __shfl_xor(v, 8);
            dsum[i][r] = v;
        }
    if (l15 == 0) {
        #pragma unroll
        for (int i = 0; i < 2; i++)
            #pragma unroll
            for (int r = 0; r < 4; r++)
                dpart[kh][16 * (w1 + 2 * i) + 4 * quad + r] = dsum[i][r];
    }
    __syncthreads();

    // epilogue: normalize, cube, write bf16 O in [m=z*2048+s][k=h*128+d] layout
    #pragma unroll
    for (int i = 0; i < 2; i++)
        #pragma unroll
        for (int r = 0; r < 4; r++) {
            int row = 16 * (w1 + 2 * i) + 4 * quad + r;
            float den = dpart[0][row] + dpart[1][row];
            float inv = den > 0.f ? 1.f / den : 0.f;
            u16t* dst = O3b + (size_t)(z * SQ + q0 + row) * KOUT + h * 128 + 64 * kh;
            #pragma unroll
            for (int dt = 0; dt < 4; dt++)
                dst[16 * dt + l15] = f2bf(cubef(acc[i][dt][r] * inv));
        }
}

// ---------------- K4: partial[s] = O3b[:, chunk] @ W[chunk, :]  (1-term bf16 MFMA) ----------------
__global__ __launch_bounds__(256) void final_gemm2(const u16t* __restrict__ Ab,
                                                   const u16t* __restrict__ Bh,
                                                   float* __restrict__ part) {
    __shared__ __align__(16) u16t as_h[4 * 128 * 8];
    __shared__ __align__(16) u16t bs_h[4 * 128 * 8];

    const int t = threadIdx.x;
    const int lane = t & 63, wid = t >> 6;
    const int quad = lane >> 4, l15 = lane & 15;
    const int wm = (wid & 1) * 64;
    const int wn = (wid >> 1) * 64;
    const int rowBase = blockIdx.x * 128;
    const int kBase   = blockIdx.y * (KOUT / KSPLIT);
    const int sm = t & 127;
    const int skh = t >> 7;

    f32x4 acc[4][4];
    #pragma unroll
    for (int i = 0; i < 4; i++)
        #pragma unroll
        for (int j = 0; j < 4; j++) acc[i][j] = (f32x4){0.f, 0.f, 0.f, 0.f};

    const u16t* aPtr = Ab + (size_t)(rowBase + sm) * KOUT + kBase + skh * 16;
    const u16t* bPtr = Bh + (size_t)sm * KOUT + kBase + skh * 16;
    u16t* aw = &as_h[(skh * 2) * 1024 + sm * 8];
    u16t* bw = &bs_h[(skh * 2) * 1024 + sm * 8];

    for (int k0 = 0; k0 < KOUT / KSPLIT; k0 += 32) {
        uint4 a0 = *(const uint4*)(aPtr + k0);
        uint4 a1 = *(const uint4*)(aPtr + k0 + 8);
        uint4 b0 = *(const uint4*)(bPtr + k0);
        uint4 b1 = *(const uint4*)(bPtr + k0 + 8);
        __syncthreads();
        *(uint4*)(aw)        = a0;
        *(uint4*)(aw + 1024) = a1;
        *(uint4*)(bw)        = b0;
        *(uint4*)(bw + 1024) = b1;
        __syncthreads();

        bf16x8 ah[4], bh[4];
        #pragma unroll
        for (int mt = 0; mt < 4; mt++)
            ah[mt] = *(const bf16x8*)&as_h[quad * 1024 + (wm + mt * 16 + l15) * 8];
        #pragma unroll
        for (int nt = 0; nt < 4; nt++)
            bh[nt] = *(const bf16x8*)&bs_h[quad * 1024 + (wn + nt * 16 + l15) * 8];
        #pragma unroll
        for (int mt = 0; mt < 4; mt++)
            #pragma unroll
            for (int nt = 0; nt < 4; nt++)
                acc[mt][nt] = __builtin_amdgcn_mfma_f32_16x16x32_bf16(ah[mt], bh[nt], acc[mt][nt], 0, 0, 0);
    }

    float* pbase = part + (size_t)blockIdx.y * ((size_t)MROWS * 128);
    #pragma unroll
    for (int mt = 0; mt < 4; mt++)
        #pragma unroll
        for (int nt = 0; nt < 4; nt++) {
            int col = wn + nt * 16 + l15;
            #pragma unroll
            for (int r = 0; r < 4; r++) {
                int row = rowBase + wm + mt * 16 + quad * 4 + r;
                pbase[(size_t)row * 128 + col] = acc[mt][nt][r];
            }
        }
}

// ---------------- K5: out = cube(sum partials + bias) ----------------
__global__ __launch_bounds__(256) void reduce_bias_cube(const float* __restrict__ part,
                                                        const float* __restrict__ bias,
                                                        float* __restrict__ out) {
    const int idx = (blockIdx.x * 256 + threadIdx.x) * 4;
    float4 s = {0.f, 0.f, 0.f, 0.f};
    #pragma unroll
    for (int p = 0; p < KSPLIT; p++) {
        float4 v = *(const float4*)&part[(size_t)p * ((size_t)MROWS * 128) + idx];
        s.x += v.x; s.y += v.y; s.z += v.z; s.w += v.w;
    }
    float4 b = *(const float4*)&bias[idx & 127];
    float4 r;
    r.x = cubef(s.x + b.x);
    r.y = cubef(s.y + b.y);
    r.z = cubef(s.z + b.z);
    r.w = cubef(s.w + b.w);
    *(float4*)&out[idx] = r;
}

extern "C" void kernel_launch(void* const* d_in, const int* in_sizes, int n_in,
                              void* d_out, int out_size, void* d_ws, size_t ws_size,
                              hipStream_t stream) {
    const float* x        = (const float*)d_in[0];
    const int*   mask     = (const int*)d_in[1];
    const float* proj_in  = (const float*)d_in[2];
    const float* v_bias   = (const float*)d_in[3];
    const float* proj_out = (const float*)d_in[4];
    const float* po_bias  = (const float*)d_in[5];
    float* out = (float*)d_out;

    // ws layout (~72 MB):
    u16t* QB  = (u16t*)d_ws;                      // [z,h,s,d] bf16 16 MB
    u16t* KB  = QB + (size_t)8388608;             // 16 MB
    u16t* VTh = KB + (size_t)8388608;             // 16 MB ([s][d] from gemm, [d][s]-tiled after prep)
    u16t* xb  = VTh + (size_t)8388608;            // [4096,1024] bf16 8 MB
    u16t* O3b = xb + (size_t)4194304;             // [4096,2048] bf16 16 MB
    // pTh aliases O3b (dead before attn writes O3b; gemm reads complete first — stream order)
    u16t* pTh = O3b;                              // [6144,1024] bf16 12.6 MB
    // WTh + partials alias QB/KB (dead after attn)
    u16t* WTh = QB;                               // [128,2048] bf16 0.5 MB
    float* partials = (float*)(WTh + (size_t)128 * KOUT);  // [8,4096,128] f32 16 MB

    bf16_x<<<(MROWS * DIN) / (256 * 8), 256, 0, stream>>>(x, xb);
    transpose_w<<<dim3(NT / 64, DIN / 64), 256, 0, stream>>>(proj_in, pTh);
    gemm_qkv3<<<dim3(48, MROWS / 128), 256, 0, stream>>>(xb, pTh, v_bias, QB, KB, VTh);
    prep_rot_trans<<<BZ * HH * (SQ / 32), 256, 0, stream>>>(QB, KB, VTh);
    attn_kernel3<<<BZ * HH * (SQ / 64), 256, 0, stream>>>(QB, KB, VTh, mask, O3b);
    transpose_w2<<<dim3(2, KOUT / 64), 256, 0, stream>>>(proj_out, WTh);
    final_gemm2<<<dim3(MROWS / 128, KSPLIT), 256, 0, stream>>>(O3b, WTh, partials);
    reduce_bias_cube<<<(MROWS * 128) / (256 * 4), 256, 0, stream>>>(partials, po_bias, out);
}

// Round 9
// 344.569 us; speedup vs baseline: 8.7050x; 1.0083x over previous
//
#include <hip/hip_runtime.h>
#include <math.h>

#define BZ 2
#define SQ 2048
#define DIN 1024
#define HH 16
#define NT 6144
#define MROWS 4096
#define KOUT 2048
#define KSPLIT 8

typedef unsigned short u16t;
typedef unsigned int u32t;
typedef __attribute__((ext_vector_type(8))) short bf16x8;
typedef __attribute__((ext_vector_type(4))) float f32x4;

__device__ __forceinline__ float cubef(float x) { return x * x * x; }

__device__ __forceinline__ u16t f2bf(float f) {          // fp32 -> bf16 RNE (unbiased)
    u32t b = __float_as_uint(f);
    b += 0x7FFFu + ((b >> 16) & 1u);
    return (u16t)(b >> 16);
}
__device__ __forceinline__ float bf2f(u16t u) { return __uint_as_float(((u32t)u) << 16); }
__device__ __forceinline__ u32t pk2(float a, float b) {
    return (u32t)f2bf(a) | ((u32t)f2bf(b) << 16);
}

// ---------------- K0x: x fp32 -> xb bf16 RNE ----------------
__global__ __launch_bounds__(256) void bf16_x(const float* __restrict__ x,
                                              u16t* __restrict__ xb) {
    const size_t idx = ((size_t)blockIdx.x * 256 + threadIdx.x) * 8;
    float4 f0 = *(const float4*)&x[idx];
    float4 f1 = *(const float4*)&x[idx + 4];
    u32t h[4];
    h[0] = pk2(f0.x, f0.y); h[1] = pk2(f0.z, f0.w);
    h[2] = pk2(f1.x, f1.y); h[3] = pk2(f1.z, f1.w);
    *(uint4*)&xb[idx] = *(uint4*)&h[0];
}

// ---------------- K0a: proj_in [k][n] fp32 -> pTh [n][k] bf16 RNE ----------------
__global__ __launch_bounds__(256) void transpose_w(const float* __restrict__ W,
                                                   u16t* __restrict__ Th) {
    __shared__ float tile[64][68];
    const int n0 = blockIdx.x * 64;
    const int k0 = blockIdx.y * 64;
    const int t = threadIdx.x;
    {
        const int r = t >> 4, c = (t & 15) * 4;
        #pragma unroll
        for (int p = 0; p < 4; p++) {
            float4 v = *(const float4*)&W[(size_t)(k0 + r + p * 16) * NT + n0 + c];
            *(float4*)&tile[r + p * 16][c] = v;
        }
    }
    __syncthreads();
    const int nr = t >> 2;
    const int kc = (t & 3) * 16;
    u32t hi[8];
    #pragma unroll
    for (int j = 0; j < 8; j++)
        hi[j] = pk2(tile[kc + 2 * j][nr], tile[kc + 2 * j + 1][nr]);
    size_t ob = (size_t)(n0 + nr) * DIN + k0 + kc;
    *(uint4*)&Th[ob]     = *(uint4*)&hi[0];
    *(uint4*)&Th[ob + 8] = *(uint4*)&hi[4];
}

// ---------------- K0b: proj_out [k][y] fp32 -> WTh [y][k] bf16 RNE ----------------
__global__ __launch_bounds__(256) void transpose_w2(const float* __restrict__ W,
                                                    u16t* __restrict__ Th) {
    __shared__ float tile[64][68];
    const int n0 = blockIdx.x * 64;
    const int k0 = blockIdx.y * 64;
    const int t = threadIdx.x;
    {
        const int r = t >> 4, c = (t & 15) * 4;
        #pragma unroll
        for (int p = 0; p < 4; p++) {
            float4 v = *(const float4*)&W[(size_t)(k0 + r + p * 16) * 128 + n0 + c];
            *(float4*)&tile[r + p * 16][c] = v;
        }
    }
    __syncthreads();
    const int nr = t >> 2;
    const int kc = (t & 3) * 16;
    u32t hi[8];
    #pragma unroll
    for (int j = 0; j < 8; j++)
        hi[j] = pk2(tile[kc + 2 * j][nr], tile[kc + 2 * j + 1][nr]);
    size_t ob = (size_t)(n0 + nr) * KOUT + k0 + kc;
    *(uint4*)&Th[ob]     = *(uint4*)&hi[0];
    *(uint4*)&Th[ob + 8] = *(uint4*)&hi[4];
}

// ---------------- K1: qkv GEMM, 1-term bf16, head-major epilogue ----------------
__global__ __launch_bounds__(256) void gemm_qkv3(const u16t* __restrict__ Ah,
                                                 const u16t* __restrict__ Bh,
                                                 const float* __restrict__ vb,
                                                 u16t* __restrict__ QB,
                                                 u16t* __restrict__ KB,
                                                 u16t* __restrict__ VF) {
    __shared__ __align__(16) u16t as_h[4 * 128 * 8];
    __shared__ __align__(16) u16t bs_h[4 * 128 * 8];

    const int t = threadIdx.x;
    const int lane = t & 63, wid = t >> 6;
    const int quad = lane >> 4, l15 = lane & 15;
    const int wm = (wid & 1) * 64;
    const int wn = (wid >> 1) * 64;
    const int tile = blockIdx.x;               // 0..47 = h*3 + {q,k,v}
    const int h = tile / 3, t3 = tile - h * 3;
    const int colBase = tile * 128;
    const int rowBase = blockIdx.y * 128;
    const int sm = t & 127;
    const int skh = t >> 7;

    f32x4 acc[4][4];
    #pragma unroll
    for (int i = 0; i < 4; i++)
        #pragma unroll
        for (int j = 0; j < 4; j++) acc[i][j] = (f32x4){0.f, 0.f, 0.f, 0.f};

    const u16t* aPtr = Ah + (size_t)(rowBase + sm) * DIN + skh * 16;
    const u16t* bPtr = Bh + (size_t)(colBase + sm) * DIN + skh * 16;
    u16t* aw = &as_h[(skh * 2) * 1024 + sm * 8];
    u16t* bw = &bs_h[(skh * 2) * 1024 + sm * 8];

    for (int k0 = 0; k0 < DIN; k0 += 32) {
        uint4 a0 = *(const uint4*)(aPtr + k0);
        uint4 a1 = *(const uint4*)(aPtr + k0 + 8);
        uint4 b0 = *(const uint4*)(bPtr + k0);
        uint4 b1 = *(const uint4*)(bPtr + k0 + 8);
        __syncthreads();
        *(uint4*)(aw)        = a0;
        *(uint4*)(aw + 1024) = a1;
        *(uint4*)(bw)        = b0;
        *(uint4*)(bw + 1024) = b1;
        __syncthreads();

        bf16x8 ah[4], bh[4];
        #pragma unroll
        for (int mt = 0; mt < 4; mt++)
            ah[mt] = *(const bf16x8*)&as_h[quad * 1024 + (wm + mt * 16 + l15) * 8];
        #pragma unroll
        for (int nt = 0; nt < 4; nt++)
            bh[nt] = *(const bf16x8*)&bs_h[quad * 1024 + (wn + nt * 16 + l15) * 8];
        #pragma unroll
        for (int mt = 0; mt < 4; mt++)
            #pragma unroll
            for (int nt = 0; nt < 4; nt++)
                acc[mt][nt] = __builtin_amdgcn_mfma_f32_16x16x32_bf16(ah[mt], bh[nt], acc[mt][nt], 0, 0, 0);
    }

    const int z = rowBase >> 11;
    const int s0 = (rowBase & 2047) + wm + quad * 4;
    const size_t obase = (size_t)(z * 16 + h) * 2048;
    if (t3 == 2) {
        #pragma unroll
        for (int nt = 0; nt < 4; nt++) {
            int c = wn + nt * 16 + l15;
            float bb = vb[h * 128 + c];
            #pragma unroll
            for (int mt = 0; mt < 4; mt++)
                #pragma unroll
                for (int r = 0; r < 4; r++)
                    VF[(obase + s0 + mt * 16 + r) * 128 + c] = f2bf(acc[mt][nt][r] + bb);
        }
    } else {
        u16t* dst = t3 ? KB : QB;
        #pragma unroll
        for (int nt = 0; nt < 4; nt++) {
            int c = wn + nt * 16 + l15;
            #pragma unroll
            for (int mt = 0; mt < 4; mt++)
                #pragma unroll
                for (int r = 0; r < 4; r++)
                    dst[(obase + s0 + mt * 16 + r) * 128 + c] = f2bf(acc[mt][nt][r]);
        }
    }
}

// ---------------- K2: rotary in-place on QB/KB; V tile-transpose in-place ----------------
__global__ __launch_bounds__(256) void prep_rot_trans(u16t* __restrict__ QB,
                                                      u16t* __restrict__ KB,
                                                      u16t* __restrict__ VTh) {
    const int bx = blockIdx.x;
    const int st = bx & 63, h = (bx >> 6) & 15, z = bx >> 10;
    const int t = threadIdx.x;
    const size_t base = ((size_t)(z * 16 + h) * 2048 + st * 32) * 128;

    {
        const int r = t >> 3, w = t & 7;
        const int c = w & 3;
        const int s = st * 32 + r;
        u16t* buf = (w < 4) ? QB : KB;
        u16t* p1 = buf + base + (size_t)r * 128 + c * 16;
        u16t* p2 = p1 + 64;
        uint4 a0 = *(uint4*)p1, a1 = *(uint4*)(p1 + 8);
        uint4 b0 = *(uint4*)p2, b1 = *(uint4*)(p2 + 8);
        u32t A[8] = {a0.x, a0.y, a0.z, a0.w, a1.x, a1.y, a1.z, a1.w};
        u32t B[8] = {b0.x, b0.y, b0.z, b0.w, b1.x, b1.y, b1.z, b1.w};
        u32t OA[8], OB[8];
        #pragma unroll
        for (int p = 0; p < 8; p++) {
            float x1a = bf2f((u16t)(A[p] & 0xFFFFu)), x1b = bf2f((u16t)(A[p] >> 16));
            float x2a = bf2f((u16t)(B[p] & 0xFFFFu)), x2b = bf2f((u16t)(B[p] >> 16));
            int j0 = c * 16 + 2 * p;
            float f0 = expf(-0.14391156831212788f * (float)j0);
            float f1 = expf(-0.14391156831212788f * (float)(j0 + 1));
            float sn0, cs0, sn1, cs1;
            sincosf((float)s * f0, &sn0, &cs0);
            sincosf((float)s * f1, &sn1, &cs1);
            OA[p] = pk2(x1a * cs0 - x2a * sn0, x1b * cs1 - x2b * sn1);
            OB[p] = pk2(x2a * cs0 + x1a * sn0, x2b * cs1 + x1b * sn1);
        }
        *(uint4*)p1       = make_uint4(OA[0], OA[1], OA[2], OA[3]);
        *(uint4*)(p1 + 8) = make_uint4(OA[4], OA[5], OA[6], OA[7]);
        *(uint4*)p2       = make_uint4(OB[0], OB[1], OB[2], OB[3]);
        *(uint4*)(p2 + 8) = make_uint4(OB[4], OB[5], OB[6], OB[7]);
    }

    __shared__ u16t vt[128 * 40];
    {
        uint4 a = *(uint4*)(VTh + base + t * 16);
        uint4 b = *(uint4*)(VTh + base + t * 16 + 8);
        int row = t >> 3, d0 = (t & 7) * 16;
        u32t W[8] = {a.x, a.y, a.z, a.w, b.x, b.y, b.z, b.w};
        #pragma unroll
        for (int p = 0; p < 8; p++) {
            vt[(d0 + 2 * p) * 40 + row]     = (u16t)(W[p] & 0xFFFFu);
            vt[(d0 + 2 * p + 1) * 40 + row] = (u16t)(W[p] >> 16);
        }
    }
    __syncthreads();
    {
        int d = t >> 1, k0 = (t & 1) * 16;
        uint4 a = *(uint4*)&vt[d * 40 + k0];
        uint4 b = *(uint4*)&vt[d * 40 + k0 + 8];
        *(uint4*)(VTh + base + t * 16)     = a;
        *(uint4*)(VTh + base + t * 16 + 8) = b;
    }
}

// ---------------- K3: MFMA attention v4 — 128-q blocks, wave-private P, 2 barriers/iter ----------------
#define ATTSCALE 0.08838834764831845f

__global__ __launch_bounds__(256, 3) void attn_kernel4(const u16t* __restrict__ QB,
                                                       const u16t* __restrict__ KB,
                                                       const u16t* __restrict__ VTh,
                                                       const int* __restrict__ mask,
                                                       u16t* __restrict__ O3b) {
    const int blk = blockIdx.x;
    const int qt = blk & 15;           // 16 q-blocks of 128
    const int h  = (blk >> 4) & 15;
    const int z  = blk >> 8;
    const int t  = threadIdx.x;
    const int lane = t & 63, wid = t >> 6;
    const int quad = lane >> 4, l15 = lane & 15;

    __shared__ __align__(16) u16t ks[32 * 136];     // K bf16 [key][d]
    __shared__ __align__(16) u16t vth[128 * 40];    // V^T bf16 [d][key]
    __shared__ __align__(16) u16t wlb[128 * 40];    // P bf16 [q][key] (wave-private rows)
    __shared__ int qm[128], km[32];

    const int q0 = qt * 128;
    const size_t zh = (size_t)(z * 16 + h);
    const u16t* qb  = QB  + zh * 262144;
    const u16t* kb  = KB  + zh * 262144;
    const u16t* vhg = VTh + zh * 262144;

    // wave owns q-16-tiles {2*wid, 2*wid+1}
    bf16x8 qf[2][4];
    #pragma unroll
    for (int i = 0; i < 2; i++)
        #pragma unroll
        for (int kk = 0; kk < 4; kk++)
            qf[i][kk] = *(const bf16x8*)(qb + (size_t)(q0 + 16 * (2 * wid + i) + l15) * 128 + kk * 32 + quad * 8);
    if (t < 128) qm[t] = mask[z * SQ + q0 + t];

    f32x4 acc[2][8];
    #pragma unroll
    for (int i = 0; i < 2; i++)
        #pragma unroll
        for (int d = 0; d < 8; d++) acc[i][d] = (f32x4){0.f, 0.f, 0.f, 0.f};
    float dsum[2][4] = {{0.f, 0.f, 0.f, 0.f}, {0.f, 0.f, 0.f, 0.f}};

    for (int kt = 0; kt < SQ; kt += 32) {
        __syncthreads();      // prior-iter ks/vth reads complete
        {   // stage K tile (8 KB, contiguous)
            const u16t* src = kb + (size_t)kt * 128 + t * 16;
            uint4 a = *(const uint4*)(src);
            uint4 b = *(const uint4*)(src + 8);
            int row = t >> 3, co = (t & 7) * 16;
            *(uint4*)&ks[row * 136 + co]     = a;
            *(uint4*)&ks[row * 136 + co + 8] = b;
        }
        {   // stage V^T tile (8 KB, contiguous)
            const u16t* srch = vhg + (size_t)(kt >> 5) * 4096 + t * 16;
            uint4 a = *(const uint4*)(srch);
            uint4 b = *(const uint4*)(srch + 8);
            int dd = t >> 1, k0 = (t & 1) * 16;
            *(uint4*)&vth[dd * 40 + k0]     = a;
            *(uint4*)&vth[dd * 40 + k0 + 8] = b;
        }
        if (t < 32) km[t] = mask[z * SQ + kt + t];
        __syncthreads();

        // QK^T: 2 q-tiles x 2 key-cols, kf shared across q
        f32x4 s4[2][2];
        #pragma unroll
        for (int i = 0; i < 2; i++)
            #pragma unroll
            for (int n = 0; n < 2; n++) s4[i][n] = (f32x4){0.f, 0.f, 0.f, 0.f};
        #pragma unroll
        for (int kk = 0; kk < 4; kk++) {
            bf16x8 kf0 = *(const bf16x8*)&ks[l15 * 136 + kk * 32 + quad * 8];
            bf16x8 kf1 = *(const bf16x8*)&ks[(16 + l15) * 136 + kk * 32 + quad * 8];
            s4[0][0] = __builtin_amdgcn_mfma_f32_16x16x32_bf16(qf[0][kk], kf0, s4[0][0], 0, 0, 0);
            s4[0][1] = __builtin_amdgcn_mfma_f32_16x16x32_bf16(qf[0][kk], kf1, s4[0][1], 0, 0, 0);
            s4[1][0] = __builtin_amdgcn_mfma_f32_16x16x32_bf16(qf[1][kk], kf0, s4[1][0], 0, 0, 0);
            s4[1][1] = __builtin_amdgcn_mfma_f32_16x16x32_bf16(qf[1][kk], kf1, s4[1][1], 0, 0, 0);
        }
        {   // mask + exp -> bf16 P into wave-private LDS rows; fp32 denominator
            int colm0 = km[l15], colm1 = km[16 + l15];
            #pragma unroll
            for (int i = 0; i < 2; i++)
                #pragma unroll
                for (int r = 0; r < 4; r++) {
                    int row = 16 * (2 * wid + i) + 4 * quad + r;
                    int qmr = qm[row];
                    float w0 = (qmr | colm0) ? 0.f : __expf(s4[i][0][r] * ATTSCALE);
                    float w1 = (qmr | colm1) ? 0.f : __expf(s4[i][1][r] * ATTSCALE);
                    dsum[i][r] += w0 + w1;
                    wlb[row * 40 + l15]      = f2bf(w0);
                    wlb[row * 40 + 16 + l15] = f2bf(w1);
                }
        }
        // P·V: same-wave read-back (no barrier — wave-private rows, lgkmcnt ordering)
        bf16x8 pa[2];
        #pragma unroll
        for (int i = 0; i < 2; i++)
            pa[i] = *(const bf16x8*)&wlb[(16 * (2 * wid + i) + l15) * 40 + quad * 8];
        #pragma unroll
        for (int dt = 0; dt < 8; dt++) {
            bf16x8 vh = *(const bf16x8*)&vth[(16 * dt + l15) * 40 + quad * 8];
            acc[0][dt] = __builtin_amdgcn_mfma_f32_16x16x32_bf16(pa[0], vh, acc[0][dt], 0, 0, 0);
            acc[1][dt] = __builtin_amdgcn_mfma_f32_16x16x32_bf16(pa[1], vh, acc[1][dt], 0, 0, 0);
        }
    }

    // denominator: complete within wave — 16-lane shuffle reduce
    #pragma unroll
    for (int i = 0; i < 2; i++)
        #pragma unroll
        for (int r = 0; r < 4; r++) {
            float v = dsum[i][r];
            v += __shfl_xor(v, 1);
            v += __shfl_xor(v, 2);
            v += __shfl_xor(v, 4);
            v += __shfl_xor(v, 8);
            dsum[i][r] = v;
        }

    // epilogue: normalize, cube, write bf16 O in [m=z*2048+s][k=h*128+d]
    #pragma unroll
    for (int i = 0; i < 2; i++)
        #pragma unroll
        for (int r = 0; r < 4; r++) {
            int row = 16 * (2 * wid + i) + 4 * quad + r;
            float den = dsum[i][r];
            float inv = den > 0.f ? 1.f / den : 0.f;
            u16t* dst = O3b + (size_t)(z * SQ + q0 + row) * KOUT + h * 128;
            #pragma unroll
            for (int dt = 0; dt < 8; dt++)
                dst[16 * dt + l15] = f2bf(cubef(acc[i][dt][r] * inv));
        }
}

// ---------------- K4: partial[s] = O3b[:, chunk] @ W[chunk, :]  (1-term bf16 MFMA) ----------------
__global__ __launch_bounds__(256) void final_gemm2(const u16t* __restrict__ Ab,
                                                   const u16t* __restrict__ Bh,
                                                   float* __restrict__ part) {
    __shared__ __align__(16) u16t as_h[4 * 128 * 8];
    __shared__ __align__(16) u16t bs_h[4 * 128 * 8];

    const int t = threadIdx.x;
    const int lane = t & 63, wid = t >> 6;
    const int quad = lane >> 4, l15 = lane & 15;
    const int wm = (wid & 1) * 64;
    const int wn = (wid >> 1) * 64;
    const int rowBase = blockIdx.x * 128;
    const int kBase   = blockIdx.y * (KOUT / KSPLIT);
    const int sm = t & 127;
    const int skh = t >> 7;

    f32x4 acc[4][4];
    #pragma unroll
    for (int i = 0; i < 4; i++)
        #pragma unroll
        for (int j = 0; j < 4; j++) acc[i][j] = (f32x4){0.f, 0.f, 0.f, 0.f};

    const u16t* aPtr = Ab + (size_t)(rowBase + sm) * KOUT + kBase + skh * 16;
    const u16t* bPtr = Bh + (size_t)sm * KOUT + kBase + skh * 16;
    u16t* aw = &as_h[(skh * 2) * 1024 + sm * 8];
    u16t* bw = &bs_h[(skh * 2) * 1024 + sm * 8];

    for (int k0 = 0; k0 < KOUT / KSPLIT; k0 += 32) {
        uint4 a0 = *(const uint4*)(aPtr + k0);
        uint4 a1 = *(const uint4*)(aPtr + k0 + 8);
        uint4 b0 = *(const uint4*)(bPtr + k0);
        uint4 b1 = *(const uint4*)(bPtr + k0 + 8);
        __syncthreads();
        *(uint4*)(aw)        = a0;
        *(uint4*)(aw + 1024) = a1;
        *(uint4*)(bw)        = b0;
        *(uint4*)(bw + 1024) = b1;
        __syncthreads();

        bf16x8 ah[4], bh[4];
        #pragma unroll
        for (int mt = 0; mt < 4; mt++)
            ah[mt] = *(const bf16x8*)&as_h[quad * 1024 + (wm + mt * 16 + l15) * 8];
        #pragma unroll
        for (int nt = 0; nt < 4; nt++)
            bh[nt] = *(const bf16x8*)&bs_h[quad * 1024 + (wn + nt * 16 + l15) * 8];
        #pragma unroll
        for (int mt = 0; mt < 4; mt++)
            #pragma unroll
            for (int nt = 0; nt < 4; nt++)
                acc[mt][nt] = __builtin_amdgcn_mfma_f32_16x16x32_bf16(ah[mt], bh[nt], acc[mt][nt], 0, 0, 0);
    }

    float* pbase = part + (size_t)blockIdx.y * ((size_t)MROWS * 128);
    #pragma unroll
    for (int mt = 0; mt < 4; mt++)
        #pragma unroll
        for (int nt = 0; nt < 4; nt++) {
            int col = wn + nt * 16 + l15;
            #pragma unroll
            for (int r = 0; r < 4; r++) {
                int row = rowBase + wm + mt * 16 + quad * 4 + r;
                pbase[(size_t)row * 128 + col] = acc[mt][nt][r];
            }
        }
}

// ---------------- K5: out = cube(sum partials + bias) ----------------
__global__ __launch_bounds__(256) void reduce_bias_cube(const float* __restrict__ part,
                                                        const float* __restrict__ bias,
                                                        float* __restrict__ out) {
    const int idx = (blockIdx.x * 256 + threadIdx.x) * 4;
    float4 s = {0.f, 0.f, 0.f, 0.f};
    #pragma unroll
    for (int p = 0; p < KSPLIT; p++) {
        float4 v = *(const float4*)&part[(size_t)p * ((size_t)MROWS * 128) + idx];
        s.x += v.x; s.y += v.y; s.z += v.z; s.w += v.w;
    }
    float4 b = *(const float4*)&bias[idx & 127];
    float4 r;
    r.x = cubef(s.x + b.x);
    r.y = cubef(s.y + b.y);
    r.z = cubef(s.z + b.z);
    r.w = cubef(s.w + b.w);
    *(float4*)&out[idx] = r;
}

extern "C" void kernel_launch(void* const* d_in, const int* in_sizes, int n_in,
                              void* d_out, int out_size, void* d_ws, size_t ws_size,
                              hipStream_t stream) {
    const float* x        = (const float*)d_in[0];
    const int*   mask     = (const int*)d_in[1];
    const float* proj_in  = (const float*)d_in[2];
    const float* v_bias   = (const float*)d_in[3];
    const float* proj_out = (const float*)d_in[4];
    const float* po_bias  = (const float*)d_in[5];
    float* out = (float*)d_out;

    // ws layout (~72 MB):
    u16t* QB  = (u16t*)d_ws;                      // [z,h,s,d] bf16 16 MB
    u16t* KB  = QB + (size_t)8388608;             // 16 MB
    u16t* VTh = KB + (size_t)8388608;             // 16 MB ([s][d] from gemm, [d][s]-tiled after prep)
    u16t* xb  = VTh + (size_t)8388608;            // [4096,1024] bf16 8 MB
    u16t* O3b = xb + (size_t)4194304;             // [4096,2048] bf16 16 MB
    // pTh aliases O3b (dead before attn writes O3b; gemm reads complete first — stream order)
    u16t* pTh = O3b;                              // [6144,1024] bf16 12.6 MB
    // WTh + partials alias QB/KB (dead after attn)
    u16t* WTh = QB;                               // [128,2048] bf16 0.5 MB
    float* partials = (float*)(WTh + (size_t)128 * KOUT);  // [8,4096,128] f32 16 MB

    bf16_x<<<(MROWS * DIN) / (256 * 8), 256, 0, stream>>>(x, xb);
    transpose_w<<<dim3(NT / 64, DIN / 64), 256, 0, stream>>>(proj_in, pTh);
    gemm_qkv3<<<dim3(48, MROWS / 128), 256, 0, stream>>>(xb, pTh, v_bias, QB, KB, VTh);
    prep_rot_trans<<<BZ * HH * (SQ / 32), 256, 0, stream>>>(QB, KB, VTh);
    attn_kernel4<<<BZ * HH * (SQ / 128), 256, 0, stream>>>(QB, KB, VTh, mask, O3b);
    transpose_w2<<<dim3(2, KOUT / 64), 256, 0, stream>>>(proj_out, WTh);
    final_gemm2<<<dim3(MROWS / 128, KSPLIT), 256, 0, stream>>>(O3b, WTh, partials);
    reduce_bias_cube<<<(MROWS * 128) / (256 * 4), 256, 0, stream>>>(partials, po_bias, out);
}

// Round 10
// 335.109 us; speedup vs baseline: 8.9507x; 1.0282x over previous
//
#include <hip/hip_runtime.h>
#include <math.h>

#define BZ 2
#define SQ 2048
#define DIN 1024
#define HH 16
#define NT 6144
#define MROWS 4096
#define KOUT 2048
#define KSPLIT 8

typedef unsigned short u16t;
typedef unsigned int u32t;
typedef __attribute__((ext_vector_type(8))) short bf16x8;
typedef __attribute__((ext_vector_type(4))) float f32x4;

__device__ __forceinline__ float cubef(float x) { return x * x * x; }

__device__ __forceinline__ u16t f2bf(float f) {          // fp32 -> bf16 RNE (unbiased)
    u32t b = __float_as_uint(f);
    b += 0x7FFFu + ((b >> 16) & 1u);
    return (u16t)(b >> 16);
}
__device__ __forceinline__ float bf2f(u16t u) { return __uint_as_float(((u32t)u) << 16); }
__device__ __forceinline__ u32t pk2(float a, float b) {
    return (u32t)f2bf(a) | ((u32t)f2bf(b) << 16);
}

// ---------------- K0x: x fp32 -> xb bf16 RNE ----------------
__global__ __launch_bounds__(256) void bf16_x(const float* __restrict__ x,
                                              u16t* __restrict__ xb) {
    const size_t idx = ((size_t)blockIdx.x * 256 + threadIdx.x) * 8;
    float4 f0 = *(const float4*)&x[idx];
    float4 f1 = *(const float4*)&x[idx + 4];
    u32t h[4];
    h[0] = pk2(f0.x, f0.y); h[1] = pk2(f0.z, f0.w);
    h[2] = pk2(f1.x, f1.y); h[3] = pk2(f1.z, f1.w);
    *(uint4*)&xb[idx] = *(uint4*)&h[0];
}

// ---------------- K0a: proj_in [k][n] fp32 -> pTh [n][k] bf16 RNE ----------------
__global__ __launch_bounds__(256) void transpose_w(const float* __restrict__ W,
                                                   u16t* __restrict__ Th) {
    __shared__ float tile[64][68];
    const int n0 = blockIdx.x * 64;
    const int k0 = blockIdx.y * 64;
    const int t = threadIdx.x;
    {
        const int r = t >> 4, c = (t & 15) * 4;
        #pragma unroll
        for (int p = 0; p < 4; p++) {
            float4 v = *(const float4*)&W[(size_t)(k0 + r + p * 16) * NT + n0 + c];
            *(float4*)&tile[r + p * 16][c] = v;
        }
    }
    __syncthreads();
    const int nr = t >> 2;
    const int kc = (t & 3) * 16;
    u32t hi[8];
    #pragma unroll
    for (int j = 0; j < 8; j++)
        hi[j] = pk2(tile[kc + 2 * j][nr], tile[kc + 2 * j + 1][nr]);
    size_t ob = (size_t)(n0 + nr) * DIN + k0 + kc;
    *(uint4*)&Th[ob]     = *(uint4*)&hi[0];
    *(uint4*)&Th[ob + 8] = *(uint4*)&hi[4];
}

// ---------------- K0b: proj_out [k][y] fp32 -> WTh [y][k] bf16 RNE ----------------
__global__ __launch_bounds__(256) void transpose_w2(const float* __restrict__ W,
                                                    u16t* __restrict__ Th) {
    __shared__ float tile[64][68];
    const int n0 = blockIdx.x * 64;
    const int k0 = blockIdx.y * 64;
    const int t = threadIdx.x;
    {
        const int r = t >> 4, c = (t & 15) * 4;
        #pragma unroll
        for (int p = 0; p < 4; p++) {
            float4 v = *(const float4*)&W[(size_t)(k0 + r + p * 16) * 128 + n0 + c];
            *(float4*)&tile[r + p * 16][c] = v;
        }
    }
    __syncthreads();
    const int nr = t >> 2;
    const int kc = (t & 3) * 16;
    u32t hi[8];
    #pragma unroll
    for (int j = 0; j < 8; j++)
        hi[j] = pk2(tile[kc + 2 * j][nr], tile[kc + 2 * j + 1][nr]);
    size_t ob = (size_t)(n0 + nr) * KOUT + k0 + kc;
    *(uint4*)&Th[ob]     = *(uint4*)&hi[0];
    *(uint4*)&Th[ob + 8] = *(uint4*)&hi[4];
}

// ---------------- K1: qkv GEMM, 1-term bf16, head-major epilogue ----------------
__global__ __launch_bounds__(256) void gemm_qkv3(const u16t* __restrict__ Ah,
                                                 const u16t* __restrict__ Bh,
                                                 const float* __restrict__ vb,
                                                 u16t* __restrict__ QB,
                                                 u16t* __restrict__ KB,
                                                 u16t* __restrict__ VF) {
    __shared__ __align__(16) u16t as_h[4 * 128 * 8];
    __shared__ __align__(16) u16t bs_h[4 * 128 * 8];

    const int t = threadIdx.x;
    const int lane = t & 63, wid = t >> 6;
    const int quad = lane >> 4, l15 = lane & 15;
    const int wm = (wid & 1) * 64;
    const int wn = (wid >> 1) * 64;
    const int tile = blockIdx.x;               // 0..47 = h*3 + {q,k,v}
    const int h = tile / 3, t3 = tile - h * 3;
    const int colBase = tile * 128;
    const int rowBase = blockIdx.y * 128;
    const int sm = t & 127;
    const int skh = t >> 7;

    f32x4 acc[4][4];
    #pragma unroll
    for (int i = 0; i < 4; i++)
        #pragma unroll
        for (int j = 0; j < 4; j++) acc[i][j] = (f32x4){0.f, 0.f, 0.f, 0.f};

    const u16t* aPtr = Ah + (size_t)(rowBase + sm) * DIN + skh * 16;
    const u16t* bPtr = Bh + (size_t)(colBase + sm) * DIN + skh * 16;
    u16t* aw = &as_h[(skh * 2) * 1024 + sm * 8];
    u16t* bw = &bs_h[(skh * 2) * 1024 + sm * 8];

    for (int k0 = 0; k0 < DIN; k0 += 32) {
        uint4 a0 = *(const uint4*)(aPtr + k0);
        uint4 a1 = *(const uint4*)(aPtr + k0 + 8);
        uint4 b0 = *(const uint4*)(bPtr + k0);
        uint4 b1 = *(const uint4*)(bPtr + k0 + 8);
        __syncthreads();
        *(uint4*)(aw)        = a0;
        *(uint4*)(aw + 1024) = a1;
        *(uint4*)(bw)        = b0;
        *(uint4*)(bw + 1024) = b1;
        __syncthreads();

        bf16x8 ah[4], bh[4];
        #pragma unroll
        for (int mt = 0; mt < 4; mt++)
            ah[mt] = *(const bf16x8*)&as_h[quad * 1024 + (wm + mt * 16 + l15) * 8];
        #pragma unroll
        for (int nt = 0; nt < 4; nt++)
            bh[nt] = *(const bf16x8*)&bs_h[quad * 1024 + (wn + nt * 16 + l15) * 8];
        #pragma unroll
        for (int mt = 0; mt < 4; mt++)
            #pragma unroll
            for (int nt = 0; nt < 4; nt++)
                acc[mt][nt] = __builtin_amdgcn_mfma_f32_16x16x32_bf16(ah[mt], bh[nt], acc[mt][nt], 0, 0, 0);
    }

    const int z = rowBase >> 11;
    const int s0 = (rowBase & 2047) + wm + quad * 4;
    const size_t obase = (size_t)(z * 16 + h) * 2048;
    if (t3 == 2) {
        #pragma unroll
        for (int nt = 0; nt < 4; nt++) {
            int c = wn + nt * 16 + l15;
            float bb = vb[h * 128 + c];
            #pragma unroll
            for (int mt = 0; mt < 4; mt++)
                #pragma unroll
                for (int r = 0; r < 4; r++)
                    VF[(obase + s0 + mt * 16 + r) * 128 + c] = f2bf(acc[mt][nt][r] + bb);
        }
    } else {
        u16t* dst = t3 ? KB : QB;
        #pragma unroll
        for (int nt = 0; nt < 4; nt++) {
            int c = wn + nt * 16 + l15;
            #pragma unroll
            for (int mt = 0; mt < 4; mt++)
                #pragma unroll
                for (int r = 0; r < 4; r++)
                    dst[(obase + s0 + mt * 16 + r) * 128 + c] = f2bf(acc[mt][nt][r]);
        }
    }
}

// ---------------- K2: rotary in-place on QB/KB; V tile-transpose in-place ----------------
__global__ __launch_bounds__(256) void prep_rot_trans(u16t* __restrict__ QB,
                                                      u16t* __restrict__ KB,
                                                      u16t* __restrict__ VTh) {
    const int bx = blockIdx.x;
    const int st = bx & 63, h = (bx >> 6) & 15, z = bx >> 10;
    const int t = threadIdx.x;
    const size_t base = ((size_t)(z * 16 + h) * 2048 + st * 32) * 128;

    {
        const int r = t >> 3, w = t & 7;
        const int c = w & 3;
        const int s = st * 32 + r;
        u16t* buf = (w < 4) ? QB : KB;
        u16t* p1 = buf + base + (size_t)r * 128 + c * 16;
        u16t* p2 = p1 + 64;
        uint4 a0 = *(uint4*)p1, a1 = *(uint4*)(p1 + 8);
        uint4 b0 = *(uint4*)p2, b1 = *(uint4*)(p2 + 8);
        u32t A[8] = {a0.x, a0.y, a0.z, a0.w, a1.x, a1.y, a1.z, a1.w};
        u32t B[8] = {b0.x, b0.y, b0.z, b0.w, b1.x, b1.y, b1.z, b1.w};
        u32t OA[8], OB[8];
        #pragma unroll
        for (int p = 0; p < 8; p++) {
            float x1a = bf2f((u16t)(A[p] & 0xFFFFu)), x1b = bf2f((u16t)(A[p] >> 16));
            float x2a = bf2f((u16t)(B[p] & 0xFFFFu)), x2b = bf2f((u16t)(B[p] >> 16));
            int j0 = c * 16 + 2 * p;
            float f0 = expf(-0.14391156831212788f * (float)j0);
            float f1 = expf(-0.14391156831212788f * (float)(j0 + 1));
            float sn0, cs0, sn1, cs1;
            sincosf((float)s * f0, &sn0, &cs0);
            sincosf((float)s * f1, &sn1, &cs1);
            OA[p] = pk2(x1a * cs0 - x2a * sn0, x1b * cs1 - x2b * sn1);
            OB[p] = pk2(x2a * cs0 + x1a * sn0, x2b * cs1 + x1b * sn1);
        }
        *(uint4*)p1       = make_uint4(OA[0], OA[1], OA[2], OA[3]);
        *(uint4*)(p1 + 8) = make_uint4(OA[4], OA[5], OA[6], OA[7]);
        *(uint4*)p2       = make_uint4(OB[0], OB[1], OB[2], OB[3]);
        *(uint4*)(p2 + 8) = make_uint4(OB[4], OB[5], OB[6], OB[7]);
    }

    __shared__ u16t vt[128 * 40];
    {
        uint4 a = *(uint4*)(VTh + base + t * 16);
        uint4 b = *(uint4*)(VTh + base + t * 16 + 8);
        int row = t >> 3, d0 = (t & 7) * 16;
        u32t W[8] = {a.x, a.y, a.z, a.w, b.x, b.y, b.z, b.w};
        #pragma unroll
        for (int p = 0; p < 8; p++) {
            vt[(d0 + 2 * p) * 40 + row]     = (u16t)(W[p] & 0xFFFFu);
            vt[(d0 + 2 * p + 1) * 40 + row] = (u16t)(W[p] >> 16);
        }
    }
    __syncthreads();
    {
        int d = t >> 1, k0 = (t & 1) * 16;
        uint4 a = *(uint4*)&vt[d * 40 + k0];
        uint4 b = *(uint4*)&vt[d * 40 + k0 + 8];
        *(uint4*)(VTh + base + t * 16)     = a;
        *(uint4*)(VTh + base + t * 16 + 8) = b;
    }
}

// ---------------- K3: attention v5 — pipelined, double-buffered, ONE barrier/iter ----------------
#define ATTSCALE 0.08838834764831845f

__global__ __launch_bounds__(256, 2) void attn_kernel5(const u16t* __restrict__ QB,
                                                       const u16t* __restrict__ KB,
                                                       const u16t* __restrict__ VTh,
                                                       const int* __restrict__ mask,
                                                       u16t* __restrict__ O3b) {
    const int blk = blockIdx.x;
    const int qt = blk & 15;           // 16 q-blocks of 128
    const int h  = (blk >> 4) & 15;
    const int z  = blk >> 8;
    const int t  = threadIdx.x;
    const int lane = t & 63, wid = t >> 6;
    const int quad = lane >> 4, l15 = lane & 15;

    __shared__ __align__(16) u16t ks[2][32 * 136];   // K bf16 [key][d], double-buffered
    __shared__ __align__(16) u16t vth[2][128 * 40];  // V^T bf16 [d][key], double-buffered
    __shared__ __align__(16) u16t wlb[128 * 40];     // P bf16 [q][key] (wave-private rows)
    __shared__ int qm[128], km[2][32];

    const int q0 = qt * 128;
    const size_t zh = (size_t)(z * 16 + h);
    const u16t* qb  = QB  + zh * 262144;
    const u16t* kb  = KB  + zh * 262144;
    const u16t* vhg = VTh + zh * 262144;

    // wave owns q-16-tiles {2*wid, 2*wid+1}
    bf16x8 qf[2][4];
    #pragma unroll
    for (int i = 0; i < 2; i++)
        #pragma unroll
        for (int kk = 0; kk < 4; kk++)
            qf[i][kk] = *(const bf16x8*)(qb + (size_t)(q0 + 16 * (2 * wid + i) + l15) * 128 + kk * 32 + quad * 8);
    if (t < 128) qm[t] = mask[z * SQ + q0 + t];

    // staging maps
    const int srow = t >> 3, sco = (t & 7) * 16;     // K: [key srow][d sco..]
    const int sdd = t >> 1, sk0 = (t & 1) * 16;      // V: [d sdd][key sk0..]

    // prefetch tile 0
    uint4 ka, kb2, va, vb2;
    int kmv = 0;
    {
        const u16t* src = kb + t * 16;
        ka  = *(const uint4*)(src);
        kb2 = *(const uint4*)(src + 8);
        const u16t* srch = vhg + t * 16;
        va  = *(const uint4*)(srch);
        vb2 = *(const uint4*)(srch + 8);
        if (t < 32) kmv = mask[z * SQ + t];
    }

    f32x4 acc[2][8];
    #pragma unroll
    for (int i = 0; i < 2; i++)
        #pragma unroll
        for (int d = 0; d < 8; d++) acc[i][d] = (f32x4){0.f, 0.f, 0.f, 0.f};
    float dsum[2][4] = {{0.f, 0.f, 0.f, 0.f}, {0.f, 0.f, 0.f, 0.f}};

    for (int it = 0; it < 64; it++) {
        const int buf = it & 1;
        // commit prefetched tile to LDS (vmcnt wait lands here, after a full compute phase)
        *(uint4*)&ks[buf][srow * 136 + sco]     = ka;
        *(uint4*)&ks[buf][srow * 136 + sco + 8] = kb2;
        *(uint4*)&vth[buf][sdd * 40 + sk0]      = va;
        *(uint4*)&vth[buf][sdd * 40 + sk0 + 8]  = vb2;
        if (t < 32) km[buf][t] = kmv;

        // issue next tile's loads (values unused on last iter; addresses clamped in-range)
        {
            const int ktn = (it < 63) ? (it + 1) * 32 : it * 32;
            const u16t* src = kb + (size_t)ktn * 128 + t * 16;
            ka  = *(const uint4*)(src);
            kb2 = *(const uint4*)(src + 8);
            const u16t* srch = vhg + (size_t)(ktn >> 5) * 4096 + t * 16;
            va  = *(const uint4*)(srch);
            vb2 = *(const uint4*)(srch + 8);
            if (t < 32) kmv = mask[z * SQ + ktn + t];
        }

        __syncthreads();   // single barrier: buf writes visible; prior buf^1 reads were consumed pre-barrier

        // QK^T: 2 q-tiles x 2 key-cols, kf shared across q
        f32x4 s4[2][2];
        #pragma unroll
        for (int i = 0; i < 2; i++)
            #pragma unroll
            for (int n = 0; n < 2; n++) s4[i][n] = (f32x4){0.f, 0.f, 0.f, 0.f};
        #pragma unroll
        for (int kk = 0; kk < 4; kk++) {
            bf16x8 kf0 = *(const bf16x8*)&ks[buf][l15 * 136 + kk * 32 + quad * 8];
            bf16x8 kf1 = *(const bf16x8*)&ks[buf][(16 + l15) * 136 + kk * 32 + quad * 8];
            s4[0][0] = __builtin_amdgcn_mfma_f32_16x16x32_bf16(qf[0][kk], kf0, s4[0][0], 0, 0, 0);
            s4[0][1] = __builtin_amdgcn_mfma_f32_16x16x32_bf16(qf[0][kk], kf1, s4[0][1], 0, 0, 0);
            s4[1][0] = __builtin_amdgcn_mfma_f32_16x16x32_bf16(qf[1][kk], kf0, s4[1][0], 0, 0, 0);
            s4[1][1] = __builtin_amdgcn_mfma_f32_16x16x32_bf16(qf[1][kk], kf1, s4[1][1], 0, 0, 0);
        }
        {   // mask + exp -> bf16 P into wave-private LDS rows; fp32 denominator
            int colm0 = km[buf][l15], colm1 = km[buf][16 + l15];
            #pragma unroll
            for (int i = 0; i < 2; i++)
                #pragma unroll
                for (int r = 0; r < 4; r++) {
                    int row = 16 * (2 * wid + i) + 4 * quad + r;
                    int qmr = qm[row];
                    float w0 = (qmr | colm0) ? 0.f : __expf(s4[i][0][r] * ATTSCALE);
                    float w1 = (qmr | colm1) ? 0.f : __expf(s4[i][1][r] * ATTSCALE);
                    dsum[i][r] += w0 + w1;
                    wlb[row * 40 + l15]      = f2bf(w0);
                    wlb[row * 40 + 16 + l15] = f2bf(w1);
                }
        }
        // P·V: same-wave read-back (wave-private rows; lgkmcnt ordering, no barrier)
        bf16x8 pa[2];
        #pragma unroll
        for (int i = 0; i < 2; i++)
            pa[i] = *(const bf16x8*)&wlb[(16 * (2 * wid + i) + l15) * 40 + quad * 8];
        #pragma unroll
        for (int dt = 0; dt < 8; dt++) {
            bf16x8 vh = *(const bf16x8*)&vth[buf][(16 * dt + l15) * 40 + quad * 8];
            acc[0][dt] = __builtin_amdgcn_mfma_f32_16x16x32_bf16(pa[0], vh, acc[0][dt], 0, 0, 0);
            acc[1][dt] = __builtin_amdgcn_mfma_f32_16x16x32_bf16(pa[1], vh, acc[1][dt], 0, 0, 0);
        }
    }

    // denominator: complete within wave — 16-lane shuffle reduce
    #pragma unroll
    for (int i = 0; i < 2; i++)
        #pragma unroll
        for (int r = 0; r < 4; r++) {
            float v = dsum[i][r];
            v += __shfl_xor(v, 1);
            v += __shfl_xor(v, 2);
            v += __shfl_xor(v, 4);
            v += __shfl_xor(v, 8);
            dsum[i][r] = v;
        }

    // epilogue: normalize, cube, write bf16 O in [m=z*2048+s][k=h*128+d]
    #pragma unroll
    for (int i = 0; i < 2; i++)
        #pragma unroll
        for (int r = 0; r < 4; r++) {
            int row = 16 * (2 * wid + i) + 4 * quad + r;
            float den = dsum[i][r];
            float inv = den > 0.f ? 1.f / den : 0.f;
            u16t* dst = O3b + (size_t)(z * SQ + q0 + row) * KOUT + h * 128;
            #pragma unroll
            for (int dt = 0; dt < 8; dt++)
                dst[16 * dt + l15] = f2bf(cubef(acc[i][dt][r] * inv));
        }
}

// ---------------- K4: partial[s] = O3b[:, chunk] @ W[chunk, :]  (1-term bf16 MFMA) ----------------
__global__ __launch_bounds__(256) void final_gemm2(const u16t* __restrict__ Ab,
                                                   const u16t* __restrict__ Bh,
                                                   float* __restrict__ part) {
    __shared__ __align__(16) u16t as_h[4 * 128 * 8];
    __shared__ __align__(16) u16t bs_h[4 * 128 * 8];

    const int t = threadIdx.x;
    const int lane = t & 63, wid = t >> 6;
    const int quad = lane >> 4, l15 = lane & 15;
    const int wm = (wid & 1) * 64;
    const int wn = (wid >> 1) * 64;
    const int rowBase = blockIdx.x * 128;
    const int kBase   = blockIdx.y * (KOUT / KSPLIT);
    const int sm = t & 127;
    const int skh = t >> 7;

    f32x4 acc[4][4];
    #pragma unroll
    for (int i = 0; i < 4; i++)
        #pragma unroll
        for (int j = 0; j < 4; j++) acc[i][j] = (f32x4){0.f, 0.f, 0.f, 0.f};

    const u16t* aPtr = Ab + (size_t)(rowBase + sm) * KOUT + kBase + skh * 16;
    const u16t* bPtr = Bh + (size_t)sm * KOUT + kBase + skh * 16;
    u16t* aw = &as_h[(skh * 2) * 1024 + sm * 8];
    u16t* bw = &bs_h[(skh * 2) * 1024 + sm * 8];

    for (int k0 = 0; k0 < KOUT / KSPLIT; k0 += 32) {
        uint4 a0 = *(const uint4*)(aPtr + k0);
        uint4 a1 = *(const uint4*)(aPtr + k0 + 8);
        uint4 b0 = *(const uint4*)(bPtr + k0);
        uint4 b1 = *(const uint4*)(bPtr + k0 + 8);
        __syncthreads();
        *(uint4*)(aw)        = a0;
        *(uint4*)(aw + 1024) = a1;
        *(uint4*)(bw)        = b0;
        *(uint4*)(bw + 1024) = b1;
        __syncthreads();

        bf16x8 ah[4], bh[4];
        #pragma unroll
        for (int mt = 0; mt < 4; mt++)
            ah[mt] = *(const bf16x8*)&as_h[quad * 1024 + (wm + mt * 16 + l15) * 8];
        #pragma unroll
        for (int nt = 0; nt < 4; nt++)
            bh[nt] = *(const bf16x8*)&bs_h[quad * 1024 + (wn + nt * 16 + l15) * 8];
        #pragma unroll
        for (int mt = 0; mt < 4; mt++)
            #pragma unroll
            for (int nt = 0; nt < 4; nt++)
                acc[mt][nt] = __builtin_amdgcn_mfma_f32_16x16x32_bf16(ah[mt], bh[nt], acc[mt][nt], 0, 0, 0);
    }

    float* pbase = part + (size_t)blockIdx.y * ((size_t)MROWS * 128);
    #pragma unroll
    for (int mt = 0; mt < 4; mt++)
        #pragma unroll
        for (int nt = 0; nt < 4; nt++) {
            int col = wn + nt * 16 + l15;
            #pragma unroll
            for (int r = 0; r < 4; r++) {
                int row = rowBase + wm + mt * 16 + quad * 4 + r;
                pbase[(size_t)row * 128 + col] = acc[mt][nt][r];
            }
        }
}

// ---------------- K5: out = cube(sum partials + bias) ----------------
__global__ __launch_bounds__(256) void reduce_bias_cube(const float* __restrict__ part,
                                                        const float* __restrict__ bias,
                                                        float* __restrict__ out) {
    const int idx = (blockIdx.x * 256 + threadIdx.x) * 4;
    float4 s = {0.f, 0.f, 0.f, 0.f};
    #pragma unroll
    for (int p = 0; p < KSPLIT; p++) {
        float4 v = *(const float4*)&part[(size_t)p * ((size_t)MROWS * 128) + idx];
        s.x += v.x; s.y += v.y; s.z += v.z; s.w += v.w;
    }
    float4 b = *(const float4*)&bias[idx & 127];
    float4 r;
    r.x = cubef(s.x + b.x);
    r.y = cubef(s.y + b.y);
    r.z = cubef(s.z + b.z);
    r.w = cubef(s.w + b.w);
    *(float4*)&out[idx] = r;
}

extern "C" void kernel_launch(void* const* d_in, const int* in_sizes, int n_in,
                              void* d_out, int out_size, void* d_ws, size_t ws_size,
                              hipStream_t stream) {
    const float* x        = (const float*)d_in[0];
    const int*   mask     = (const int*)d_in[1];
    const float* proj_in  = (const float*)d_in[2];
    const float* v_bias   = (const float*)d_in[3];
    const float* proj_out = (const float*)d_in[4];
    const float* po_bias  = (const float*)d_in[5];
    float* out = (float*)d_out;

    // ws layout (~72 MB):
    u16t* QB  = (u16t*)d_ws;                      // [z,h,s,d] bf16 16 MB
    u16t* KB  = QB + (size_t)8388608;             // 16 MB
    u16t* VTh = KB + (size_t)8388608;             // 16 MB ([s][d] from gemm, [d][s]-tiled after prep)
    u16t* xb  = VTh + (size_t)8388608;            // [4096,1024] bf16 8 MB
    u16t* O3b = xb + (size_t)4194304;             // [4096,2048] bf16 16 MB
    // pTh aliases O3b (dead before attn writes O3b; gemm reads complete first — stream order)
    u16t* pTh = O3b;                              // [6144,1024] bf16 12.6 MB
    // WTh + partials alias QB/KB (dead after attn)
    u16t* WTh = QB;                               // [128,2048] bf16 0.5 MB
    float* partials = (float*)(WTh + (size_t)128 * KOUT);  // [8,4096,128] f32 16 MB

    bf16_x<<<(MROWS * DIN) / (256 * 8), 256, 0, stream>>>(x, xb);
    transpose_w<<<dim3(NT / 64, DIN / 64), 256, 0, stream>>>(proj_in, pTh);
    gemm_qkv3<<<dim3(48, MROWS / 128), 256, 0, stream>>>(xb, pTh, v_bias, QB, KB, VTh);
    prep_rot_trans<<<BZ * HH * (SQ / 32), 256, 0, stream>>>(QB, KB, VTh);
    attn_kernel5<<<BZ * HH * (SQ / 128), 256, 0, stream>>>(QB, KB, VTh, mask, O3b);
    transpose_w2<<<dim3(2, KOUT / 64), 256, 0, stream>>>(proj_out, WTh);
    final_gemm2<<<dim3(MROWS / 128, KSPLIT), 256, 0, stream>>>(O3b, WTh, partials);
    reduce_bias_cube<<<(MROWS * 128) / (256 * 4), 256, 0, stream>>>(partials, po_bias, out);
}